// Round 1
// baseline (4699.747 us; speedup 1.0000x reference)
//
#include <hip/hip_runtime.h>

#define NN 50000
#define NE 600000
#define HD 128
#define NG 512
#define OD 64
#define BN_EPS 1e-5f

// ---------------- CSR build ----------------

__global__ void hist_kernel(const int* __restrict__ dst, int* __restrict__ deg, int E) {
    int i = blockIdx.x * blockDim.x + threadIdx.x;
    if (i < E) atomicAdd(&deg[dst[i]], 1);
}

__global__ void scan_kernel(const int* __restrict__ deg, int* __restrict__ offsets,
                            int* __restrict__ cursor, int n) {
    __shared__ int part[1024];
    const int tid = threadIdx.x;
    const int chunk = (n + 1023) >> 10;
    const int s0 = tid * chunk;
    const int s1 = (s0 + chunk < n) ? (s0 + chunk) : n;
    int s = 0;
    for (int i = s0; i < s1; ++i) s += deg[i];
    part[tid] = s;
    __syncthreads();
    int v = s;
    for (int off = 1; off < 1024; off <<= 1) {
        int t = (tid >= off) ? part[tid - off] : 0;
        __syncthreads();
        v += t;
        part[tid] = v;
        __syncthreads();
    }
    int pre = v - s;  // exclusive prefix of this thread's chunk
    for (int i = s0; i < s1; ++i) {
        offsets[i] = pre;
        cursor[i] = pre;
        pre += deg[i];
    }
    if (tid == 1023) offsets[n] = v;  // total = E
}

__global__ void fill_kernel(const int* __restrict__ src, const int* __restrict__ dst,
                            int* __restrict__ cursor, int* __restrict__ srcs, int E) {
    int i = blockIdx.x * blockDim.x + threadIdx.x;
    if (i < E) {
        int pos = atomicAdd(&cursor[dst[i]], 1);
        srcs[pos] = src[i];
    }
}

__global__ void gstart_kernel(const int* __restrict__ batch, int* __restrict__ gstart,
                              int n, int G) {
    int i = blockIdx.x * blockDim.x + threadIdx.x;
    if (i >= n) return;
    int b = batch[i];
    int bp = (i == 0) ? -1 : batch[i - 1];
    for (int g = bp + 1; g <= b; ++g) gstart[g] = i;
    if (i == n - 1) {
        for (int g = b + 1; g <= G; ++g) gstart[g] = n;
    }
}

// ---------------- GIN aggregation: z[i] = h[i] + sum_{j in N(i)} h[j] ----------------
// one 64-lane wave per node, float2 per lane (128 cols)

__global__ void agg_kernel(const float* __restrict__ h, const int* __restrict__ offsets,
                           const int* __restrict__ srcs, float* __restrict__ z, int n) {
    int node = blockIdx.x * 4 + (threadIdx.x >> 6);
    int lane = threadIdx.x & 63;
    if (node >= n) return;
    const float2* hr = (const float2*)(h + (size_t)node * HD);
    float2 acc = hr[lane];
    int e0 = offsets[node], e1 = offsets[node + 1];
    for (int j = e0; j < e1; ++j) {
        int s = srcs[j];
        float2 v = ((const float2*)(h + (size_t)s * HD))[lane];
        acc.x += v.x;
        acc.y += v.y;
    }
    ((float2*)(z + (size_t)node * HD))[lane] = acc;
}

// ---------------- fp32 GEMM: C[i][o] = sum_k A[i][k] * W[o][k] + b[o] ----------------
// block tile 32 rows x 128 cols, 256 threads, k chunked by 32

template <bool RELU>
__global__ __launch_bounds__(256) void gemm128(const float* __restrict__ A,
                                               const float* __restrict__ W,
                                               const float* __restrict__ bias,
                                               float* __restrict__ C, int nrows) {
    __shared__ float Alds[32 * 36];    // [row][36], padded
    __shared__ float Wlds[32 * 130];   // [k][130] transposed, padded

    const int tx = threadIdx.x;
    const int colh = tx & 63;   // cols 2*colh, 2*colh+1
    const int rowg = tx >> 6;   // 0..3 -> rows rowg*8 .. +7
    const int row0 = blockIdx.x * 32;

    float acc0[8], acc1[8];
#pragma unroll
    for (int rr = 0; rr < 8; ++rr) { acc0[rr] = 0.f; acc1[rr] = 0.f; }

    const int ar = tx >> 3;          // 0..31 (A stage row)
    const int ak = (tx & 7) << 2;    // 0,4,..28 (A stage k)
    const int wc = tx >> 1;          // 0..127 (W stage col)
    const int wk = (tx & 1) << 4;    // 0 or 16 (W stage k base)

    for (int kc = 0; kc < 4; ++kc) {
        const int k0 = kc * 32;
        // stage A tile
        {
            int arow = row0 + ar;
            float4 av = make_float4(0.f, 0.f, 0.f, 0.f);
            if (arow < nrows) av = *(const float4*)(A + (size_t)arow * HD + k0 + ak);
            *(float4*)(&Alds[ar * 36 + ak]) = av;
        }
        // stage W tile, transposed to [k][col]
        {
            const float* wsrc = W + wc * HD + k0 + wk;
            float4 w0 = *(const float4*)(wsrc + 0);
            float4 w1 = *(const float4*)(wsrc + 4);
            float4 w2 = *(const float4*)(wsrc + 8);
            float4 w3 = *(const float4*)(wsrc + 12);
            float* wl = &Wlds[wk * 130 + wc];
            wl[0 * 130] = w0.x;  wl[1 * 130] = w0.y;  wl[2 * 130] = w0.z;  wl[3 * 130] = w0.w;
            wl[4 * 130] = w1.x;  wl[5 * 130] = w1.y;  wl[6 * 130] = w1.z;  wl[7 * 130] = w1.w;
            wl[8 * 130] = w2.x;  wl[9 * 130] = w2.y;  wl[10 * 130] = w2.z; wl[11 * 130] = w2.w;
            wl[12 * 130] = w3.x; wl[13 * 130] = w3.y; wl[14 * 130] = w3.z; wl[15 * 130] = w3.w;
        }
        __syncthreads();

#pragma unroll
        for (int kq = 0; kq < 8; ++kq) {
            float4 a[8];
#pragma unroll
            for (int rr = 0; rr < 8; ++rr)
                a[rr] = *(const float4*)(&Alds[(rowg * 8 + rr) * 36 + kq * 4]);
#pragma unroll
            for (int j = 0; j < 4; ++j) {
                float2 w = *(const float2*)(&Wlds[(kq * 4 + j) * 130 + 2 * colh]);
#pragma unroll
                for (int rr = 0; rr < 8; ++rr) {
                    float av = (j == 0) ? a[rr].x : (j == 1) ? a[rr].y : (j == 2) ? a[rr].z : a[rr].w;
                    acc0[rr] = fmaf(av, w.x, acc0[rr]);
                    acc1[rr] = fmaf(av, w.y, acc1[rr]);
                }
            }
        }
        __syncthreads();
    }

    const float b0 = bias[2 * colh];
    const float b1 = bias[2 * colh + 1];
#pragma unroll
    for (int rr = 0; rr < 8; ++rr) {
        int row = row0 + rowg * 8 + rr;
        if (row < nrows) {
            float v0 = acc0[rr] + b0;
            float v1 = acc1[rr] + b1;
            if (RELU) { v0 = fmaxf(v0, 0.f); v1 = fmaxf(v1, 0.f); }
            *(float2*)(C + (size_t)row * HD + 2 * colh) = make_float2(v0, v1);
        }
    }
}

// ---------------- BatchNorm ----------------

__global__ void bn_stats_kernel(const float* __restrict__ y, float* __restrict__ stats, int n) {
    __shared__ float redS[256], redQ[256];
    const int tx = threadIdx.x;
    const int c = tx & 127;
    const int half = tx >> 7;
    float s = 0.f, ss = 0.f;
    for (int row = blockIdx.x * 2 + half; row < n; row += gridDim.x * 2) {
        float v = y[(size_t)row * HD + c];
        s += v;
        ss = fmaf(v, v, ss);
    }
    redS[tx] = s;
    redQ[tx] = ss;
    __syncthreads();
    if (tx < 128) {
        atomicAdd(&stats[tx], redS[tx] + redS[tx + 128]);
        atomicAdd(&stats[128 + tx], redQ[tx] + redQ[tx + 128]);
    }
}

__global__ void bn_apply_kernel(float* __restrict__ y, const float* __restrict__ stats,
                                const float* __restrict__ gam, const float* __restrict__ bet,
                                int n) {
    int idx = blockIdx.x * blockDim.x + threadIdx.x;  // float4 index
    int total = n * (HD / 4);
    if (idx >= total) return;
    const int c = (idx & 31) * 4;
    const float invn = 1.0f / (float)n;
    float4 v = *(float4*)(y + (size_t)idx * 4);
    float r[4] = {v.x, v.y, v.z, v.w};
#pragma unroll
    for (int j = 0; j < 4; ++j) {
        float mu = stats[c + j] * invn;
        float var = stats[128 + c + j] * invn - mu * mu;
        float sc = gam[c + j] * rsqrtf(var + BN_EPS);
        float sh = bet[c + j] - mu * sc;
        r[j] = fmaxf(fmaf(r[j], sc, sh), 0.0f);
    }
    *(float4*)(y + (size_t)idx * 4) = make_float4(r[0], r[1], r[2], r[3]);
}

// ---------------- mean pool per graph (batch sorted) ----------------

__global__ void pool_kernel(const float* __restrict__ h, const int* __restrict__ gstart,
                            float* __restrict__ pooled, int layerOff) {
    const int g = blockIdx.x;
    const int c = threadIdx.x;  // 128 threads
    int s0 = gstart[g], s1 = gstart[g + 1];
    float acc = 0.f;
    for (int i = s0; i < s1; ++i) acc += h[(size_t)i * HD + c];
    int cnt = s1 - s0;
    float fc = (cnt > 0) ? (float)cnt : 1.0f;
    pooled[(size_t)g * (3 * HD) + layerOff + c] = acc / fc;
}

// ---------------- final linear + row L2 normalize ----------------

__global__ void final_kernel(const float* __restrict__ pooled, const float* __restrict__ linW,
                             const float* __restrict__ linb, float* __restrict__ out) {
    __shared__ float p[3 * HD];
    const int g = blockIdx.x;
    const int o = threadIdx.x;  // 64 threads = 1 wave
    for (int k = o; k < 3 * HD; k += 64) p[k] = pooled[(size_t)g * (3 * HD) + k];
    __syncthreads();
    float acc = linb[o];
    const float* wrow = linW + (size_t)o * (3 * HD);
#pragma unroll 4
    for (int k = 0; k < 3 * HD; k += 4) {
        float4 w = *(const float4*)(wrow + k);
        float4 pv = *(const float4*)(&p[k]);
        acc = fmaf(w.x, pv.x, acc);
        acc = fmaf(w.y, pv.y, acc);
        acc = fmaf(w.z, pv.z, acc);
        acc = fmaf(w.w, pv.w, acc);
    }
    float sq = acc * acc;
#pragma unroll
    for (int off = 32; off > 0; off >>= 1) sq += __shfl_xor(sq, off);
    float nrm = sqrtf(sq);
    nrm = fmaxf(nrm, 1e-12f);
    out[(size_t)g * OD + o] = acc / nrm;
}

// ---------------- launch ----------------

extern "C" void kernel_launch(void* const* d_in, const int* in_sizes, int n_in,
                              void* d_out, int out_size, void* d_ws, size_t ws_size,
                              hipStream_t stream) {
    const float* x    = (const float*)d_in[0];
    const int* ei     = (const int*)d_in[1];
    const int* batch  = (const int*)d_in[2];
    const float* W11  = (const float*)d_in[3];
    const float* b11  = (const float*)d_in[4];
    const float* W12  = (const float*)d_in[5];
    const float* b12  = (const float*)d_in[6];
    const float* g1   = (const float*)d_in[7];
    const float* be1  = (const float*)d_in[8];
    const float* W21  = (const float*)d_in[9];
    const float* b21  = (const float*)d_in[10];
    const float* W22  = (const float*)d_in[11];
    const float* b22  = (const float*)d_in[12];
    const float* g2   = (const float*)d_in[13];
    const float* be2  = (const float*)d_in[14];
    const float* W31  = (const float*)d_in[15];
    const float* b31  = (const float*)d_in[16];
    const float* W32  = (const float*)d_in[17];
    const float* b32  = (const float*)d_in[18];
    const float* g3   = (const float*)d_in[19];
    const float* be3  = (const float*)d_in[20];
    const float* linW = (const float*)d_in[21];
    const float* linb = (const float*)d_in[22];

    const int* src = ei;
    const int* dst = ei + NE;

    char* ws = (char*)d_ws;
    size_t off = 0;
    auto alloc = [&](size_t bytes) -> void* {
        void* p = ws + off;
        off += (bytes + 255) & ~(size_t)255;
        return p;
    };
    int* deg      = (int*)alloc((size_t)NN * 4);
    int* offsets  = (int*)alloc((size_t)(NN + 1) * 4);
    int* cursor   = (int*)alloc((size_t)NN * 4);
    int* srcs     = (int*)alloc((size_t)NE * 4);
    int* gstart   = (int*)alloc((size_t)(NG + 1) * 4);
    float* stats  = (float*)alloc(512 * 4);
    float* pooled = (float*)alloc((size_t)NG * 3 * HD * 4);
    float* bufA   = (float*)alloc((size_t)NN * HD * 4);
    float* bufB   = (float*)alloc((size_t)NN * HD * 4);
    float* bufC   = (float*)alloc((size_t)NN * HD * 4);
    (void)ws_size; (void)n_in; (void)in_sizes; (void)out_size;

    // CSR build
    hipMemsetAsync(deg, 0, (size_t)NN * 4, stream);
    hist_kernel<<<(NE + 255) / 256, 256, 0, stream>>>(dst, deg, NE);
    scan_kernel<<<1, 1024, 0, stream>>>(deg, offsets, cursor, NN);
    fill_kernel<<<(NE + 255) / 256, 256, 0, stream>>>(src, dst, cursor, srcs, NE);
    gstart_kernel<<<(NN + 255) / 256, 256, 0, stream>>>(batch, gstart, NN, NG);

    const int gemmGrid = (NN + 31) / 32;

    auto layer = [&](const float* hin, float* zbuf, float* tbuf,
                     const float* Wa, const float* ba, const float* Wb, const float* bb,
                     const float* gg, const float* bee, int layerOff) {
        agg_kernel<<<(NN + 3) / 4, 256, 0, stream>>>(hin, offsets, srcs, zbuf, NN);
        gemm128<true><<<gemmGrid, 256, 0, stream>>>(zbuf, Wa, ba, tbuf, NN);
        gemm128<false><<<gemmGrid, 256, 0, stream>>>(tbuf, Wb, bb, zbuf, NN);
        hipMemsetAsync(stats, 0, 256 * 4, stream);
        bn_stats_kernel<<<256, 256, 0, stream>>>(zbuf, stats, NN);
        bn_apply_kernel<<<(NN * (HD / 4) + 255) / 256, 256, 0, stream>>>(zbuf, stats, gg, bee, NN);
        pool_kernel<<<NG, HD, 0, stream>>>(zbuf, gstart, pooled, layerOff);
    };

    // L1: h_in = x      -> h1 in bufA
    layer(x, bufA, bufB, W11, b11, W12, b12, g1, be1, 0);
    // L2: h_in = bufA   -> h2 in bufB
    layer(bufA, bufB, bufC, W21, b21, W22, b22, g2, be2, HD);
    // L3: h_in = bufB   -> h3 in bufA
    layer(bufB, bufA, bufC, W31, b31, W32, b32, g3, be3, 2 * HD);

    final_kernel<<<NG, OD, 0, stream>>>(pooled, linW, linb, (float*)d_out);
}

// Round 2
// 786.973 us; speedup vs baseline: 5.9719x; 5.9719x over previous
//
#include <hip/hip_runtime.h>

#define NN 50000
#define NE 600000
#define HD 128
#define NG 512
#define OD 64
#define BN_EPS 1e-5f

// ---------------- CSR build ----------------

__global__ void hist_kernel(const int* __restrict__ dst, int* __restrict__ deg, int E) {
    int i = blockIdx.x * blockDim.x + threadIdx.x;
    if (i < E) atomicAdd(&deg[dst[i]], 1);
}

__global__ void scan_kernel(const int* __restrict__ deg, int* __restrict__ offsets,
                            int* __restrict__ cursor, int n) {
    __shared__ int part[1024];
    const int tid = threadIdx.x;
    const int chunk = (n + 1023) >> 10;
    const int s0 = tid * chunk;
    const int s1 = (s0 + chunk < n) ? (s0 + chunk) : n;
    int s = 0;
    for (int i = s0; i < s1; ++i) s += deg[i];
    part[tid] = s;
    __syncthreads();
    int v = s;
    for (int off = 1; off < 1024; off <<= 1) {
        int t = (tid >= off) ? part[tid - off] : 0;
        __syncthreads();
        v += t;
        part[tid] = v;
        __syncthreads();
    }
    int pre = v - s;  // exclusive prefix of this thread's chunk
    for (int i = s0; i < s1; ++i) {
        offsets[i] = pre;
        cursor[i] = pre;
        pre += deg[i];
    }
    if (tid == 1023) offsets[n] = v;  // total = E
}

__global__ void fill_kernel(const int* __restrict__ src, const int* __restrict__ dst,
                            int* __restrict__ cursor, int* __restrict__ srcs, int E) {
    int i = blockIdx.x * blockDim.x + threadIdx.x;
    if (i < E) {
        int pos = atomicAdd(&cursor[dst[i]], 1);
        srcs[pos] = src[i];
    }
}

__global__ void gstart_kernel(const int* __restrict__ batch, int* __restrict__ gstart,
                              int n, int G) {
    int i = blockIdx.x * blockDim.x + threadIdx.x;
    if (i >= n) return;
    int b = batch[i];
    int bp = (i == 0) ? -1 : batch[i - 1];
    for (int g = bp + 1; g <= b; ++g) gstart[g] = i;
    if (i == n - 1) {
        for (int g = b + 1; g <= G; ++g) gstart[g] = n;
    }
}

// ---------------- GIN aggregation: z[i] = h[i] + sum_{j in N(i)} h[j] ----------------
// one 64-lane wave per node, float2 per lane (128 cols)

__global__ void agg_kernel(const float* __restrict__ h, const int* __restrict__ offsets,
                           const int* __restrict__ srcs, float* __restrict__ z, int n) {
    int node = blockIdx.x * 4 + (threadIdx.x >> 6);
    int lane = threadIdx.x & 63;
    if (node >= n) return;
    const float2* hr = (const float2*)(h + (size_t)node * HD);
    float2 acc = hr[lane];
    int e0 = offsets[node], e1 = offsets[node + 1];
    for (int j = e0; j < e1; ++j) {
        int s = srcs[j];
        float2 v = ((const float2*)(h + (size_t)s * HD))[lane];
        acc.x += v.x;
        acc.y += v.y;
    }
    ((float2*)(z + (size_t)node * HD))[lane] = acc;
}

// ---------------- fp32 GEMM: C[i][o] = sum_k A[i][k] * W[o][k] + b[o] ----------------
// 64x64 tile, 256 threads (16x16), 4x4 outputs/thread, K chunked by 64.
// Both LDS tiles K-major so fragment reads are float4.

template <bool RELU>
__global__ __launch_bounds__(256) void gemm64(const float* __restrict__ A,
                                              const float* __restrict__ W,
                                              const float* __restrict__ bias,
                                              float* __restrict__ C, int nrows) {
    __shared__ float Alds[64][64];  // [k][row]
    __shared__ float Wlds[64][64];  // [k][col]

    const int t = threadIdx.x;
    const int tx = t & 15;   // col group: cols tx*4 .. +3
    const int ty = t >> 4;   // row group: rows ty*4 .. +3
    const int row0 = blockIdx.x * 64;
    const int col0 = blockIdx.y * 64;

    const int sr = t & 63;          // staging row (A) / col (W)
    const int sk = (t >> 6) << 4;   // staging k base: 0,16,32,48

    float acc[4][4];
#pragma unroll
    for (int r = 0; r < 4; ++r)
#pragma unroll
        for (int c = 0; c < 4; ++c) acc[r][c] = 0.f;

    for (int kc = 0; kc < 2; ++kc) {
        const int k0 = kc * 64;
        // stage A tile (transposed to [k][row])
        {
            const int grow = row0 + sr;
            float4 v0, v1, v2, v3;
            if (grow < nrows) {
                const float* ap = A + (size_t)grow * HD + k0 + sk;
                v0 = *(const float4*)(ap + 0);
                v1 = *(const float4*)(ap + 4);
                v2 = *(const float4*)(ap + 8);
                v3 = *(const float4*)(ap + 12);
            } else {
                v0 = v1 = v2 = v3 = make_float4(0.f, 0.f, 0.f, 0.f);
            }
            Alds[sk + 0][sr] = v0.x;  Alds[sk + 1][sr] = v0.y;
            Alds[sk + 2][sr] = v0.z;  Alds[sk + 3][sr] = v0.w;
            Alds[sk + 4][sr] = v1.x;  Alds[sk + 5][sr] = v1.y;
            Alds[sk + 6][sr] = v1.z;  Alds[sk + 7][sr] = v1.w;
            Alds[sk + 8][sr] = v2.x;  Alds[sk + 9][sr] = v2.y;
            Alds[sk + 10][sr] = v2.z; Alds[sk + 11][sr] = v2.w;
            Alds[sk + 12][sr] = v3.x; Alds[sk + 13][sr] = v3.y;
            Alds[sk + 14][sr] = v3.z; Alds[sk + 15][sr] = v3.w;
        }
        // stage W tile (transposed to [k][col])
        {
            const float* wp = W + (size_t)(col0 + sr) * HD + k0 + sk;
            float4 v0 = *(const float4*)(wp + 0);
            float4 v1 = *(const float4*)(wp + 4);
            float4 v2 = *(const float4*)(wp + 8);
            float4 v3 = *(const float4*)(wp + 12);
            Wlds[sk + 0][sr] = v0.x;  Wlds[sk + 1][sr] = v0.y;
            Wlds[sk + 2][sr] = v0.z;  Wlds[sk + 3][sr] = v0.w;
            Wlds[sk + 4][sr] = v1.x;  Wlds[sk + 5][sr] = v1.y;
            Wlds[sk + 6][sr] = v1.z;  Wlds[sk + 7][sr] = v1.w;
            Wlds[sk + 8][sr] = v2.x;  Wlds[sk + 9][sr] = v2.y;
            Wlds[sk + 10][sr] = v2.z; Wlds[sk + 11][sr] = v2.w;
            Wlds[sk + 12][sr] = v3.x; Wlds[sk + 13][sr] = v3.y;
            Wlds[sk + 14][sr] = v3.z; Wlds[sk + 15][sr] = v3.w;
        }
        __syncthreads();

#pragma unroll 8
        for (int k = 0; k < 64; ++k) {
            float4 av = *(const float4*)(&Alds[k][ty * 4]);
            float4 wv = *(const float4*)(&Wlds[k][tx * 4]);
            acc[0][0] = fmaf(av.x, wv.x, acc[0][0]);
            acc[0][1] = fmaf(av.x, wv.y, acc[0][1]);
            acc[0][2] = fmaf(av.x, wv.z, acc[0][2]);
            acc[0][3] = fmaf(av.x, wv.w, acc[0][3]);
            acc[1][0] = fmaf(av.y, wv.x, acc[1][0]);
            acc[1][1] = fmaf(av.y, wv.y, acc[1][1]);
            acc[1][2] = fmaf(av.y, wv.z, acc[1][2]);
            acc[1][3] = fmaf(av.y, wv.w, acc[1][3]);
            acc[2][0] = fmaf(av.z, wv.x, acc[2][0]);
            acc[2][1] = fmaf(av.z, wv.y, acc[2][1]);
            acc[2][2] = fmaf(av.z, wv.z, acc[2][2]);
            acc[2][3] = fmaf(av.z, wv.w, acc[2][3]);
            acc[3][0] = fmaf(av.w, wv.x, acc[3][0]);
            acc[3][1] = fmaf(av.w, wv.y, acc[3][1]);
            acc[3][2] = fmaf(av.w, wv.z, acc[3][2]);
            acc[3][3] = fmaf(av.w, wv.w, acc[3][3]);
        }
        __syncthreads();
    }

    // epilogue
    float4 bv = *(const float4*)(bias + col0 + tx * 4);
#pragma unroll
    for (int r = 0; r < 4; ++r) {
        const int row = row0 + ty * 4 + r;
        if (row < nrows) {
            float4 o;
            o.x = acc[r][0] + bv.x;
            o.y = acc[r][1] + bv.y;
            o.z = acc[r][2] + bv.z;
            o.w = acc[r][3] + bv.w;
            if (RELU) {
                o.x = fmaxf(o.x, 0.f); o.y = fmaxf(o.y, 0.f);
                o.z = fmaxf(o.z, 0.f); o.w = fmaxf(o.w, 0.f);
            }
            *(float4*)(C + (size_t)row * HD + col0 + tx * 4) = o;
        }
    }
}

// ---------------- BatchNorm ----------------

__global__ void bn_stats_kernel(const float* __restrict__ y, float* __restrict__ stats, int n) {
    __shared__ float redS[256], redQ[256];
    const int tx = threadIdx.x;
    const int c = tx & 127;
    const int half = tx >> 7;
    float s = 0.f, ss = 0.f;
    for (int row = blockIdx.x * 2 + half; row < n; row += gridDim.x * 2) {
        float v = y[(size_t)row * HD + c];
        s += v;
        ss = fmaf(v, v, ss);
    }
    redS[tx] = s;
    redQ[tx] = ss;
    __syncthreads();
    if (tx < 128) {
        atomicAdd(&stats[tx], redS[tx] + redS[tx + 128]);
        atomicAdd(&stats[128 + tx], redQ[tx] + redQ[tx + 128]);
    }
}

__global__ void bn_apply_kernel(float* __restrict__ y, const float* __restrict__ stats,
                                const float* __restrict__ gam, const float* __restrict__ bet,
                                int n) {
    int idx = blockIdx.x * blockDim.x + threadIdx.x;  // float4 index
    int total = n * (HD / 4);
    if (idx >= total) return;
    const int c = (idx & 31) * 4;
    const float invn = 1.0f / (float)n;
    float4 v = *(float4*)(y + (size_t)idx * 4);
    float r[4] = {v.x, v.y, v.z, v.w};
#pragma unroll
    for (int j = 0; j < 4; ++j) {
        float mu = stats[c + j] * invn;
        float var = stats[128 + c + j] * invn - mu * mu;
        float sc = gam[c + j] * rsqrtf(var + BN_EPS);
        float sh = bet[c + j] - mu * sc;
        r[j] = fmaxf(fmaf(r[j], sc, sh), 0.0f);
    }
    *(float4*)(y + (size_t)idx * 4) = make_float4(r[0], r[1], r[2], r[3]);
}

// ---------------- mean pool per graph (batch sorted) ----------------

__global__ void pool_kernel(const float* __restrict__ h, const int* __restrict__ gstart,
                            float* __restrict__ pooled, int layerOff) {
    const int g = blockIdx.x;
    const int c = threadIdx.x;  // 128 threads
    int s0 = gstart[g], s1 = gstart[g + 1];
    float acc = 0.f;
    for (int i = s0; i < s1; ++i) acc += h[(size_t)i * HD + c];
    int cnt = s1 - s0;
    float fc = (cnt > 0) ? (float)cnt : 1.0f;
    pooled[(size_t)g * (3 * HD) + layerOff + c] = acc / fc;
}

// ---------------- final linear + row L2 normalize ----------------

__global__ void final_kernel(const float* __restrict__ pooled, const float* __restrict__ linW,
                             const float* __restrict__ linb, float* __restrict__ out) {
    __shared__ float p[3 * HD];
    const int g = blockIdx.x;
    const int o = threadIdx.x;  // 64 threads = 1 wave
    for (int k = o; k < 3 * HD; k += 64) p[k] = pooled[(size_t)g * (3 * HD) + k];
    __syncthreads();
    float acc = linb[o];
    const float* wrow = linW + (size_t)o * (3 * HD);
#pragma unroll 4
    for (int k = 0; k < 3 * HD; k += 4) {
        float4 w = *(const float4*)(wrow + k);
        float4 pv = *(const float4*)(&p[k]);
        acc = fmaf(w.x, pv.x, acc);
        acc = fmaf(w.y, pv.y, acc);
        acc = fmaf(w.z, pv.z, acc);
        acc = fmaf(w.w, pv.w, acc);
    }
    float sq = acc * acc;
#pragma unroll
    for (int off = 32; off > 0; off >>= 1) sq += __shfl_xor(sq, off);
    float nrm = sqrtf(sq);
    nrm = fmaxf(nrm, 1e-12f);
    out[(size_t)g * OD + o] = acc / nrm;
}

// ---------------- launch ----------------

extern "C" void kernel_launch(void* const* d_in, const int* in_sizes, int n_in,
                              void* d_out, int out_size, void* d_ws, size_t ws_size,
                              hipStream_t stream) {
    const float* x    = (const float*)d_in[0];
    const int* ei     = (const int*)d_in[1];
    const int* batch  = (const int*)d_in[2];
    const float* W11  = (const float*)d_in[3];
    const float* b11  = (const float*)d_in[4];
    const float* W12  = (const float*)d_in[5];
    const float* b12  = (const float*)d_in[6];
    const float* g1   = (const float*)d_in[7];
    const float* be1  = (const float*)d_in[8];
    const float* W21  = (const float*)d_in[9];
    const float* b21  = (const float*)d_in[10];
    const float* W22  = (const float*)d_in[11];
    const float* b22  = (const float*)d_in[12];
    const float* g2   = (const float*)d_in[13];
    const float* be2  = (const float*)d_in[14];
    const float* W31  = (const float*)d_in[15];
    const float* b31  = (const float*)d_in[16];
    const float* W32  = (const float*)d_in[17];
    const float* b32  = (const float*)d_in[18];
    const float* g3   = (const float*)d_in[19];
    const float* be3  = (const float*)d_in[20];
    const float* linW = (const float*)d_in[21];
    const float* linb = (const float*)d_in[22];

    const int* src = ei;
    const int* dst = ei + NE;

    char* ws = (char*)d_ws;
    size_t off = 0;
    auto alloc = [&](size_t bytes) -> void* {
        void* p = ws + off;
        off += (bytes + 255) & ~(size_t)255;
        return p;
    };
    int* deg      = (int*)alloc((size_t)NN * 4);
    int* offsets  = (int*)alloc((size_t)(NN + 1) * 4);
    int* cursor   = (int*)alloc((size_t)NN * 4);
    int* srcs     = (int*)alloc((size_t)NE * 4);
    int* gstart   = (int*)alloc((size_t)(NG + 1) * 4);
    float* stats  = (float*)alloc(512 * 4);
    float* pooled = (float*)alloc((size_t)NG * 3 * HD * 4);
    float* bufA   = (float*)alloc((size_t)NN * HD * 4);
    float* bufB   = (float*)alloc((size_t)NN * HD * 4);
    float* bufC   = (float*)alloc((size_t)NN * HD * 4);
    (void)ws_size; (void)n_in; (void)in_sizes; (void)out_size;

    // CSR build
    hipMemsetAsync(deg, 0, (size_t)NN * 4, stream);
    hist_kernel<<<(NE + 255) / 256, 256, 0, stream>>>(dst, deg, NE);
    scan_kernel<<<1, 1024, 0, stream>>>(deg, offsets, cursor, NN);
    fill_kernel<<<(NE + 255) / 256, 256, 0, stream>>>(src, dst, cursor, srcs, NE);
    gstart_kernel<<<(NN + 255) / 256, 256, 0, stream>>>(batch, gstart, NN, NG);

    const dim3 gemmGrid((NN + 63) / 64, 2);

    auto layer = [&](const float* hin, float* zbuf, float* tbuf,
                     const float* Wa, const float* ba, const float* Wb, const float* bb,
                     const float* gg, const float* bee, int layerOff) {
        agg_kernel<<<(NN + 3) / 4, 256, 0, stream>>>(hin, offsets, srcs, zbuf, NN);
        gemm64<true><<<gemmGrid, 256, 0, stream>>>(zbuf, Wa, ba, tbuf, NN);
        gemm64<false><<<gemmGrid, 256, 0, stream>>>(tbuf, Wb, bb, zbuf, NN);
        hipMemsetAsync(stats, 0, 256 * 4, stream);
        bn_stats_kernel<<<256, 256, 0, stream>>>(zbuf, stats, NN);
        bn_apply_kernel<<<(NN * (HD / 4) + 255) / 256, 256, 0, stream>>>(zbuf, stats, gg, bee, NN);
        pool_kernel<<<NG, HD, 0, stream>>>(zbuf, gstart, pooled, layerOff);
    };

    // L1: h_in = x      -> h1 in bufA
    layer(x, bufA, bufB, W11, b11, W12, b12, g1, be1, 0);
    // L2: h_in = bufA   -> h2 in bufB
    layer(bufA, bufB, bufC, W21, b21, W22, b22, g2, be2, HD);
    // L3: h_in = bufB   -> h3 in bufA
    layer(bufB, bufA, bufC, W31, b31, W32, b32, g3, be3, 2 * HD);

    final_kernel<<<NG, OD, 0, stream>>>(pooled, linW, linb, (float*)d_out);
}

// Round 3
// 611.274 us; speedup vs baseline: 7.6884x; 1.2874x over previous
//
#include <hip/hip_runtime.h>

#define NN 50000
#define NE 600000
#define HD 128
#define NG 512
#define OD 64
#define BN_EPS 1e-5f

#define SCAN_BLK 1024
#define NSB ((NN + SCAN_BLK - 1) / SCAN_BLK)  // 49

// ---------------- CSR build ----------------

__global__ void hist_kernel(const int* __restrict__ dst, int* __restrict__ deg, int E) {
    int i = blockIdx.x * blockDim.x + threadIdx.x;
    if (i < E) atomicAdd(&deg[dst[i]], 1);
}

// phase 1: per-block inclusive scan -> exclusive local scan + block totals
__global__ void local_scan_kernel(const int* __restrict__ deg, int* __restrict__ lexcl,
                                  int* __restrict__ bsum, int n) {
    __shared__ int part[SCAN_BLK];
    const int tid = threadIdx.x;
    const int i = blockIdx.x * SCAN_BLK + tid;
    int v = (i < n) ? deg[i] : 0;
    part[tid] = v;
    __syncthreads();
    int incl = v;
    for (int off = 1; off < SCAN_BLK; off <<= 1) {
        int t = (tid >= off) ? part[tid - off] : 0;
        __syncthreads();
        incl += t;
        part[tid] = incl;
        __syncthreads();
    }
    if (i < n) lexcl[i] = incl - v;
    if (tid == SCAN_BLK - 1) bsum[blockIdx.x] = incl;
}

// phase 2: scan the (<=64) block sums with one wave
__global__ void scan_bsum_kernel(const int* __restrict__ bsum, int* __restrict__ boff,
                                 int* __restrict__ offsets, int nb, int n) {
    const int tid = threadIdx.x;  // 64 threads
    int orig = (tid < nb) ? bsum[tid] : 0;
    int v = orig;
    for (int off = 1; off < 64; off <<= 1) {
        int t = __shfl_up(v, off);
        if (tid >= off) v += t;
    }
    if (tid < nb) boff[tid] = v - orig;
    if (tid == 63) offsets[n] = v;  // total = E
}

// phase 3: add block offsets
__global__ void finalize_scan_kernel(const int* __restrict__ lexcl, const int* __restrict__ boff,
                                     int* __restrict__ offsets, int* __restrict__ cursor, int n) {
    int i = blockIdx.x * blockDim.x + threadIdx.x;
    if (i < n) {
        int o = lexcl[i] + boff[i >> 10];  // SCAN_BLK = 1024
        offsets[i] = o;
        cursor[i] = o;
    }
}

__global__ void fill_kernel(const int* __restrict__ src, const int* __restrict__ dst,
                            int* __restrict__ cursor, int* __restrict__ srcs, int E) {
    int i = blockIdx.x * blockDim.x + threadIdx.x;
    if (i < E) {
        int pos = atomicAdd(&cursor[dst[i]], 1);
        srcs[pos] = src[i];
    }
}

__global__ void gstart_kernel(const int* __restrict__ batch, int* __restrict__ gstart,
                              int n, int G) {
    int i = blockIdx.x * blockDim.x + threadIdx.x;
    if (i >= n) return;
    int b = batch[i];
    int bp = (i == 0) ? -1 : batch[i - 1];
    for (int g = bp + 1; g <= b; ++g) gstart[g] = i;
    if (i == n - 1) {
        for (int g = b + 1; g <= G; ++g) gstart[g] = n;
    }
}

// ---------------- GIN aggregation: z[i] = h[i] + sum_{j in N(i)} h[j] ----------------

__global__ void agg_kernel(const float* __restrict__ h, const int* __restrict__ offsets,
                           const int* __restrict__ srcs, float* __restrict__ z, int n) {
    int node = blockIdx.x * 4 + (threadIdx.x >> 6);
    int lane = threadIdx.x & 63;
    if (node >= n) return;
    const float2* hr = (const float2*)(h + (size_t)node * HD);
    float2 acc = hr[lane];
    int e0 = offsets[node], e1 = offsets[node + 1];
    for (int j = e0; j < e1; ++j) {
        int s = srcs[j];
        float2 v = ((const float2*)(h + (size_t)s * HD))[lane];
        acc.x += v.x;
        acc.y += v.y;
    }
    ((float2*)(z + (size_t)node * HD))[lane] = acc;
}

// ---------------- fp32 GEMM: C[i][o] = sum_k A[i][k] * W[o][k] + b[o] ----------------
// 64x64 tile, 256 threads (16x16), 4x4 outputs/thread, K chunked by 64.

template <bool RELU>
__global__ __launch_bounds__(256) void gemm64(const float* __restrict__ A,
                                              const float* __restrict__ W,
                                              const float* __restrict__ bias,
                                              float* __restrict__ C, int nrows) {
    __shared__ float Alds[64][64];  // [k][row]
    __shared__ float Wlds[64][64];  // [k][col]

    const int t = threadIdx.x;
    const int tx = t & 15;   // col group: cols tx*4 .. +3
    const int ty = t >> 4;   // row group: rows ty*4 .. +3
    const int row0 = blockIdx.x * 64;
    const int col0 = blockIdx.y * 64;

    const int sr = t & 63;          // staging row (A) / col (W)
    const int sk = (t >> 6) << 4;   // staging k base: 0,16,32,48

    float acc[4][4];
#pragma unroll
    for (int r = 0; r < 4; ++r)
#pragma unroll
        for (int c = 0; c < 4; ++c) acc[r][c] = 0.f;

    for (int kc = 0; kc < 2; ++kc) {
        const int k0 = kc * 64;
        {
            const int grow = row0 + sr;
            float4 v0, v1, v2, v3;
            if (grow < nrows) {
                const float* ap = A + (size_t)grow * HD + k0 + sk;
                v0 = *(const float4*)(ap + 0);
                v1 = *(const float4*)(ap + 4);
                v2 = *(const float4*)(ap + 8);
                v3 = *(const float4*)(ap + 12);
            } else {
                v0 = v1 = v2 = v3 = make_float4(0.f, 0.f, 0.f, 0.f);
            }
            Alds[sk + 0][sr] = v0.x;  Alds[sk + 1][sr] = v0.y;
            Alds[sk + 2][sr] = v0.z;  Alds[sk + 3][sr] = v0.w;
            Alds[sk + 4][sr] = v1.x;  Alds[sk + 5][sr] = v1.y;
            Alds[sk + 6][sr] = v1.z;  Alds[sk + 7][sr] = v1.w;
            Alds[sk + 8][sr] = v2.x;  Alds[sk + 9][sr] = v2.y;
            Alds[sk + 10][sr] = v2.z; Alds[sk + 11][sr] = v2.w;
            Alds[sk + 12][sr] = v3.x; Alds[sk + 13][sr] = v3.y;
            Alds[sk + 14][sr] = v3.z; Alds[sk + 15][sr] = v3.w;
        }
        {
            const float* wp = W + (size_t)(col0 + sr) * HD + k0 + sk;
            float4 v0 = *(const float4*)(wp + 0);
            float4 v1 = *(const float4*)(wp + 4);
            float4 v2 = *(const float4*)(wp + 8);
            float4 v3 = *(const float4*)(wp + 12);
            Wlds[sk + 0][sr] = v0.x;  Wlds[sk + 1][sr] = v0.y;
            Wlds[sk + 2][sr] = v0.z;  Wlds[sk + 3][sr] = v0.w;
            Wlds[sk + 4][sr] = v1.x;  Wlds[sk + 5][sr] = v1.y;
            Wlds[sk + 6][sr] = v1.z;  Wlds[sk + 7][sr] = v1.w;
            Wlds[sk + 8][sr] = v2.x;  Wlds[sk + 9][sr] = v2.y;
            Wlds[sk + 10][sr] = v2.z; Wlds[sk + 11][sr] = v2.w;
            Wlds[sk + 12][sr] = v3.x; Wlds[sk + 13][sr] = v3.y;
            Wlds[sk + 14][sr] = v3.z; Wlds[sk + 15][sr] = v3.w;
        }
        __syncthreads();

#pragma unroll 8
        for (int k = 0; k < 64; ++k) {
            float4 av = *(const float4*)(&Alds[k][ty * 4]);
            float4 wv = *(const float4*)(&Wlds[k][tx * 4]);
            acc[0][0] = fmaf(av.x, wv.x, acc[0][0]);
            acc[0][1] = fmaf(av.x, wv.y, acc[0][1]);
            acc[0][2] = fmaf(av.x, wv.z, acc[0][2]);
            acc[0][3] = fmaf(av.x, wv.w, acc[0][3]);
            acc[1][0] = fmaf(av.y, wv.x, acc[1][0]);
            acc[1][1] = fmaf(av.y, wv.y, acc[1][1]);
            acc[1][2] = fmaf(av.y, wv.z, acc[1][2]);
            acc[1][3] = fmaf(av.y, wv.w, acc[1][3]);
            acc[2][0] = fmaf(av.z, wv.x, acc[2][0]);
            acc[2][1] = fmaf(av.z, wv.y, acc[2][1]);
            acc[2][2] = fmaf(av.z, wv.z, acc[2][2]);
            acc[2][3] = fmaf(av.z, wv.w, acc[2][3]);
            acc[3][0] = fmaf(av.w, wv.x, acc[3][0]);
            acc[3][1] = fmaf(av.w, wv.y, acc[3][1]);
            acc[3][2] = fmaf(av.w, wv.z, acc[3][2]);
            acc[3][3] = fmaf(av.w, wv.w, acc[3][3]);
        }
        __syncthreads();
    }

    float4 bv = *(const float4*)(bias + col0 + tx * 4);
#pragma unroll
    for (int r = 0; r < 4; ++r) {
        const int row = row0 + ty * 4 + r;
        if (row < nrows) {
            float4 o;
            o.x = acc[r][0] + bv.x;
            o.y = acc[r][1] + bv.y;
            o.z = acc[r][2] + bv.z;
            o.w = acc[r][3] + bv.w;
            if (RELU) {
                o.x = fmaxf(o.x, 0.f); o.y = fmaxf(o.y, 0.f);
                o.z = fmaxf(o.z, 0.f); o.w = fmaxf(o.w, 0.f);
            }
            *(float4*)(C + (size_t)row * HD + col0 + tx * 4) = o;
        }
    }
}

// ---------------- BatchNorm ----------------

__global__ void bn_stats_kernel(const float* __restrict__ y, float* __restrict__ stats, int n) {
    __shared__ float redS[256], redQ[256];
    const int tx = threadIdx.x;
    const int c = tx & 127;
    const int half = tx >> 7;
    float s = 0.f, ss = 0.f;
    for (int row = blockIdx.x * 2 + half; row < n; row += gridDim.x * 2) {
        float v = y[(size_t)row * HD + c];
        s += v;
        ss = fmaf(v, v, ss);
    }
    redS[tx] = s;
    redQ[tx] = ss;
    __syncthreads();
    if (tx < 128) {
        atomicAdd(&stats[tx], redS[tx] + redS[tx + 128]);
        atomicAdd(&stats[128 + tx], redQ[tx] + redQ[tx + 128]);
    }
}

__global__ void bn_apply_kernel(float* __restrict__ y, const float* __restrict__ stats,
                                const float* __restrict__ gam, const float* __restrict__ bet,
                                int n) {
    int idx = blockIdx.x * blockDim.x + threadIdx.x;  // float4 index
    int total = n * (HD / 4);
    if (idx >= total) return;
    const int c = (idx & 31) * 4;
    const float invn = 1.0f / (float)n;
    float4 v = *(float4*)(y + (size_t)idx * 4);
    float r[4] = {v.x, v.y, v.z, v.w};
#pragma unroll
    for (int j = 0; j < 4; ++j) {
        float mu = stats[c + j] * invn;
        float var = stats[128 + c + j] * invn - mu * mu;
        float sc = gam[c + j] * rsqrtf(var + BN_EPS);
        float sh = bet[c + j] - mu * sc;
        r[j] = fmaxf(fmaf(r[j], sc, sh), 0.0f);
    }
    *(float4*)(y + (size_t)idx * 4) = make_float4(r[0], r[1], r[2], r[3]);
}

// ---------------- mean pool per graph (batch sorted), 512 threads ----------------

__global__ void pool_kernel(const float* __restrict__ h, const int* __restrict__ gstart,
                            float* __restrict__ pooled, int layerOff) {
    __shared__ float red[4][HD];
    const int g = blockIdx.x;
    const int tx = threadIdx.x;   // 512
    const int c = tx & 127;
    const int q = tx >> 7;        // 0..3
    int s0 = gstart[g], s1 = gstart[g + 1];
    float acc = 0.f;
    for (int i = s0 + q; i < s1; i += 4) acc += h[(size_t)i * HD + c];
    red[q][c] = acc;
    __syncthreads();
    if (q == 0) {
        float s = red[0][c] + red[1][c] + red[2][c] + red[3][c];
        int cnt = s1 - s0;
        float fc = (cnt > 0) ? (float)cnt : 1.0f;
        pooled[(size_t)g * (3 * HD) + layerOff + c] = s / fc;
    }
}

// ---------------- final linear + row L2 normalize ----------------

__global__ void final_kernel(const float* __restrict__ pooled, const float* __restrict__ linW,
                             const float* __restrict__ linb, float* __restrict__ out) {
    __shared__ float p[3 * HD];
    const int g = blockIdx.x;
    const int o = threadIdx.x;  // 64 threads = 1 wave
    for (int k = o; k < 3 * HD; k += 64) p[k] = pooled[(size_t)g * (3 * HD) + k];
    __syncthreads();
    float acc = linb[o];
    const float* wrow = linW + (size_t)o * (3 * HD);
#pragma unroll 4
    for (int k = 0; k < 3 * HD; k += 4) {
        float4 w = *(const float4*)(wrow + k);
        float4 pv = *(const float4*)(&p[k]);
        acc = fmaf(w.x, pv.x, acc);
        acc = fmaf(w.y, pv.y, acc);
        acc = fmaf(w.z, pv.z, acc);
        acc = fmaf(w.w, pv.w, acc);
    }
    float sq = acc * acc;
#pragma unroll
    for (int off = 32; off > 0; off >>= 1) sq += __shfl_xor(sq, off);
    float nrm = sqrtf(sq);
    nrm = fmaxf(nrm, 1e-12f);
    out[(size_t)g * OD + o] = acc / nrm;
}

// ---------------- launch ----------------

extern "C" void kernel_launch(void* const* d_in, const int* in_sizes, int n_in,
                              void* d_out, int out_size, void* d_ws, size_t ws_size,
                              hipStream_t stream) {
    const float* x    = (const float*)d_in[0];
    const int* ei     = (const int*)d_in[1];
    const int* batch  = (const int*)d_in[2];
    const float* W11  = (const float*)d_in[3];
    const float* b11  = (const float*)d_in[4];
    const float* W12  = (const float*)d_in[5];
    const float* b12  = (const float*)d_in[6];
    const float* g1   = (const float*)d_in[7];
    const float* be1  = (const float*)d_in[8];
    const float* W21  = (const float*)d_in[9];
    const float* b21  = (const float*)d_in[10];
    const float* W22  = (const float*)d_in[11];
    const float* b22  = (const float*)d_in[12];
    const float* g2   = (const float*)d_in[13];
    const float* be2  = (const float*)d_in[14];
    const float* W31  = (const float*)d_in[15];
    const float* b31  = (const float*)d_in[16];
    const float* W32  = (const float*)d_in[17];
    const float* b32  = (const float*)d_in[18];
    const float* g3   = (const float*)d_in[19];
    const float* be3  = (const float*)d_in[20];
    const float* linW = (const float*)d_in[21];
    const float* linb = (const float*)d_in[22];

    const int* src = ei;
    const int* dst = ei + NE;

    char* ws = (char*)d_ws;
    size_t off = 0;
    auto alloc = [&](size_t bytes) -> void* {
        void* p = ws + off;
        off += (bytes + 255) & ~(size_t)255;
        return p;
    };
    int* deg      = (int*)alloc((size_t)NN * 4);
    int* offsets  = (int*)alloc((size_t)(NN + 1) * 4);
    int* cursor   = (int*)alloc((size_t)NN * 4);
    int* srcs     = (int*)alloc((size_t)NE * 4);
    int* gstart   = (int*)alloc((size_t)(NG + 1) * 4);
    int* lexcl    = (int*)alloc((size_t)NN * 4);
    int* bsum     = (int*)alloc((size_t)NSB * 4);
    int* boff     = (int*)alloc((size_t)NSB * 4);
    float* stats  = (float*)alloc(512 * 4);
    float* pooled = (float*)alloc((size_t)NG * 3 * HD * 4);
    float* bufA   = (float*)alloc((size_t)NN * HD * 4);
    float* bufB   = (float*)alloc((size_t)NN * HD * 4);
    float* bufC   = (float*)alloc((size_t)NN * HD * 4);
    (void)ws_size; (void)n_in; (void)in_sizes; (void)out_size;

    // CSR build
    hipMemsetAsync(deg, 0, (size_t)NN * 4, stream);
    hist_kernel<<<(NE + 255) / 256, 256, 0, stream>>>(dst, deg, NE);
    local_scan_kernel<<<NSB, SCAN_BLK, 0, stream>>>(deg, lexcl, bsum, NN);
    scan_bsum_kernel<<<1, 64, 0, stream>>>(bsum, boff, offsets, NSB, NN);
    finalize_scan_kernel<<<(NN + 255) / 256, 256, 0, stream>>>(lexcl, boff, offsets, cursor, NN);
    fill_kernel<<<(NE + 255) / 256, 256, 0, stream>>>(src, dst, cursor, srcs, NE);
    gstart_kernel<<<(NN + 255) / 256, 256, 0, stream>>>(batch, gstart, NN, NG);

    const dim3 gemmGrid((NN + 63) / 64, 2);

    auto layer = [&](const float* hin, float* zbuf, float* tbuf,
                     const float* Wa, const float* ba, const float* Wb, const float* bb,
                     const float* gg, const float* bee, int layerOff) {
        agg_kernel<<<(NN + 3) / 4, 256, 0, stream>>>(hin, offsets, srcs, zbuf, NN);
        gemm64<true><<<gemmGrid, 256, 0, stream>>>(zbuf, Wa, ba, tbuf, NN);
        gemm64<false><<<gemmGrid, 256, 0, stream>>>(tbuf, Wb, bb, zbuf, NN);
        hipMemsetAsync(stats, 0, 256 * 4, stream);
        bn_stats_kernel<<<256, 256, 0, stream>>>(zbuf, stats, NN);
        bn_apply_kernel<<<(NN * (HD / 4) + 255) / 256, 256, 0, stream>>>(zbuf, stats, gg, bee, NN);
        pool_kernel<<<NG, 512, 0, stream>>>(zbuf, gstart, pooled, layerOff);
    };

    layer(x, bufA, bufB, W11, b11, W12, b12, g1, be1, 0);
    layer(bufA, bufB, bufC, W21, b21, W22, b22, g2, be2, HD);
    layer(bufB, bufA, bufC, W31, b31, W32, b32, g3, be3, 2 * HD);

    final_kernel<<<NG, OD, 0, stream>>>(pooled, linW, linb, (float*)d_out);
}

// Round 4
// 541.856 us; speedup vs baseline: 8.6734x; 1.1281x over previous
//
#include <hip/hip_runtime.h>

#define NN 50000
#define NE 600000
#define HD 128
#define NG 512
#define OD 64
#define BN_EPS 1e-5f

#define SCAN_BLK 1024
#define NSB ((NN + SCAN_BLK - 1) / SCAN_BLK)  // 49

typedef __attribute__((ext_vector_type(8))) short bf16x8;
typedef __attribute__((ext_vector_type(4))) float f32x4;
typedef __attribute__((ext_vector_type(4))) short short4v;

__device__ __forceinline__ short f2bf(float f) {
    unsigned u = __builtin_bit_cast(unsigned, f);
    unsigned r = u + 0x7FFFu + ((u >> 16) & 1u);  // round-to-nearest-even
    return (short)(r >> 16);
}

// ---------------- CSR build ----------------

__global__ void hist_kernel(const int* __restrict__ dst, int* __restrict__ deg, int E) {
    int i = blockIdx.x * blockDim.x + threadIdx.x;
    if (i < E) atomicAdd(&deg[dst[i]], 1);
}

__global__ void local_scan_kernel(const int* __restrict__ deg, int* __restrict__ lexcl,
                                  int* __restrict__ bsum, int n) {
    __shared__ int part[SCAN_BLK];
    const int tid = threadIdx.x;
    const int i = blockIdx.x * SCAN_BLK + tid;
    int v = (i < n) ? deg[i] : 0;
    part[tid] = v;
    __syncthreads();
    int incl = v;
    for (int off = 1; off < SCAN_BLK; off <<= 1) {
        int t = (tid >= off) ? part[tid - off] : 0;
        __syncthreads();
        incl += t;
        part[tid] = incl;
        __syncthreads();
    }
    if (i < n) lexcl[i] = incl - v;
    if (tid == SCAN_BLK - 1) bsum[blockIdx.x] = incl;
}

__global__ void scan_bsum_kernel(const int* __restrict__ bsum, int* __restrict__ boff,
                                 int* __restrict__ offsets, int nb, int n) {
    const int tid = threadIdx.x;  // 64 threads
    int orig = (tid < nb) ? bsum[tid] : 0;
    int v = orig;
    for (int off = 1; off < 64; off <<= 1) {
        int t = __shfl_up(v, off);
        if (tid >= off) v += t;
    }
    if (tid < nb) boff[tid] = v - orig;
    if (tid == 63) offsets[n] = v;  // total = E
}

__global__ void finalize_scan_kernel(const int* __restrict__ lexcl, const int* __restrict__ boff,
                                     int* __restrict__ offsets, int* __restrict__ cursor, int n) {
    int i = blockIdx.x * blockDim.x + threadIdx.x;
    if (i < n) {
        int o = lexcl[i] + boff[i >> 10];
        offsets[i] = o;
        cursor[i] = o;
    }
}

__global__ void fill_kernel(const int* __restrict__ src, const int* __restrict__ dst,
                            int* __restrict__ cursor, int* __restrict__ srcs, int E) {
    int i = blockIdx.x * blockDim.x + threadIdx.x;
    if (i < E) {
        int pos = atomicAdd(&cursor[dst[i]], 1);
        srcs[pos] = src[i];
    }
}

__global__ void gstart_kernel(const int* __restrict__ batch, int* __restrict__ gstart,
                              int n, int G) {
    int i = blockIdx.x * blockDim.x + threadIdx.x;
    if (i >= n) return;
    int b = batch[i];
    int bp = (i == 0) ? -1 : batch[i - 1];
    for (int g = bp + 1; g <= b; ++g) gstart[g] = i;
    if (i == n - 1) {
        for (int g = b + 1; g <= G; ++g) gstart[g] = n;
    }
}

// ---------------- GIN aggregation ----------------

__global__ void agg_kernel(const float* __restrict__ h, const int* __restrict__ offsets,
                           const int* __restrict__ srcs, float* __restrict__ z, int n) {
    int node = blockIdx.x * 4 + (threadIdx.x >> 6);
    int lane = threadIdx.x & 63;
    if (node >= n) return;
    const float2* hr = (const float2*)(h + (size_t)node * HD);
    float2 acc = hr[lane];
    int e0 = offsets[node], e1 = offsets[node + 1];
    for (int j = e0; j < e1; ++j) {
        int s = srcs[j];
        float2 v = ((const float2*)(h + (size_t)s * HD))[lane];
        acc.x += v.x;
        acc.y += v.y;
    }
    ((float2*)(z + (size_t)node * HD))[lane] = acc;
}

// ---------------- fused GIN MLP: C = relu(A@Wa^T+ba)@Wb^T + bb  (bf16 MFMA) -------
// 64 rows/block, full 128-wide. 4 waves in 2x2; in-place A==C safe (own rows only).

__global__ __launch_bounds__(256) void fused_mlp(const float* __restrict__ A,
                                                 const float* __restrict__ Wa,
                                                 const float* __restrict__ ba,
                                                 const float* __restrict__ Wb,
                                                 const float* __restrict__ bb,
                                                 float* __restrict__ C, int nrows) {
    __shared__ short Albuf[64 * 136];
    __shared__ short Wbuf[128 * 136];
    __shared__ short A2buf[64 * 136];

    const int t = threadIdx.x;
    const int row0 = blockIdx.x * 64;
    const int lane = t & 63;
    const int w = t >> 6;      // wave 0..3
    const int wr = w >> 1;     // row half
    const int wc = w & 1;      // col half
    const int l15 = lane & 15;
    const int l4 = lane >> 4;  // 0..3

    // stage A (fp32 -> bf16), rows t>>2, col chunk (t&3)*32
    {
        const int r = t >> 2;
        const int cb = (t & 3) * 32;
        const int grow = row0 + r;
        short* dstp = &Albuf[r * 136 + cb];
        if (grow < nrows) {
            const float* srcp = A + (size_t)grow * HD + cb;
#pragma unroll
            for (int i = 0; i < 8; ++i) {
                float4 v = *(const float4*)(srcp + i * 4);
                short4v s = {f2bf(v.x), f2bf(v.y), f2bf(v.z), f2bf(v.w)};
                *(short4v*)(dstp + i * 4) = s;
            }
        } else {
            short4v zz = {0, 0, 0, 0};
#pragma unroll
            for (int i = 0; i < 8; ++i) *(short4v*)(dstp + i * 4) = zz;
        }
    }
    // stage Wa (fp32 -> bf16), rows t>>1, col chunk (t&1)*64
    {
        const int r = t >> 1;
        const int cb = (t & 1) * 64;
        const float* srcp = Wa + (size_t)r * HD + cb;
        short* dstp = &Wbuf[r * 136 + cb];
#pragma unroll
        for (int i = 0; i < 16; ++i) {
            float4 v = *(const float4*)(srcp + i * 4);
            short4v s = {f2bf(v.x), f2bf(v.y), f2bf(v.z), f2bf(v.w)};
            *(short4v*)(dstp + i * 4) = s;
        }
    }
    __syncthreads();

    // MFMA pass 1: t = A @ Wa^T
    f32x4 acc[2][4];
#pragma unroll
    for (int m = 0; m < 2; ++m)
#pragma unroll
        for (int n = 0; n < 4; ++n) acc[m][n] = (f32x4){0.f, 0.f, 0.f, 0.f};

#pragma unroll
    for (int kk = 0; kk < 4; ++kk) {
        bf16x8 af[2], bfr[4];
#pragma unroll
        for (int m = 0; m < 2; ++m)
            af[m] = *(const bf16x8*)&Albuf[(wr * 32 + m * 16 + l15) * 136 + kk * 32 + l4 * 8];
#pragma unroll
        for (int n = 0; n < 4; ++n)
            bfr[n] = *(const bf16x8*)&Wbuf[(wc * 64 + n * 16 + l15) * 136 + kk * 32 + l4 * 8];
#pragma unroll
        for (int m = 0; m < 2; ++m)
#pragma unroll
            for (int n = 0; n < 4; ++n)
                acc[m][n] = __builtin_amdgcn_mfma_f32_16x16x32_bf16(af[m], bfr[n], acc[m][n], 0, 0, 0);
    }

    // epilogue 1: relu(t + ba) -> A2 (bf16)
#pragma unroll
    for (int n = 0; n < 4; ++n) {
        const int col = wc * 64 + n * 16 + l15;
        const float bav = ba[col];
#pragma unroll
        for (int m = 0; m < 2; ++m) {
#pragma unroll
            for (int j = 0; j < 4; ++j) {
                const int row = wr * 32 + m * 16 + l4 * 4 + j;
                float v = fmaxf(acc[m][n][j] + bav, 0.f);
                A2buf[row * 136 + col] = f2bf(v);
            }
        }
    }
    __syncthreads();  // all waves done reading Wa & writing A2

    // stage Wb over W buffer
    {
        const int r = t >> 1;
        const int cb = (t & 1) * 64;
        const float* srcp = Wb + (size_t)r * HD + cb;
        short* dstp = &Wbuf[r * 136 + cb];
#pragma unroll
        for (int i = 0; i < 16; ++i) {
            float4 v = *(const float4*)(srcp + i * 4);
            short4v s = {f2bf(v.x), f2bf(v.y), f2bf(v.z), f2bf(v.w)};
            *(short4v*)(dstp + i * 4) = s;
        }
    }
    __syncthreads();

    // MFMA pass 2: C = A2 @ Wb^T
#pragma unroll
    for (int m = 0; m < 2; ++m)
#pragma unroll
        for (int n = 0; n < 4; ++n) acc[m][n] = (f32x4){0.f, 0.f, 0.f, 0.f};

#pragma unroll
    for (int kk = 0; kk < 4; ++kk) {
        bf16x8 af[2], bfr[4];
#pragma unroll
        for (int m = 0; m < 2; ++m)
            af[m] = *(const bf16x8*)&A2buf[(wr * 32 + m * 16 + l15) * 136 + kk * 32 + l4 * 8];
#pragma unroll
        for (int n = 0; n < 4; ++n)
            bfr[n] = *(const bf16x8*)&Wbuf[(wc * 64 + n * 16 + l15) * 136 + kk * 32 + l4 * 8];
#pragma unroll
        for (int m = 0; m < 2; ++m)
#pragma unroll
            for (int n = 0; n < 4; ++n)
                acc[m][n] = __builtin_amdgcn_mfma_f32_16x16x32_bf16(af[m], bfr[n], acc[m][n], 0, 0, 0);
    }

    // epilogue 2: C = acc + bb (fp32 store)
#pragma unroll
    for (int n = 0; n < 4; ++n) {
        const int col = wc * 64 + n * 16 + l15;
        const float bbv = bb[col];
#pragma unroll
        for (int m = 0; m < 2; ++m) {
#pragma unroll
            for (int j = 0; j < 4; ++j) {
                const int row = row0 + wr * 32 + m * 16 + l4 * 4 + j;
                if (row < nrows) C[(size_t)row * HD + col] = acc[m][n][j] + bbv;
            }
        }
    }
}

// ---------------- BatchNorm ----------------

__global__ void bn_stats_kernel(const float* __restrict__ y, float* __restrict__ stats, int n) {
    __shared__ float redS[256], redQ[256];
    const int tx = threadIdx.x;
    const int c = tx & 127;
    const int half = tx >> 7;
    float s = 0.f, ss = 0.f;
    for (int row = blockIdx.x * 2 + half; row < n; row += gridDim.x * 2) {
        float v = y[(size_t)row * HD + c];
        s += v;
        ss = fmaf(v, v, ss);
    }
    redS[tx] = s;
    redQ[tx] = ss;
    __syncthreads();
    if (tx < 128) {
        atomicAdd(&stats[tx], redS[tx] + redS[tx + 128]);
        atomicAdd(&stats[128 + tx], redQ[tx] + redQ[tx + 128]);
    }
}

__global__ void bn_apply_kernel(float* __restrict__ y, const float* __restrict__ stats,
                                const float* __restrict__ gam, const float* __restrict__ bet,
                                int n) {
    int idx = blockIdx.x * blockDim.x + threadIdx.x;  // float4 index
    int total = n * (HD / 4);
    if (idx >= total) return;
    const int c = (idx & 31) * 4;
    const float invn = 1.0f / (float)n;
    float4 v = *(float4*)(y + (size_t)idx * 4);
    float r[4] = {v.x, v.y, v.z, v.w};
#pragma unroll
    for (int j = 0; j < 4; ++j) {
        float mu = stats[c + j] * invn;
        float var = stats[128 + c + j] * invn - mu * mu;
        float sc = gam[c + j] * rsqrtf(var + BN_EPS);
        float sh = bet[c + j] - mu * sc;
        r[j] = fmaxf(fmaf(r[j], sc, sh), 0.0f);
    }
    *(float4*)(y + (size_t)idx * 4) = make_float4(r[0], r[1], r[2], r[3]);
}

// ---------------- mean pool per graph ----------------

__global__ void pool_kernel(const float* __restrict__ h, const int* __restrict__ gstart,
                            float* __restrict__ pooled, int layerOff) {
    __shared__ float red[4][HD];
    const int g = blockIdx.x;
    const int tx = threadIdx.x;   // 512
    const int c = tx & 127;
    const int q = tx >> 7;        // 0..3
    int s0 = gstart[g], s1 = gstart[g + 1];
    float acc = 0.f;
    for (int i = s0 + q; i < s1; i += 4) acc += h[(size_t)i * HD + c];
    red[q][c] = acc;
    __syncthreads();
    if (q == 0) {
        float s = red[0][c] + red[1][c] + red[2][c] + red[3][c];
        int cnt = s1 - s0;
        float fc = (cnt > 0) ? (float)cnt : 1.0f;
        pooled[(size_t)g * (3 * HD) + layerOff + c] = s / fc;
    }
}

// ---------------- final linear + row L2 normalize ----------------

__global__ void final_kernel(const float* __restrict__ pooled, const float* __restrict__ linW,
                             const float* __restrict__ linb, float* __restrict__ out) {
    __shared__ float p[3 * HD];
    const int g = blockIdx.x;
    const int o = threadIdx.x;  // 64 threads = 1 wave
    for (int k = o; k < 3 * HD; k += 64) p[k] = pooled[(size_t)g * (3 * HD) + k];
    __syncthreads();
    float acc = linb[o];
    const float* wrow = linW + (size_t)o * (3 * HD);
#pragma unroll 4
    for (int k = 0; k < 3 * HD; k += 4) {
        float4 wv = *(const float4*)(wrow + k);
        float4 pv = *(const float4*)(&p[k]);
        acc = fmaf(wv.x, pv.x, acc);
        acc = fmaf(wv.y, pv.y, acc);
        acc = fmaf(wv.z, pv.z, acc);
        acc = fmaf(wv.w, pv.w, acc);
    }
    float sq = acc * acc;
#pragma unroll
    for (int off = 32; off > 0; off >>= 1) sq += __shfl_xor(sq, off);
    float nrm = sqrtf(sq);
    nrm = fmaxf(nrm, 1e-12f);
    out[(size_t)g * OD + o] = acc / nrm;
}

// ---------------- launch ----------------

extern "C" void kernel_launch(void* const* d_in, const int* in_sizes, int n_in,
                              void* d_out, int out_size, void* d_ws, size_t ws_size,
                              hipStream_t stream) {
    const float* x    = (const float*)d_in[0];
    const int* ei     = (const int*)d_in[1];
    const int* batch  = (const int*)d_in[2];
    const float* W11  = (const float*)d_in[3];
    const float* b11  = (const float*)d_in[4];
    const float* W12  = (const float*)d_in[5];
    const float* b12  = (const float*)d_in[6];
    const float* g1   = (const float*)d_in[7];
    const float* be1  = (const float*)d_in[8];
    const float* W21  = (const float*)d_in[9];
    const float* b21  = (const float*)d_in[10];
    const float* W22  = (const float*)d_in[11];
    const float* b22  = (const float*)d_in[12];
    const float* g2   = (const float*)d_in[13];
    const float* be2  = (const float*)d_in[14];
    const float* W31  = (const float*)d_in[15];
    const float* b31  = (const float*)d_in[16];
    const float* W32  = (const float*)d_in[17];
    const float* b32  = (const float*)d_in[18];
    const float* g3   = (const float*)d_in[19];
    const float* be3  = (const float*)d_in[20];
    const float* linW = (const float*)d_in[21];
    const float* linb = (const float*)d_in[22];

    const int* src = ei;
    const int* dst = ei + NE;

    char* ws = (char*)d_ws;
    size_t off = 0;
    auto alloc = [&](size_t bytes) -> void* {
        void* p = ws + off;
        off += (bytes + 255) & ~(size_t)255;
        return p;
    };
    int* deg      = (int*)alloc((size_t)NN * 4);
    int* offsets  = (int*)alloc((size_t)(NN + 1) * 4);
    int* cursor   = (int*)alloc((size_t)NN * 4);
    int* srcs     = (int*)alloc((size_t)NE * 4);
    int* gstart   = (int*)alloc((size_t)(NG + 1) * 4);
    int* lexcl    = (int*)alloc((size_t)NN * 4);
    int* bsum     = (int*)alloc((size_t)NSB * 4);
    int* boff     = (int*)alloc((size_t)NSB * 4);
    float* stats  = (float*)alloc(512 * 4);
    float* pooled = (float*)alloc((size_t)NG * 3 * HD * 4);
    float* bufA   = (float*)alloc((size_t)NN * HD * 4);
    float* bufB   = (float*)alloc((size_t)NN * HD * 4);
    (void)ws_size; (void)n_in; (void)in_sizes; (void)out_size;

    // CSR build
    hipMemsetAsync(deg, 0, (size_t)NN * 4, stream);
    hist_kernel<<<(NE + 255) / 256, 256, 0, stream>>>(dst, deg, NE);
    local_scan_kernel<<<NSB, SCAN_BLK, 0, stream>>>(deg, lexcl, bsum, NN);
    scan_bsum_kernel<<<1, 64, 0, stream>>>(bsum, boff, offsets, NSB, NN);
    finalize_scan_kernel<<<(NN + 255) / 256, 256, 0, stream>>>(lexcl, boff, offsets, cursor, NN);
    fill_kernel<<<(NE + 255) / 256, 256, 0, stream>>>(src, dst, cursor, srcs, NE);
    gstart_kernel<<<(NN + 255) / 256, 256, 0, stream>>>(batch, gstart, NN, NG);

    const int mlpGrid = (NN + 63) / 64;  // 782

    auto layer = [&](const float* hin, float* zbuf,
                     const float* Wa, const float* ba, const float* Wb, const float* bb,
                     const float* gg, const float* bee, int layerOff) {
        agg_kernel<<<(NN + 3) / 4, 256, 0, stream>>>(hin, offsets, srcs, zbuf, NN);
        fused_mlp<<<mlpGrid, 256, 0, stream>>>(zbuf, Wa, ba, Wb, bb, zbuf, NN);
        hipMemsetAsync(stats, 0, 256 * 4, stream);
        bn_stats_kernel<<<256, 256, 0, stream>>>(zbuf, stats, NN);
        bn_apply_kernel<<<(NN * (HD / 4) + 255) / 256, 256, 0, stream>>>(zbuf, stats, gg, bee, NN);
        pool_kernel<<<NG, 512, 0, stream>>>(zbuf, gstart, pooled, layerOff);
    };

    layer(x, bufA, W11, b11, W12, b12, g1, be1, 0);       // h1 in bufA
    layer(bufA, bufB, W21, b21, W22, b22, g2, be2, HD);   // h2 in bufB
    layer(bufB, bufA, W31, b31, W32, b32, g3, be3, 2 * HD); // h3 in bufA

    final_kernel<<<NG, OD, 0, stream>>>(pooled, linW, linb, (float*)d_out);
}

// Round 5
// 535.633 us; speedup vs baseline: 8.7742x; 1.0116x over previous
//
#include <hip/hip_runtime.h>

#define NN 50000
#define NE 600000
#define HD 128
#define NG 512
#define OD 64
#define BN_EPS 1e-5f

#define SCAN_BLK 1024
#define NSB ((NN + SCAN_BLK - 1) / SCAN_BLK)  // 49

typedef __attribute__((ext_vector_type(8))) short bf16x8;
typedef __attribute__((ext_vector_type(4))) float f32x4;

__device__ __forceinline__ unsigned short f2bf(float f) {
    unsigned u = __builtin_bit_cast(unsigned, f);
    unsigned r = u + 0x7FFFu + ((u >> 16) & 1u);  // round-to-nearest-even
    return (unsigned short)(r >> 16);
}

__device__ __forceinline__ float bfbits2f(unsigned b) {
    return __builtin_bit_cast(float, b << 16);
}

__device__ __forceinline__ unsigned packbf2(float x, float y) {
    return (unsigned)f2bf(x) | ((unsigned)f2bf(y) << 16);
}

// ---------------- fp32 -> bf16 bulk convert (8 elems/thread) ----------------

__global__ void cvt_kernel(const float* __restrict__ src, unsigned short* __restrict__ dst, int n8) {
    int i = blockIdx.x * blockDim.x + threadIdx.x;
    if (i >= n8) return;
    float4 a = ((const float4*)src)[2 * i];
    float4 b = ((const float4*)src)[2 * i + 1];
    uint4 o;
    o.x = packbf2(a.x, a.y);
    o.y = packbf2(a.z, a.w);
    o.z = packbf2(b.x, b.y);
    o.w = packbf2(b.z, b.w);
    ((uint4*)dst)[i] = o;
}

// ---------------- CSR build ----------------

__global__ void hist_kernel(const int* __restrict__ dst, int* __restrict__ deg, int E) {
    int i = blockIdx.x * blockDim.x + threadIdx.x;
    if (i < E) atomicAdd(&deg[dst[i]], 1);
}

__global__ void local_scan_kernel(const int* __restrict__ deg, int* __restrict__ lexcl,
                                  int* __restrict__ bsum, int n) {
    __shared__ int part[SCAN_BLK];
    const int tid = threadIdx.x;
    const int i = blockIdx.x * SCAN_BLK + tid;
    int v = (i < n) ? deg[i] : 0;
    part[tid] = v;
    __syncthreads();
    int incl = v;
    for (int off = 1; off < SCAN_BLK; off <<= 1) {
        int t = (tid >= off) ? part[tid - off] : 0;
        __syncthreads();
        incl += t;
        part[tid] = incl;
        __syncthreads();
    }
    if (i < n) lexcl[i] = incl - v;
    if (tid == SCAN_BLK - 1) bsum[blockIdx.x] = incl;
}

__global__ void scan_bsum_kernel(const int* __restrict__ bsum, int* __restrict__ boff,
                                 int* __restrict__ offsets, int nb, int n) {
    const int tid = threadIdx.x;  // 64 threads
    int orig = (tid < nb) ? bsum[tid] : 0;
    int v = orig;
    for (int off = 1; off < 64; off <<= 1) {
        int t = __shfl_up(v, off);
        if (tid >= off) v += t;
    }
    if (tid < nb) boff[tid] = v - orig;
    if (tid == 63) offsets[n] = v;  // total = E
}

__global__ void finalize_scan_kernel(const int* __restrict__ lexcl, const int* __restrict__ boff,
                                     int* __restrict__ offsets, int* __restrict__ cursor, int n) {
    int i = blockIdx.x * blockDim.x + threadIdx.x;
    if (i < n) {
        int o = lexcl[i] + boff[i >> 10];
        offsets[i] = o;
        cursor[i] = o;
    }
}

__global__ void fill_kernel(const int* __restrict__ src, const int* __restrict__ dst,
                            int* __restrict__ cursor, int* __restrict__ srcs, int E) {
    int i = blockIdx.x * blockDim.x + threadIdx.x;
    if (i < E) {
        int pos = atomicAdd(&cursor[dst[i]], 1);
        srcs[pos] = src[i];
    }
}

__global__ void gstart_kernel(const int* __restrict__ batch, int* __restrict__ gstart,
                              int n, int G) {
    int i = blockIdx.x * blockDim.x + threadIdx.x;
    if (i >= n) return;
    int b = batch[i];
    int bp = (i == 0) ? -1 : batch[i - 1];
    for (int g = bp + 1; g <= b; ++g) gstart[g] = i;
    if (i == n - 1) {
        for (int g = b + 1; g <= G; ++g) gstart[g] = n;
    }
}

// ---------------- fused GIN layer: gather + MLP (bf16 MFMA) ----------------
// C = relu((h + sum_nbr h) @ Wa^T + ba) @ Wb^T + bb
// 64 rows/block, 4 waves; gather reads bf16 h; W read from global bf16.

__global__ __launch_bounds__(256) void fused_gin(const unsigned short* __restrict__ Hbf,
                                                 const int* __restrict__ offsets,
                                                 const int* __restrict__ srcs,
                                                 const unsigned short* __restrict__ WaBf,
                                                 const float* __restrict__ ba,
                                                 const unsigned short* __restrict__ WbBf,
                                                 const float* __restrict__ bb,
                                                 float* __restrict__ C, int nrows) {
    __shared__ short Albuf[64 * 136];
    __shared__ short A2buf[64 * 136];

    const int t = threadIdx.x;
    const int lane = t & 63;
    const int w = t >> 6;      // wave 0..3
    const int row0 = blockIdx.x * 64;
    const unsigned* hp = (const unsigned*)Hbf;  // 2 bf16 per unsigned, 64 per row

    // ---- gather phase: wave w owns rows w*16 .. w*16+15
    for (int i = 0; i < 16; ++i) {
        const int r = w * 16 + i;
        const int grow = row0 + r;
        float ax = 0.f, ay = 0.f;
        if (grow < nrows) {
            unsigned u = hp[(size_t)grow * 64 + lane];
            ax = bfbits2f(u & 0xffffu);
            ay = bfbits2f(u >> 16);
            int j = offsets[grow];
            const int e1 = offsets[grow + 1];
            for (; j + 1 < e1; j += 2) {
                unsigned v0 = hp[(size_t)srcs[j] * 64 + lane];
                unsigned v1 = hp[(size_t)srcs[j + 1] * 64 + lane];
                ax += bfbits2f(v0 & 0xffffu);
                ay += bfbits2f(v0 >> 16);
                ax += bfbits2f(v1 & 0xffffu);
                ay += bfbits2f(v1 >> 16);
            }
            if (j < e1) {
                unsigned v = hp[(size_t)srcs[j] * 64 + lane];
                ax += bfbits2f(v & 0xffffu);
                ay += bfbits2f(v >> 16);
            }
        }
        *(unsigned*)&Albuf[r * 136 + 2 * lane] = packbf2(ax, ay);
    }
    __syncthreads();

    const int wr = w >> 1;     // row half (32 rows)
    const int wc = w & 1;      // col half (64 cols)
    const int l15 = lane & 15;
    const int l4 = lane >> 4;  // 0..3

    // ---- MFMA pass 1: t = A @ Wa^T
    f32x4 acc[2][4];
#pragma unroll
    for (int m = 0; m < 2; ++m)
#pragma unroll
        for (int n = 0; n < 4; ++n) acc[m][n] = (f32x4){0.f, 0.f, 0.f, 0.f};

#pragma unroll
    for (int kk = 0; kk < 4; ++kk) {
        bf16x8 af[2], bfr[4];
#pragma unroll
        for (int m = 0; m < 2; ++m)
            af[m] = *(const bf16x8*)&Albuf[(wr * 32 + m * 16 + l15) * 136 + kk * 32 + l4 * 8];
#pragma unroll
        for (int n = 0; n < 4; ++n)
            bfr[n] = *(const bf16x8*)(WaBf + (size_t)(wc * 64 + n * 16 + l15) * HD + kk * 32 + l4 * 8);
#pragma unroll
        for (int m = 0; m < 2; ++m)
#pragma unroll
            for (int n = 0; n < 4; ++n)
                acc[m][n] = __builtin_amdgcn_mfma_f32_16x16x32_bf16(af[m], bfr[n], acc[m][n], 0, 0, 0);
    }

    // epilogue 1: relu(t + ba) -> A2 (bf16)
#pragma unroll
    for (int n = 0; n < 4; ++n) {
        const int col = wc * 64 + n * 16 + l15;
        const float bav = ba[col];
#pragma unroll
        for (int m = 0; m < 2; ++m) {
#pragma unroll
            for (int j = 0; j < 4; ++j) {
                const int row = wr * 32 + m * 16 + l4 * 4 + j;
                float v = fmaxf(acc[m][n][j] + bav, 0.f);
                A2buf[row * 136 + col] = (short)f2bf(v);
            }
        }
    }
    __syncthreads();

    // ---- MFMA pass 2: C = A2 @ Wb^T
#pragma unroll
    for (int m = 0; m < 2; ++m)
#pragma unroll
        for (int n = 0; n < 4; ++n) acc[m][n] = (f32x4){0.f, 0.f, 0.f, 0.f};

#pragma unroll
    for (int kk = 0; kk < 4; ++kk) {
        bf16x8 af[2], bfr[4];
#pragma unroll
        for (int m = 0; m < 2; ++m)
            af[m] = *(const bf16x8*)&A2buf[(wr * 32 + m * 16 + l15) * 136 + kk * 32 + l4 * 8];
#pragma unroll
        for (int n = 0; n < 4; ++n)
            bfr[n] = *(const bf16x8*)(WbBf + (size_t)(wc * 64 + n * 16 + l15) * HD + kk * 32 + l4 * 8);
#pragma unroll
        for (int m = 0; m < 2; ++m)
#pragma unroll
            for (int n = 0; n < 4; ++n)
                acc[m][n] = __builtin_amdgcn_mfma_f32_16x16x32_bf16(af[m], bfr[n], acc[m][n], 0, 0, 0);
    }

    // epilogue 2: C = acc + bb (fp32 store)
#pragma unroll
    for (int n = 0; n < 4; ++n) {
        const int col = wc * 64 + n * 16 + l15;
        const float bbv = bb[col];
#pragma unroll
        for (int m = 0; m < 2; ++m) {
#pragma unroll
            for (int j = 0; j < 4; ++j) {
                const int row = row0 + wr * 32 + m * 16 + l4 * 4 + j;
                if (row < nrows) C[(size_t)row * HD + col] = acc[m][n][j] + bbv;
            }
        }
    }
}

// ---------------- BatchNorm ----------------

__global__ void bn_stats_kernel(const float* __restrict__ y, float* __restrict__ stats, int n) {
    __shared__ float redS[256], redQ[256];
    const int tx = threadIdx.x;
    const int c = tx & 127;
    const int half = tx >> 7;
    float s = 0.f, ss = 0.f;
    for (int row = blockIdx.x * 2 + half; row < n; row += gridDim.x * 2) {
        float v = y[(size_t)row * HD + c];
        s += v;
        ss = fmaf(v, v, ss);
    }
    redS[tx] = s;
    redQ[tx] = ss;
    __syncthreads();
    if (tx < 128) {
        atomicAdd(&stats[tx], redS[tx] + redS[tx + 128]);
        atomicAdd(&stats[128 + tx], redQ[tx] + redQ[tx + 128]);
    }
}

// apply BN+relu in place (fp32, for pool) and also write bf16 copy (for next gather)
__global__ void bn_apply_kernel(float* __restrict__ y, const float* __restrict__ stats,
                                const float* __restrict__ gam, const float* __restrict__ bet,
                                unsigned short* __restrict__ hbf, int n) {
    int idx = blockIdx.x * blockDim.x + threadIdx.x;  // float4 index
    int total = n * (HD / 4);
    if (idx >= total) return;
    const int c = (idx & 31) * 4;
    const float invn = 1.0f / (float)n;
    float4 v = *(float4*)(y + (size_t)idx * 4);
    float r[4] = {v.x, v.y, v.z, v.w};
#pragma unroll
    for (int j = 0; j < 4; ++j) {
        float mu = stats[c + j] * invn;
        float var = stats[128 + c + j] * invn - mu * mu;
        float sc = gam[c + j] * rsqrtf(var + BN_EPS);
        float sh = bet[c + j] - mu * sc;
        r[j] = fmaxf(fmaf(r[j], sc, sh), 0.0f);
    }
    *(float4*)(y + (size_t)idx * 4) = make_float4(r[0], r[1], r[2], r[3]);
    uint2 p;
    p.x = packbf2(r[0], r[1]);
    p.y = packbf2(r[2], r[3]);
    *(uint2*)(hbf + (size_t)idx * 4) = p;
}

// ---------------- mean pool per graph ----------------

__global__ void pool_kernel(const float* __restrict__ h, const int* __restrict__ gstart,
                            float* __restrict__ pooled, int layerOff) {
    __shared__ float red[4][HD];
    const int g = blockIdx.x;
    const int tx = threadIdx.x;   // 512
    const int c = tx & 127;
    const int q = tx >> 7;        // 0..3
    int s0 = gstart[g], s1 = gstart[g + 1];
    float acc = 0.f;
    for (int i = s0 + q; i < s1; i += 4) acc += h[(size_t)i * HD + c];
    red[q][c] = acc;
    __syncthreads();
    if (q == 0) {
        float s = red[0][c] + red[1][c] + red[2][c] + red[3][c];
        int cnt = s1 - s0;
        float fc = (cnt > 0) ? (float)cnt : 1.0f;
        pooled[(size_t)g * (3 * HD) + layerOff + c] = s / fc;
    }
}

// ---------------- final linear + row L2 normalize ----------------

__global__ void final_kernel(const float* __restrict__ pooled, const float* __restrict__ linW,
                             const float* __restrict__ linb, float* __restrict__ out) {
    __shared__ float p[3 * HD];
    const int g = blockIdx.x;
    const int o = threadIdx.x;  // 64 threads = 1 wave
    for (int k = o; k < 3 * HD; k += 64) p[k] = pooled[(size_t)g * (3 * HD) + k];
    __syncthreads();
    float acc = linb[o];
    const float* wrow = linW + (size_t)o * (3 * HD);
#pragma unroll 4
    for (int k = 0; k < 3 * HD; k += 4) {
        float4 wv = *(const float4*)(wrow + k);
        float4 pv = *(const float4*)(&p[k]);
        acc = fmaf(wv.x, pv.x, acc);
        acc = fmaf(wv.y, pv.y, acc);
        acc = fmaf(wv.z, pv.z, acc);
        acc = fmaf(wv.w, pv.w, acc);
    }
    float sq = acc * acc;
#pragma unroll
    for (int off = 32; off > 0; off >>= 1) sq += __shfl_xor(sq, off);
    float nrm = sqrtf(sq);
    nrm = fmaxf(nrm, 1e-12f);
    out[(size_t)g * OD + o] = acc / nrm;
}

// ---------------- launch ----------------

extern "C" void kernel_launch(void* const* d_in, const int* in_sizes, int n_in,
                              void* d_out, int out_size, void* d_ws, size_t ws_size,
                              hipStream_t stream) {
    const float* x    = (const float*)d_in[0];
    const int* ei     = (const int*)d_in[1];
    const int* batch  = (const int*)d_in[2];
    const float* W11  = (const float*)d_in[3];
    const float* b11  = (const float*)d_in[4];
    const float* W12  = (const float*)d_in[5];
    const float* b12  = (const float*)d_in[6];
    const float* g1   = (const float*)d_in[7];
    const float* be1  = (const float*)d_in[8];
    const float* W21  = (const float*)d_in[9];
    const float* b21  = (const float*)d_in[10];
    const float* W22  = (const float*)d_in[11];
    const float* b22  = (const float*)d_in[12];
    const float* g2   = (const float*)d_in[13];
    const float* be2  = (const float*)d_in[14];
    const float* W31  = (const float*)d_in[15];
    const float* b31  = (const float*)d_in[16];
    const float* W32  = (const float*)d_in[17];
    const float* b32  = (const float*)d_in[18];
    const float* g3   = (const float*)d_in[19];
    const float* be3  = (const float*)d_in[20];
    const float* linW = (const float*)d_in[21];
    const float* linb = (const float*)d_in[22];

    const int* src = ei;
    const int* dst = ei + NE;

    char* ws = (char*)d_ws;
    size_t off = 0;
    auto alloc = [&](size_t bytes) -> void* {
        void* p = ws + off;
        off += (bytes + 255) & ~(size_t)255;
        return p;
    };
    int* deg      = (int*)alloc((size_t)NN * 4);
    int* offsets  = (int*)alloc((size_t)(NN + 1) * 4);
    int* cursor   = (int*)alloc((size_t)NN * 4);
    int* srcs     = (int*)alloc((size_t)NE * 4);
    int* gstart   = (int*)alloc((size_t)(NG + 1) * 4);
    int* lexcl    = (int*)alloc((size_t)NN * 4);
    int* bsum     = (int*)alloc((size_t)NSB * 4);
    int* boff     = (int*)alloc((size_t)NSB * 4);
    float* stats  = (float*)alloc(512 * 4);
    float* pooled = (float*)alloc((size_t)NG * 3 * HD * 4);
    float* Cbuf   = (float*)alloc((size_t)NN * HD * 4);
    unsigned short* xbf  = (unsigned short*)alloc((size_t)NN * HD * 2);
    unsigned short* hbf1 = (unsigned short*)alloc((size_t)NN * HD * 2);
    unsigned short* hbf2 = (unsigned short*)alloc((size_t)NN * HD * 2);
    unsigned short* wbf  = (unsigned short*)alloc((size_t)6 * HD * HD * 2);
    (void)ws_size; (void)n_in; (void)in_sizes; (void)out_size;

    // ---- weight + input conversions to bf16
    const int w8 = HD * HD / 8;  // 2048
    cvt_kernel<<<(NN * HD / 8 + 255) / 256, 256, 0, stream>>>(x, xbf, NN * HD / 8);
    cvt_kernel<<<(w8 + 255) / 256, 256, 0, stream>>>(W11, wbf + 0 * HD * HD, w8);
    cvt_kernel<<<(w8 + 255) / 256, 256, 0, stream>>>(W12, wbf + 1 * HD * HD, w8);
    cvt_kernel<<<(w8 + 255) / 256, 256, 0, stream>>>(W21, wbf + 2 * HD * HD, w8);
    cvt_kernel<<<(w8 + 255) / 256, 256, 0, stream>>>(W22, wbf + 3 * HD * HD, w8);
    cvt_kernel<<<(w8 + 255) / 256, 256, 0, stream>>>(W31, wbf + 4 * HD * HD, w8);
    cvt_kernel<<<(w8 + 255) / 256, 256, 0, stream>>>(W32, wbf + 5 * HD * HD, w8);

    // ---- CSR build
    hipMemsetAsync(deg, 0, (size_t)NN * 4, stream);
    hist_kernel<<<(NE + 255) / 256, 256, 0, stream>>>(dst, deg, NE);
    local_scan_kernel<<<NSB, SCAN_BLK, 0, stream>>>(deg, lexcl, bsum, NN);
    scan_bsum_kernel<<<1, 64, 0, stream>>>(bsum, boff, offsets, NSB, NN);
    finalize_scan_kernel<<<(NN + 255) / 256, 256, 0, stream>>>(lexcl, boff, offsets, cursor, NN);
    fill_kernel<<<(NE + 255) / 256, 256, 0, stream>>>(src, dst, cursor, srcs, NE);
    gstart_kernel<<<(NN + 255) / 256, 256, 0, stream>>>(batch, gstart, NN, NG);

    const int ginGrid = (NN + 63) / 64;  // 782

    auto layer = [&](const unsigned short* hinbf, unsigned short* houtbf,
                     const unsigned short* WaBf, const float* ba,
                     const unsigned short* WbBf, const float* bb,
                     const float* gg, const float* bee, int layerOff) {
        fused_gin<<<ginGrid, 256, 0, stream>>>(hinbf, offsets, srcs, WaBf, ba, WbBf, bb, Cbuf, NN);
        hipMemsetAsync(stats, 0, 256 * 4, stream);
        bn_stats_kernel<<<256, 256, 0, stream>>>(Cbuf, stats, NN);
        bn_apply_kernel<<<(NN * (HD / 4) + 255) / 256, 256, 0, stream>>>(Cbuf, stats, gg, bee, houtbf, NN);
        pool_kernel<<<NG, 512, 0, stream>>>(Cbuf, gstart, pooled, layerOff);
    };

    layer(xbf, hbf1, wbf + 0 * HD * HD, b11, wbf + 1 * HD * HD, b12, g1, be1, 0);
    layer(hbf1, hbf2, wbf + 2 * HD * HD, b21, wbf + 3 * HD * HD, b22, g2, be2, HD);
    layer(hbf2, hbf1, wbf + 4 * HD * HD, b31, wbf + 5 * HD * HD, b32, g3, be3, 2 * HD);

    final_kernel<<<NG, OD, 0, stream>>>(pooled, linW, linb, (float*)d_out);
}

// Round 6
// 423.370 us; speedup vs baseline: 11.1008x; 1.2652x over previous
//
#include <hip/hip_runtime.h>

#define NN 50000
#define NE 600000
#define HD 128
#define NG 512
#define OD 64
#define BN_EPS 1e-5f

#define SCAN_BLK 1024
#define NSB ((NN + SCAN_BLK - 1) / SCAN_BLK)  // 49
#define ECAP 4096  // LDS edge-index capacity per block (aliases A2buf)

typedef __attribute__((ext_vector_type(8))) short bf16x8;
typedef __attribute__((ext_vector_type(4))) float f32x4;

__device__ __forceinline__ unsigned short f2bf(float f) {
    unsigned u = __builtin_bit_cast(unsigned, f);
    unsigned r = u + 0x7FFFu + ((u >> 16) & 1u);  // round-to-nearest-even
    return (unsigned short)(r >> 16);
}

__device__ __forceinline__ float bflo(unsigned u) { return __builtin_bit_cast(float, u << 16); }
__device__ __forceinline__ float bfhi(unsigned u) { return __builtin_bit_cast(float, u & 0xffff0000u); }

__device__ __forceinline__ unsigned packbf2(float x, float y) {
    return (unsigned)f2bf(x) | ((unsigned)f2bf(y) << 16);
}

// ---------------- fp32 -> bf16 bulk convert (8 elems/thread) ----------------

__global__ void cvt_kernel(const float* __restrict__ src, unsigned short* __restrict__ dst, int n8) {
    int i = blockIdx.x * blockDim.x + threadIdx.x;
    if (i >= n8) return;
    float4 a = ((const float4*)src)[2 * i];
    float4 b = ((const float4*)src)[2 * i + 1];
    uint4 o;
    o.x = packbf2(a.x, a.y);
    o.y = packbf2(a.z, a.w);
    o.z = packbf2(b.x, b.y);
    o.w = packbf2(b.z, b.w);
    ((uint4*)dst)[i] = o;
}

// ---------------- CSR build ----------------

__global__ void hist_kernel(const int* __restrict__ dst, int* __restrict__ deg, int E) {
    int i = blockIdx.x * blockDim.x + threadIdx.x;
    if (i < E) atomicAdd(&deg[dst[i]], 1);
}

__global__ void local_scan_kernel(const int* __restrict__ deg, int* __restrict__ lexcl,
                                  int* __restrict__ bsum, int n) {
    __shared__ int part[SCAN_BLK];
    const int tid = threadIdx.x;
    const int i = blockIdx.x * SCAN_BLK + tid;
    int v = (i < n) ? deg[i] : 0;
    part[tid] = v;
    __syncthreads();
    int incl = v;
    for (int off = 1; off < SCAN_BLK; off <<= 1) {
        int t = (tid >= off) ? part[tid - off] : 0;
        __syncthreads();
        incl += t;
        part[tid] = incl;
        __syncthreads();
    }
    if (i < n) lexcl[i] = incl - v;
    if (tid == SCAN_BLK - 1) bsum[blockIdx.x] = incl;
}

__global__ void scan_bsum_kernel(const int* __restrict__ bsum, int* __restrict__ boff,
                                 int* __restrict__ offsets, int nb, int n) {
    const int tid = threadIdx.x;  // 64 threads
    int orig = (tid < nb) ? bsum[tid] : 0;
    int v = orig;
    for (int off = 1; off < 64; off <<= 1) {
        int t = __shfl_up(v, off);
        if (tid >= off) v += t;
    }
    if (tid < nb) boff[tid] = v - orig;
    if (tid == 63) offsets[n] = v;  // total = E
}

__global__ void finalize_scan_kernel(const int* __restrict__ lexcl, const int* __restrict__ boff,
                                     int* __restrict__ offsets, int* __restrict__ cursor, int n) {
    int i = blockIdx.x * blockDim.x + threadIdx.x;
    if (i < n) {
        int o = lexcl[i] + boff[i >> 10];
        offsets[i] = o;
        cursor[i] = o;
    }
}

__global__ void fill_kernel(const int* __restrict__ src, const int* __restrict__ dst,
                            int* __restrict__ cursor, int* __restrict__ srcs, int E) {
    int i = blockIdx.x * blockDim.x + threadIdx.x;
    if (i < E) {
        int pos = atomicAdd(&cursor[dst[i]], 1);
        srcs[pos] = src[i];
    }
}

__global__ void gstart_kernel(const int* __restrict__ batch, int* __restrict__ gstart,
                              int n, int G) {
    int i = blockIdx.x * blockDim.x + threadIdx.x;
    if (i >= n) return;
    int b = batch[i];
    int bp = (i == 0) ? -1 : batch[i - 1];
    for (int g = bp + 1; g <= b; ++g) gstart[g] = i;
    if (i == n - 1) {
        for (int g = b + 1; g <= G; ++g) gstart[g] = n;
    }
}

// ---------------- fused GIN layer: gather + MLP (bf16 MFMA) ----------------
// C = relu((h + sum_nbr h) @ Wa^T + ba) @ Wb^T + bb
// 64 rows/block, 4 waves. Edge indices staged in LDS (aliasing A2buf) to break
// the srcs->h dependent-load chain; gather unrolled 4-deep.

__global__ __launch_bounds__(256) void fused_gin(const unsigned short* __restrict__ Hbf,
                                                 const int* __restrict__ offsets,
                                                 const int* __restrict__ srcs,
                                                 const unsigned short* __restrict__ WaBf,
                                                 const float* __restrict__ ba,
                                                 const unsigned short* __restrict__ WbBf,
                                                 const float* __restrict__ bb,
                                                 float* __restrict__ C, int nrows) {
    __shared__ short Albuf[64 * 136];
    __shared__ short A2buf[64 * 136];
    int* elds = (int*)A2buf;  // alias: dead until after the post-gather barrier

    const int t = threadIdx.x;
    const int lane = t & 63;
    const int w = t >> 6;      // wave 0..3
    const int row0 = blockIdx.x * 64;
    const unsigned* hp = (const unsigned*)Hbf;  // 2 bf16 per unsigned, 64 per row

    const int rend = (row0 + 64 < nrows) ? row0 + 64 : nrows;
    const int ebase = offsets[row0];
    const int eend = offsets[rend];
    const int cnt = eend - ebase;
    const bool fast = (cnt <= ECAP);

    // ---- cooperative edge-index staging (coalesced)
    if (fast) {
        for (int k = t; k < cnt; k += 256) elds[k] = srcs[ebase + k];
    }
    __syncthreads();

    // ---- gather phase: wave w owns rows w*16 .. w*16+15
    for (int i = 0; i < 16; ++i) {
        const int r = w * 16 + i;
        const int grow = row0 + r;
        float ax = 0.f, ay = 0.f;
        if (grow < nrows) {
            unsigned u = hp[(size_t)grow * 64 + lane];
            ax = bflo(u);
            ay = bfhi(u);
            const int j0 = offsets[grow], e1 = offsets[grow + 1];
            if (fast) {
                int jj = j0 - ebase;
                const int ee = e1 - ebase;
                for (; jj + 3 < ee; jj += 4) {
                    const int s0 = elds[jj], s1 = elds[jj + 1], s2 = elds[jj + 2], s3 = elds[jj + 3];
                    unsigned v0 = hp[(size_t)s0 * 64 + lane];
                    unsigned v1 = hp[(size_t)s1 * 64 + lane];
                    unsigned v2 = hp[(size_t)s2 * 64 + lane];
                    unsigned v3 = hp[(size_t)s3 * 64 + lane];
                    ax += bflo(v0) + bflo(v1);
                    ay += bfhi(v0) + bfhi(v1);
                    ax += bflo(v2) + bflo(v3);
                    ay += bfhi(v2) + bfhi(v3);
                }
                for (; jj < ee; ++jj) {
                    unsigned v = hp[(size_t)elds[jj] * 64 + lane];
                    ax += bflo(v);
                    ay += bfhi(v);
                }
            } else {
                for (int j = j0; j < e1; ++j) {
                    unsigned v = hp[(size_t)srcs[j] * 64 + lane];
                    ax += bflo(v);
                    ay += bfhi(v);
                }
            }
        }
        *(unsigned*)&Albuf[r * 136 + 2 * lane] = packbf2(ax, ay);
    }
    __syncthreads();  // gather done; elds dead; A2buf reusable

    const int wr = w >> 1;     // row half (32 rows)
    const int wc = w & 1;      // col half (64 cols)
    const int l15 = lane & 15;
    const int l4 = lane >> 4;  // 0..3

    // ---- MFMA pass 1: t = A @ Wa^T
    f32x4 acc[2][4];
#pragma unroll
    for (int m = 0; m < 2; ++m)
#pragma unroll
        for (int n = 0; n < 4; ++n) acc[m][n] = (f32x4){0.f, 0.f, 0.f, 0.f};

#pragma unroll
    for (int kk = 0; kk < 4; ++kk) {
        bf16x8 af[2], bfr[4];
#pragma unroll
        for (int m = 0; m < 2; ++m)
            af[m] = *(const bf16x8*)&Albuf[(wr * 32 + m * 16 + l15) * 136 + kk * 32 + l4 * 8];
#pragma unroll
        for (int n = 0; n < 4; ++n)
            bfr[n] = *(const bf16x8*)(WaBf + (size_t)(wc * 64 + n * 16 + l15) * HD + kk * 32 + l4 * 8);
#pragma unroll
        for (int m = 0; m < 2; ++m)
#pragma unroll
            for (int n = 0; n < 4; ++n)
                acc[m][n] = __builtin_amdgcn_mfma_f32_16x16x32_bf16(af[m], bfr[n], acc[m][n], 0, 0, 0);
    }

    // epilogue 1: relu(t + ba) -> A2 (bf16)
#pragma unroll
    for (int n = 0; n < 4; ++n) {
        const int col = wc * 64 + n * 16 + l15;
        const float bav = ba[col];
#pragma unroll
        for (int m = 0; m < 2; ++m) {
#pragma unroll
            for (int j = 0; j < 4; ++j) {
                const int row = wr * 32 + m * 16 + l4 * 4 + j;
                float v = fmaxf(acc[m][n][j] + bav, 0.f);
                A2buf[row * 136 + col] = (short)f2bf(v);
            }
        }
    }
    __syncthreads();

    // ---- MFMA pass 2: C = A2 @ Wb^T
#pragma unroll
    for (int m = 0; m < 2; ++m)
#pragma unroll
        for (int n = 0; n < 4; ++n) acc[m][n] = (f32x4){0.f, 0.f, 0.f, 0.f};

#pragma unroll
    for (int kk = 0; kk < 4; ++kk) {
        bf16x8 af[2], bfr[4];
#pragma unroll
        for (int m = 0; m < 2; ++m)
            af[m] = *(const bf16x8*)&A2buf[(wr * 32 + m * 16 + l15) * 136 + kk * 32 + l4 * 8];
#pragma unroll
        for (int n = 0; n < 4; ++n)
            bfr[n] = *(const bf16x8*)(WbBf + (size_t)(wc * 64 + n * 16 + l15) * HD + kk * 32 + l4 * 8);
#pragma unroll
        for (int m = 0; m < 2; ++m)
#pragma unroll
            for (int n = 0; n < 4; ++n)
                acc[m][n] = __builtin_amdgcn_mfma_f32_16x16x32_bf16(af[m], bfr[n], acc[m][n], 0, 0, 0);
    }

    // epilogue 2: C = acc + bb (fp32 store)
#pragma unroll
    for (int n = 0; n < 4; ++n) {
        const int col = wc * 64 + n * 16 + l15;
        const float bbv = bb[col];
#pragma unroll
        for (int m = 0; m < 2; ++m) {
#pragma unroll
            for (int j = 0; j < 4; ++j) {
                const int row = row0 + wr * 32 + m * 16 + l4 * 4 + j;
                if (row < nrows) C[(size_t)row * HD + col] = acc[m][n][j] + bbv;
            }
        }
    }
}

// ---------------- BatchNorm ----------------

__global__ void bn_stats_kernel(const float* __restrict__ y, float* __restrict__ stats, int n) {
    __shared__ float redS[256], redQ[256];
    const int tx = threadIdx.x;
    const int c = tx & 127;
    const int half = tx >> 7;
    float s = 0.f, ss = 0.f;
    for (int row = blockIdx.x * 2 + half; row < n; row += gridDim.x * 2) {
        float v = y[(size_t)row * HD + c];
        s += v;
        ss = fmaf(v, v, ss);
    }
    redS[tx] = s;
    redQ[tx] = ss;
    __syncthreads();
    if (tx < 128) {
        atomicAdd(&stats[tx], redS[tx] + redS[tx + 128]);
        atomicAdd(&stats[128 + tx], redQ[tx] + redQ[tx + 128]);
    }
}

// apply BN+relu in place (fp32, for pool) and also write bf16 copy (for next gather)
__global__ void bn_apply_kernel(float* __restrict__ y, const float* __restrict__ stats,
                                const float* __restrict__ gam, const float* __restrict__ bet,
                                unsigned short* __restrict__ hbf, int n) {
    int idx = blockIdx.x * blockDim.x + threadIdx.x;  // float4 index
    int total = n * (HD / 4);
    if (idx >= total) return;
    const int c = (idx & 31) * 4;
    const float invn = 1.0f / (float)n;
    float4 v = *(float4*)(y + (size_t)idx * 4);
    float r[4] = {v.x, v.y, v.z, v.w};
#pragma unroll
    for (int j = 0; j < 4; ++j) {
        float mu = stats[c + j] * invn;
        float var = stats[128 + c + j] * invn - mu * mu;
        float sc = gam[c + j] * rsqrtf(var + BN_EPS);
        float sh = bet[c + j] - mu * sc;
        r[j] = fmaxf(fmaf(r[j], sc, sh), 0.0f);
    }
    *(float4*)(y + (size_t)idx * 4) = make_float4(r[0], r[1], r[2], r[3]);
    uint2 p;
    p.x = packbf2(r[0], r[1]);
    p.y = packbf2(r[2], r[3]);
    *(uint2*)(hbf + (size_t)idx * 4) = p;
}

// ---------------- mean pool per graph ----------------

__global__ void pool_kernel(const float* __restrict__ h, const int* __restrict__ gstart,
                            float* __restrict__ pooled, int layerOff) {
    __shared__ float red[4][HD];
    const int g = blockIdx.x;
    const int tx = threadIdx.x;   // 512
    const int c = tx & 127;
    const int q = tx >> 7;        // 0..3
    int s0 = gstart[g], s1 = gstart[g + 1];
    float acc = 0.f;
    for (int i = s0 + q; i < s1; i += 4) acc += h[(size_t)i * HD + c];
    red[q][c] = acc;
    __syncthreads();
    if (q == 0) {
        float s = red[0][c] + red[1][c] + red[2][c] + red[3][c];
        int cnt = s1 - s0;
        float fc = (cnt > 0) ? (float)cnt : 1.0f;
        pooled[(size_t)g * (3 * HD) + layerOff + c] = s / fc;
    }
}

// ---------------- final linear + row L2 normalize ----------------

__global__ void final_kernel(const float* __restrict__ pooled, const float* __restrict__ linW,
                             const float* __restrict__ linb, float* __restrict__ out) {
    __shared__ float p[3 * HD];
    const int g = blockIdx.x;
    const int o = threadIdx.x;  // 64 threads = 1 wave
    for (int k = o; k < 3 * HD; k += 64) p[k] = pooled[(size_t)g * (3 * HD) + k];
    __syncthreads();
    float acc = linb[o];
    const float* wrow = linW + (size_t)o * (3 * HD);
#pragma unroll 4
    for (int k = 0; k < 3 * HD; k += 4) {
        float4 wv = *(const float4*)(wrow + k);
        float4 pv = *(const float4*)(&p[k]);
        acc = fmaf(wv.x, pv.x, acc);
        acc = fmaf(wv.y, pv.y, acc);
        acc = fmaf(wv.z, pv.z, acc);
        acc = fmaf(wv.w, pv.w, acc);
    }
    float sq = acc * acc;
#pragma unroll
    for (int off = 32; off > 0; off >>= 1) sq += __shfl_xor(sq, off);
    float nrm = sqrtf(sq);
    nrm = fmaxf(nrm, 1e-12f);
    out[(size_t)g * OD + o] = acc / nrm;
}

// ---------------- launch ----------------

extern "C" void kernel_launch(void* const* d_in, const int* in_sizes, int n_in,
                              void* d_out, int out_size, void* d_ws, size_t ws_size,
                              hipStream_t stream) {
    const float* x    = (const float*)d_in[0];
    const int* ei     = (const int*)d_in[1];
    const int* batch  = (const int*)d_in[2];
    const float* W11  = (const float*)d_in[3];
    const float* b11  = (const float*)d_in[4];
    const float* W12  = (const float*)d_in[5];
    const float* b12  = (const float*)d_in[6];
    const float* g1   = (const float*)d_in[7];
    const float* be1  = (const float*)d_in[8];
    const float* W21  = (const float*)d_in[9];
    const float* b21  = (const float*)d_in[10];
    const float* W22  = (const float*)d_in[11];
    const float* b22  = (const float*)d_in[12];
    const float* g2   = (const float*)d_in[13];
    const float* be2  = (const float*)d_in[14];
    const float* W31  = (const float*)d_in[15];
    const float* b31  = (const float*)d_in[16];
    const float* W32  = (const float*)d_in[17];
    const float* b32  = (const float*)d_in[18];
    const float* g3   = (const float*)d_in[19];
    const float* be3  = (const float*)d_in[20];
    const float* linW = (const float*)d_in[21];
    const float* linb = (const float*)d_in[22];

    const int* src = ei;
    const int* dst = ei + NE;

    char* ws = (char*)d_ws;
    size_t off = 0;
    auto alloc = [&](size_t bytes) -> void* {
        void* p = ws + off;
        off += (bytes + 255) & ~(size_t)255;
        return p;
    };
    int* deg      = (int*)alloc((size_t)NN * 4);
    int* offsets  = (int*)alloc((size_t)(NN + 1) * 4);
    int* cursor   = (int*)alloc((size_t)NN * 4);
    int* srcs     = (int*)alloc((size_t)NE * 4);
    int* gstart   = (int*)alloc((size_t)(NG + 1) * 4);
    int* lexcl    = (int*)alloc((size_t)NN * 4);
    int* bsum     = (int*)alloc((size_t)NSB * 4);
    int* boff     = (int*)alloc((size_t)NSB * 4);
    float* stats  = (float*)alloc(512 * 4);
    float* pooled = (float*)alloc((size_t)NG * 3 * HD * 4);
    float* Cbuf   = (float*)alloc((size_t)NN * HD * 4);
    unsigned short* xbf  = (unsigned short*)alloc((size_t)NN * HD * 2);
    unsigned short* hbf1 = (unsigned short*)alloc((size_t)NN * HD * 2);
    unsigned short* hbf2 = (unsigned short*)alloc((size_t)NN * HD * 2);
    unsigned short* wbf  = (unsigned short*)alloc((size_t)6 * HD * HD * 2);
    (void)ws_size; (void)n_in; (void)in_sizes; (void)out_size;

    // ---- weight + input conversions to bf16
    const int w8 = HD * HD / 8;  // 2048
    cvt_kernel<<<(NN * HD / 8 + 255) / 256, 256, 0, stream>>>(x, xbf, NN * HD / 8);
    cvt_kernel<<<(w8 + 255) / 256, 256, 0, stream>>>(W11, wbf + 0 * HD * HD, w8);
    cvt_kernel<<<(w8 + 255) / 256, 256, 0, stream>>>(W12, wbf + 1 * HD * HD, w8);
    cvt_kernel<<<(w8 + 255) / 256, 256, 0, stream>>>(W21, wbf + 2 * HD * HD, w8);
    cvt_kernel<<<(w8 + 255) / 256, 256, 0, stream>>>(W22, wbf + 3 * HD * HD, w8);
    cvt_kernel<<<(w8 + 255) / 256, 256, 0, stream>>>(W31, wbf + 4 * HD * HD, w8);
    cvt_kernel<<<(w8 + 255) / 256, 256, 0, stream>>>(W32, wbf + 5 * HD * HD, w8);

    // ---- CSR build
    hipMemsetAsync(deg, 0, (size_t)NN * 4, stream);
    hist_kernel<<<(NE + 255) / 256, 256, 0, stream>>>(dst, deg, NE);
    local_scan_kernel<<<NSB, SCAN_BLK, 0, stream>>>(deg, lexcl, bsum, NN);
    scan_bsum_kernel<<<1, 64, 0, stream>>>(bsum, boff, offsets, NSB, NN);
    finalize_scan_kernel<<<(NN + 255) / 256, 256, 0, stream>>>(lexcl, boff, offsets, cursor, NN);
    fill_kernel<<<(NE + 255) / 256, 256, 0, stream>>>(src, dst, cursor, srcs, NE);
    gstart_kernel<<<(NN + 255) / 256, 256, 0, stream>>>(batch, gstart, NN, NG);

    const int ginGrid = (NN + 63) / 64;  // 782

    auto layer = [&](const unsigned short* hinbf, unsigned short* houtbf,
                     const unsigned short* WaBf, const float* ba,
                     const unsigned short* WbBf, const float* bb,
                     const float* gg, const float* bee, int layerOff) {
        fused_gin<<<ginGrid, 256, 0, stream>>>(hinbf, offsets, srcs, WaBf, ba, WbBf, bb, Cbuf, NN);
        hipMemsetAsync(stats, 0, 256 * 4, stream);
        bn_stats_kernel<<<256, 256, 0, stream>>>(Cbuf, stats, NN);
        bn_apply_kernel<<<(NN * (HD / 4) + 255) / 256, 256, 0, stream>>>(Cbuf, stats, gg, bee, houtbf, NN);
        pool_kernel<<<NG, 512, 0, stream>>>(Cbuf, gstart, pooled, layerOff);
    };

    layer(xbf, hbf1, wbf + 0 * HD * HD, b11, wbf + 1 * HD * HD, b12, g1, be1, 0);
    layer(hbf1, hbf2, wbf + 2 * HD * HD, b21, wbf + 3 * HD * HD, b22, g2, be2, HD);
    layer(hbf2, hbf1, wbf + 4 * HD * HD, b31, wbf + 5 * HD * HD, b32, g3, be3, 2 * HD);

    final_kernel<<<NG, OD, 0, stream>>>(pooled, linW, linb, (float*)d_out);
}

// Round 7
// 353.629 us; speedup vs baseline: 13.2901x; 1.1972x over previous
//
#include <hip/hip_runtime.h>

#define NN 50000
#define NE 600000
#define HD 128
#define NG 512
#define OD 64
#define BN_EPS 1e-5f

#define SCAN_BLK 1024
#define NSB ((NN + SCAN_BLK - 1) / SCAN_BLK)  // 49
#define ECAP 1536  // LDS edge-index capacity (mean 768, sigma ~28; fallback path if exceeded)

typedef __attribute__((ext_vector_type(8))) short bf16x8;
typedef __attribute__((ext_vector_type(4))) float f32x4;

__device__ __forceinline__ unsigned short f2bf(float f) {
    unsigned u = __builtin_bit_cast(unsigned, f);
    unsigned r = u + 0x7FFFu + ((u >> 16) & 1u);  // round-to-nearest-even
    return (unsigned short)(r >> 16);
}

__device__ __forceinline__ float bflo(unsigned u) { return __builtin_bit_cast(float, u << 16); }
__device__ __forceinline__ float bfhi(unsigned u) { return __builtin_bit_cast(float, u & 0xffff0000u); }

__device__ __forceinline__ unsigned packbf2(float x, float y) {
    return (unsigned)f2bf(x) | ((unsigned)f2bf(y) << 16);
}

// ---------------- fp32 -> bf16 bulk convert (8 elems/thread) ----------------

__global__ void cvt_kernel(const float* __restrict__ src, unsigned short* __restrict__ dst, int n8) {
    int i = blockIdx.x * blockDim.x + threadIdx.x;
    if (i >= n8) return;
    float4 a = ((const float4*)src)[2 * i];
    float4 b = ((const float4*)src)[2 * i + 1];
    uint4 o;
    o.x = packbf2(a.x, a.y);
    o.y = packbf2(a.z, a.w);
    o.z = packbf2(b.x, b.y);
    o.w = packbf2(b.z, b.w);
    ((uint4*)dst)[i] = o;
}

// ---------------- CSR build ----------------

__global__ void hist_kernel(const int* __restrict__ dst, int* __restrict__ deg, int E) {
    int i = blockIdx.x * blockDim.x + threadIdx.x;
    if (i < E) atomicAdd(&deg[dst[i]], 1);
}

__global__ void local_scan_kernel(const int* __restrict__ deg, int* __restrict__ lexcl,
                                  int* __restrict__ bsum, int n) {
    __shared__ int part[SCAN_BLK];
    const int tid = threadIdx.x;
    const int i = blockIdx.x * SCAN_BLK + tid;
    int v = (i < n) ? deg[i] : 0;
    part[tid] = v;
    __syncthreads();
    int incl = v;
    for (int off = 1; off < SCAN_BLK; off <<= 1) {
        int t = (tid >= off) ? part[tid - off] : 0;
        __syncthreads();
        incl += t;
        part[tid] = incl;
        __syncthreads();
    }
    if (i < n) lexcl[i] = incl - v;
    if (tid == SCAN_BLK - 1) bsum[blockIdx.x] = incl;
}

__global__ void scan_bsum_kernel(const int* __restrict__ bsum, int* __restrict__ boff,
                                 int* __restrict__ offsets, int nb, int n) {
    const int tid = threadIdx.x;  // 64 threads
    int orig = (tid < nb) ? bsum[tid] : 0;
    int v = orig;
    for (int off = 1; off < 64; off <<= 1) {
        int t = __shfl_up(v, off);
        if (tid >= off) v += t;
    }
    if (tid < nb) boff[tid] = v - orig;
    if (tid == 63) offsets[n] = v;  // total = E
}

__global__ void finalize_scan_kernel(const int* __restrict__ lexcl, const int* __restrict__ boff,
                                     int* __restrict__ offsets, int* __restrict__ cursor, int n) {
    int i = blockIdx.x * blockDim.x + threadIdx.x;
    if (i < n) {
        int o = lexcl[i] + boff[i >> 10];
        offsets[i] = o;
        cursor[i] = o;
    }
}

__global__ void fill_kernel(const int* __restrict__ src, const int* __restrict__ dst,
                            int* __restrict__ cursor, int* __restrict__ srcs, int E) {
    int i = blockIdx.x * blockDim.x + threadIdx.x;
    if (i < E) {
        int pos = atomicAdd(&cursor[dst[i]], 1);
        srcs[pos] = src[i];
    }
}

__global__ void gstart_kernel(const int* __restrict__ batch, int* __restrict__ gstart,
                              int n, int G) {
    int i = blockIdx.x * blockDim.x + threadIdx.x;
    if (i >= n) return;
    int b = batch[i];
    int bp = (i == 0) ? -1 : batch[i - 1];
    for (int g = bp + 1; g <= b; ++g) gstart[g] = i;
    if (i == n - 1) {
        for (int g = b + 1; g <= G; ++g) gstart[g] = n;
    }
}

// ---------------- fused GIN layer: [BN+relu] gather + 2xMFMA MLP ----------------
// h = DOBN ? relu(sc*c+sh) : c  (applied per gathered element)
// C = relu((h_i + sum_nbr h_j) @ Wa^T + ba) @ Wb^T + bb   -> bf16 out
// Single LDS tile SB: holds A (gather out) for pass 1, overwritten by A2 for pass 2.

template <bool DOBN>
__global__ __launch_bounds__(256) void fused_gin(const unsigned* __restrict__ hp,
                                                 const int* __restrict__ offsets,
                                                 const int* __restrict__ srcs,
                                                 const float* __restrict__ stats,
                                                 const float* __restrict__ gam,
                                                 const float* __restrict__ bet,
                                                 const unsigned short* __restrict__ WaBf,
                                                 const float* __restrict__ ba,
                                                 const unsigned short* __restrict__ WbBf,
                                                 const float* __restrict__ bb,
                                                 unsigned short* __restrict__ Cb,
                                                 int nrows) {
    __shared__ short SB[64 * 136];
    __shared__ int elds[ECAP];

    const int t = threadIdx.x;
    const int lane = t & 63;
    const int w = t >> 6;      // wave 0..3
    const int row0 = blockIdx.x * 64;

    float sc0 = 1.f, sh0 = 0.f, sc1 = 1.f, sh1 = 0.f;
    if (DOBN) {
        const float invn = 1.0f / (float)NN;
        const int c0 = 2 * lane, c1 = c0 + 1;
        float mu0 = stats[c0] * invn;
        float va0 = stats[128 + c0] * invn - mu0 * mu0;
        sc0 = gam[c0] * rsqrtf(va0 + BN_EPS);
        sh0 = bet[c0] - mu0 * sc0;
        float mu1 = stats[c1] * invn;
        float va1 = stats[128 + c1] * invn - mu1 * mu1;
        sc1 = gam[c1] * rsqrtf(va1 + BN_EPS);
        sh1 = bet[c1] - mu1 * sc1;
    }

    auto xf = [&](unsigned u, float& x, float& y) {
        x = bflo(u);
        y = bfhi(u);
        if (DOBN) {
            x = fmaxf(fmaf(x, sc0, sh0), 0.f);
            y = fmaxf(fmaf(y, sc1, sh1), 0.f);
        }
    };

    const int rend = (row0 + 64 < nrows) ? row0 + 64 : nrows;
    const int ebase = offsets[row0];
    const int cnt = offsets[rend] - ebase;
    const bool fast = (cnt <= ECAP);

    if (fast) {
        for (int k = t; k < cnt; k += 256) elds[k] = srcs[ebase + k];
    }
    __syncthreads();

    // ---- gather: wave w owns rows w*16 .. w*16+15
    for (int i = 0; i < 16; ++i) {
        const int r = w * 16 + i;
        const int grow = row0 + r;
        float ax = 0.f, ay = 0.f;
        if (grow < nrows) {
            {
                float x, y;
                xf(hp[(size_t)grow * 64 + lane], x, y);
                ax = x; ay = y;
            }
            const int j0 = offsets[grow], e1 = offsets[grow + 1];
            if (fast) {
                int jj = j0 - ebase;
                const int ee = e1 - ebase;
                for (; jj + 7 < ee; jj += 8) {
                    const int s0 = elds[jj], s1 = elds[jj + 1], s2 = elds[jj + 2], s3 = elds[jj + 3];
                    const int s4 = elds[jj + 4], s5 = elds[jj + 5], s6 = elds[jj + 6], s7 = elds[jj + 7];
                    unsigned v0 = hp[(size_t)s0 * 64 + lane];
                    unsigned v1 = hp[(size_t)s1 * 64 + lane];
                    unsigned v2 = hp[(size_t)s2 * 64 + lane];
                    unsigned v3 = hp[(size_t)s3 * 64 + lane];
                    unsigned v4 = hp[(size_t)s4 * 64 + lane];
                    unsigned v5 = hp[(size_t)s5 * 64 + lane];
                    unsigned v6 = hp[(size_t)s6 * 64 + lane];
                    unsigned v7 = hp[(size_t)s7 * 64 + lane];
                    float x, y;
                    xf(v0, x, y); ax += x; ay += y;
                    xf(v1, x, y); ax += x; ay += y;
                    xf(v2, x, y); ax += x; ay += y;
                    xf(v3, x, y); ax += x; ay += y;
                    xf(v4, x, y); ax += x; ay += y;
                    xf(v5, x, y); ax += x; ay += y;
                    xf(v6, x, y); ax += x; ay += y;
                    xf(v7, x, y); ax += x; ay += y;
                }
                for (; jj + 3 < ee; jj += 4) {
                    const int s0 = elds[jj], s1 = elds[jj + 1], s2 = elds[jj + 2], s3 = elds[jj + 3];
                    unsigned v0 = hp[(size_t)s0 * 64 + lane];
                    unsigned v1 = hp[(size_t)s1 * 64 + lane];
                    unsigned v2 = hp[(size_t)s2 * 64 + lane];
                    unsigned v3 = hp[(size_t)s3 * 64 + lane];
                    float x, y;
                    xf(v0, x, y); ax += x; ay += y;
                    xf(v1, x, y); ax += x; ay += y;
                    xf(v2, x, y); ax += x; ay += y;
                    xf(v3, x, y); ax += x; ay += y;
                }
                for (; jj < ee; ++jj) {
                    unsigned v = hp[(size_t)elds[jj] * 64 + lane];
                    float x, y;
                    xf(v, x, y); ax += x; ay += y;
                }
            } else {
                for (int j = j0; j < e1; ++j) {
                    unsigned v = hp[(size_t)srcs[j] * 64 + lane];
                    float x, y;
                    xf(v, x, y); ax += x; ay += y;
                }
            }
        }
        *(unsigned*)&SB[r * 136 + 2 * lane] = packbf2(ax, ay);
    }
    __syncthreads();  // SB holds A

    const int wr = w >> 1;     // row half (32 rows)
    const int wc = w & 1;      // col half (64 cols)
    const int l15 = lane & 15;
    const int l4 = lane >> 4;  // 0..3

    // ---- MFMA pass 1: t = A @ Wa^T  (A from SB, B from global)
    f32x4 acc[2][4];
#pragma unroll
    for (int m = 0; m < 2; ++m)
#pragma unroll
        for (int n = 0; n < 4; ++n) acc[m][n] = (f32x4){0.f, 0.f, 0.f, 0.f};

#pragma unroll
    for (int kk = 0; kk < 4; ++kk) {
        bf16x8 af[2], bfr[4];
#pragma unroll
        for (int m = 0; m < 2; ++m)
            af[m] = *(const bf16x8*)&SB[(wr * 32 + m * 16 + l15) * 136 + kk * 32 + l4 * 8];
#pragma unroll
        for (int n = 0; n < 4; ++n)
            bfr[n] = *(const bf16x8*)(WaBf + (size_t)(wc * 64 + n * 16 + l15) * HD + kk * 32 + l4 * 8);
#pragma unroll
        for (int m = 0; m < 2; ++m)
#pragma unroll
            for (int n = 0; n < 4; ++n)
                acc[m][n] = __builtin_amdgcn_mfma_f32_16x16x32_bf16(af[m], bfr[n], acc[m][n], 0, 0, 0);
    }
    __syncthreads();  // all pass-1 SB reads complete; SB now writable

    // epilogue 1: relu(t + ba) -> SB (as A2, bf16)
#pragma unroll
    for (int n = 0; n < 4; ++n) {
        const int col = wc * 64 + n * 16 + l15;
        const float bav = ba[col];
#pragma unroll
        for (int m = 0; m < 2; ++m) {
#pragma unroll
            for (int j = 0; j < 4; ++j) {
                const int row = wr * 32 + m * 16 + l4 * 4 + j;
                float v = fmaxf(acc[m][n][j] + bav, 0.f);
                SB[row * 136 + col] = (short)f2bf(v);
            }
        }
    }
    __syncthreads();  // A2 visible

    // ---- MFMA pass 2: C = A2 @ Wb^T
#pragma unroll
    for (int m = 0; m < 2; ++m)
#pragma unroll
        for (int n = 0; n < 4; ++n) acc[m][n] = (f32x4){0.f, 0.f, 0.f, 0.f};

#pragma unroll
    for (int kk = 0; kk < 4; ++kk) {
        bf16x8 af[2], bfr[4];
#pragma unroll
        for (int m = 0; m < 2; ++m)
            af[m] = *(const bf16x8*)&SB[(wr * 32 + m * 16 + l15) * 136 + kk * 32 + l4 * 8];
#pragma unroll
        for (int n = 0; n < 4; ++n)
            bfr[n] = *(const bf16x8*)(WbBf + (size_t)(wc * 64 + n * 16 + l15) * HD + kk * 32 + l4 * 8);
#pragma unroll
        for (int m = 0; m < 2; ++m)
#pragma unroll
            for (int n = 0; n < 4; ++n)
                acc[m][n] = __builtin_amdgcn_mfma_f32_16x16x32_bf16(af[m], bfr[n], acc[m][n], 0, 0, 0);
    }

    // epilogue 2: Cb = bf16(acc + bb)
#pragma unroll
    for (int n = 0; n < 4; ++n) {
        const int col = wc * 64 + n * 16 + l15;
        const float bbv = bb[col];
#pragma unroll
        for (int m = 0; m < 2; ++m) {
#pragma unroll
            for (int j = 0; j < 4; ++j) {
                const int row = row0 + wr * 32 + m * 16 + l4 * 4 + j;
                if (row < nrows) Cb[(size_t)row * HD + col] = f2bf(acc[m][n][j] + bbv);
            }
        }
    }
}

// ---------------- BN stats over bf16 C: stats[c]=sum, stats[128+c]=sumsq ----------------

__global__ void bn_stats_bf(const unsigned* __restrict__ hp, float* __restrict__ stats, int n) {
    __shared__ float4 red[4][64];
    const int tx = threadIdx.x;  // 256
    const int cp = tx & 63;
    const int half = tx >> 6;
    float s0 = 0.f, q0 = 0.f, s1 = 0.f, q1 = 0.f;
    for (int r = blockIdx.x * 4 + half; r < n; r += gridDim.x * 4) {
        unsigned u = hp[(size_t)r * 64 + cp];
        float x0 = bflo(u), x1 = bfhi(u);
        s0 += x0; q0 = fmaf(x0, x0, q0);
        s1 += x1; q1 = fmaf(x1, x1, q1);
    }
    red[half][cp] = make_float4(s0, q0, s1, q1);
    __syncthreads();
    if (half == 0) {
        float4 a = red[0][cp], b = red[1][cp], c = red[2][cp], d = red[3][cp];
        atomicAdd(&stats[2 * cp],       a.x + b.x + c.x + d.x);
        atomicAdd(&stats[128 + 2 * cp], a.y + b.y + c.y + d.y);
        atomicAdd(&stats[2 * cp + 1],       a.z + b.z + c.z + d.z);
        atomicAdd(&stats[128 + 2 * cp + 1], a.w + b.w + c.w + d.w);
    }
}

// ---------------- mean pool with BN+relu applied on the fly ----------------

__global__ void pool_bn(const unsigned* __restrict__ hp, const int* __restrict__ gstart,
                        const float* __restrict__ stats, const float* __restrict__ gam,
                        const float* __restrict__ bet, float* __restrict__ pooled, int layerOff) {
    __shared__ float2 red[8][64];
    const int g = blockIdx.x;
    const int tx = threadIdx.x;  // 512
    const int cp = tx & 63;
    const int q = tx >> 6;       // 0..7
    const float invn = 1.0f / (float)NN;
    const int c0 = 2 * cp, c1 = c0 + 1;
    float mu0 = stats[c0] * invn;
    float va0 = stats[128 + c0] * invn - mu0 * mu0;
    float sc0 = gam[c0] * rsqrtf(va0 + BN_EPS), sh0 = bet[c0] - mu0 * sc0;
    float mu1 = stats[c1] * invn;
    float va1 = stats[128 + c1] * invn - mu1 * mu1;
    float sc1 = gam[c1] * rsqrtf(va1 + BN_EPS), sh1 = bet[c1] - mu1 * sc1;

    const int s0 = gstart[g], s1 = gstart[g + 1];
    float a0 = 0.f, a1 = 0.f;
    for (int i = s0 + q; i < s1; i += 8) {
        unsigned u = hp[(size_t)i * 64 + cp];
        a0 += fmaxf(fmaf(bflo(u), sc0, sh0), 0.f);
        a1 += fmaxf(fmaf(bfhi(u), sc1, sh1), 0.f);
    }
    red[q][cp] = make_float2(a0, a1);
    __syncthreads();
    if (q == 0) {
        float r0 = 0.f, r1 = 0.f;
#pragma unroll
        for (int k = 0; k < 8; ++k) { r0 += red[k][cp].x; r1 += red[k][cp].y; }
        const int cnt = s1 - s0;
        const float fc = (cnt > 0) ? (float)cnt : 1.0f;
        *(float2*)&pooled[(size_t)g * (3 * HD) + layerOff + c0] = make_float2(r0 / fc, r1 / fc);
    }
}

// ---------------- final linear + row L2 normalize ----------------

__global__ void final_kernel(const float* __restrict__ pooled, const float* __restrict__ linW,
                             const float* __restrict__ linb, float* __restrict__ out) {
    __shared__ float p[3 * HD];
    const int g = blockIdx.x;
    const int o = threadIdx.x;  // 64 threads = 1 wave
    for (int k = o; k < 3 * HD; k += 64) p[k] = pooled[(size_t)g * (3 * HD) + k];
    __syncthreads();
    float acc = linb[o];
    const float* wrow = linW + (size_t)o * (3 * HD);
#pragma unroll 4
    for (int k = 0; k < 3 * HD; k += 4) {
        float4 wv = *(const float4*)(wrow + k);
        float4 pv = *(const float4*)(&p[k]);
        acc = fmaf(wv.x, pv.x, acc);
        acc = fmaf(wv.y, pv.y, acc);
        acc = fmaf(wv.z, pv.z, acc);
        acc = fmaf(wv.w, pv.w, acc);
    }
    float sq = acc * acc;
#pragma unroll
    for (int off = 32; off > 0; off >>= 1) sq += __shfl_xor(sq, off);
    float nrm = sqrtf(sq);
    nrm = fmaxf(nrm, 1e-12f);
    out[(size_t)g * OD + o] = acc / nrm;
}

// ---------------- launch ----------------

extern "C" void kernel_launch(void* const* d_in, const int* in_sizes, int n_in,
                              void* d_out, int out_size, void* d_ws, size_t ws_size,
                              hipStream_t stream) {
    const float* x    = (const float*)d_in[0];
    const int* ei     = (const int*)d_in[1];
    const int* batch  = (const int*)d_in[2];
    const float* W11  = (const float*)d_in[3];
    const float* b11  = (const float*)d_in[4];
    const float* W12  = (const float*)d_in[5];
    const float* b12  = (const float*)d_in[6];
    const float* g1   = (const float*)d_in[7];
    const float* be1  = (const float*)d_in[8];
    const float* W21  = (const float*)d_in[9];
    const float* b21  = (const float*)d_in[10];
    const float* W22  = (const float*)d_in[11];
    const float* b22  = (const float*)d_in[12];
    const float* g2   = (const float*)d_in[13];
    const float* be2  = (const float*)d_in[14];
    const float* W31  = (const float*)d_in[15];
    const float* b31  = (const float*)d_in[16];
    const float* W32  = (const float*)d_in[17];
    const float* b32  = (const float*)d_in[18];
    const float* g3   = (const float*)d_in[19];
    const float* be3  = (const float*)d_in[20];
    const float* linW = (const float*)d_in[21];
    const float* linb = (const float*)d_in[22];

    const int* src = ei;
    const int* dst = ei + NE;

    char* ws = (char*)d_ws;
    size_t off = 0;
    auto alloc = [&](size_t bytes) -> void* {
        void* p = ws + off;
        off += (bytes + 255) & ~(size_t)255;
        return p;
    };
    int* deg      = (int*)alloc((size_t)NN * 4);
    int* offsets  = (int*)alloc((size_t)(NN + 1) * 4);
    int* cursor   = (int*)alloc((size_t)NN * 4);
    int* srcs     = (int*)alloc((size_t)NE * 4);
    int* gstart   = (int*)alloc((size_t)(NG + 1) * 4);
    int* lexcl    = (int*)alloc((size_t)NN * 4);
    int* bsum     = (int*)alloc((size_t)NSB * 4);
    int* boff     = (int*)alloc((size_t)NSB * 4);
    float* stats  = (float*)alloc(3 * 256 * 4);
    float* pooled = (float*)alloc((size_t)NG * 3 * HD * 4);
    unsigned short* xbf  = (unsigned short*)alloc((size_t)NN * HD * 2);
    unsigned short* cbf1 = (unsigned short*)alloc((size_t)NN * HD * 2);
    unsigned short* cbf2 = (unsigned short*)alloc((size_t)NN * HD * 2);
    unsigned short* wbf  = (unsigned short*)alloc((size_t)6 * HD * HD * 2);
    (void)ws_size; (void)n_in; (void)in_sizes; (void)out_size;

    // ---- weight + input conversions to bf16
    const int w8 = HD * HD / 8;  // 2048
    cvt_kernel<<<(NN * HD / 8 + 255) / 256, 256, 0, stream>>>(x, xbf, NN * HD / 8);
    cvt_kernel<<<(w8 + 255) / 256, 256, 0, stream>>>(W11, wbf + 0 * HD * HD, w8);
    cvt_kernel<<<(w8 + 255) / 256, 256, 0, stream>>>(W12, wbf + 1 * HD * HD, w8);
    cvt_kernel<<<(w8 + 255) / 256, 256, 0, stream>>>(W21, wbf + 2 * HD * HD, w8);
    cvt_kernel<<<(w8 + 255) / 256, 256, 0, stream>>>(W22, wbf + 3 * HD * HD, w8);
    cvt_kernel<<<(w8 + 255) / 256, 256, 0, stream>>>(W31, wbf + 4 * HD * HD, w8);
    cvt_kernel<<<(w8 + 255) / 256, 256, 0, stream>>>(W32, wbf + 5 * HD * HD, w8);

    // ---- CSR build
    hipMemsetAsync(deg, 0, (size_t)NN * 4, stream);
    hist_kernel<<<(NE + 255) / 256, 256, 0, stream>>>(dst, deg, NE);
    local_scan_kernel<<<NSB, SCAN_BLK, 0, stream>>>(deg, lexcl, bsum, NN);
    scan_bsum_kernel<<<1, 64, 0, stream>>>(bsum, boff, offsets, NSB, NN);
    finalize_scan_kernel<<<(NN + 255) / 256, 256, 0, stream>>>(lexcl, boff, offsets, cursor, NN);
    fill_kernel<<<(NE + 255) / 256, 256, 0, stream>>>(src, dst, cursor, srcs, NE);
    gstart_kernel<<<(NN + 255) / 256, 256, 0, stream>>>(batch, gstart, NN, NG);

    hipMemsetAsync(stats, 0, 3 * 256 * 4, stream);

    const int ginGrid = (NN + 63) / 64;  // 782

    const unsigned* xu  = (const unsigned*)xbf;
    const unsigned* c1u = (const unsigned*)cbf1;
    const unsigned* c2u = (const unsigned*)cbf2;

    // L1: gather x (identity) -> cbf1
    fused_gin<false><<<ginGrid, 256, 0, stream>>>(xu, offsets, srcs, stats, g1, be1,
                                                  wbf + 0 * HD * HD, b11, wbf + 1 * HD * HD, b12,
                                                  cbf1, NN);
    bn_stats_bf<<<256, 256, 0, stream>>>(c1u, stats + 0, NN);
    pool_bn<<<NG, 512, 0, stream>>>(c1u, gstart, stats + 0, g1, be1, pooled, 0);

    // L2: gather h1 = relu(BN1(c1)) -> cbf2
    fused_gin<true><<<ginGrid, 256, 0, stream>>>(c1u, offsets, srcs, stats + 0, g1, be1,
                                                 wbf + 2 * HD * HD, b21, wbf + 3 * HD * HD, b22,
                                                 cbf2, NN);
    bn_stats_bf<<<256, 256, 0, stream>>>(c2u, stats + 256, NN);
    pool_bn<<<NG, 512, 0, stream>>>(c2u, gstart, stats + 256, g2, be2, pooled, HD);

    // L3: gather h2 = relu(BN2(c2)) -> cbf1 (reuse)
    fused_gin<true><<<ginGrid, 256, 0, stream>>>(c2u, offsets, srcs, stats + 256, g2, be2,
                                                 wbf + 4 * HD * HD, b31, wbf + 5 * HD * HD, b32,
                                                 cbf1, NN);
    bn_stats_bf<<<256, 256, 0, stream>>>(c1u, stats + 512, NN);
    pool_bn<<<NG, 512, 0, stream>>>(c1u, gstart, stats + 512, g3, be3, pooled, 2 * HD);

    final_kernel<<<NG, OD, 0, stream>>>(pooled, linW, linb, (float*)d_out);
}

// Round 8
// 304.731 us; speedup vs baseline: 15.4226x; 1.1605x over previous
//
#include <hip/hip_runtime.h>

#define NN 50000
#define NE 600000
#define HD 128
#define NG 512
#define OD 64
#define BN_EPS 1e-5f

#define SCAN_BLK 1024
#define NSB ((NN + SCAN_BLK - 1) / SCAN_BLK)  // 49
#define ECAP 1536  // LDS edge-index capacity (mean 768/block; fallback path if exceeded)

typedef __attribute__((ext_vector_type(8))) short bf16x8;
typedef __attribute__((ext_vector_type(4))) float f32x4;

__device__ __forceinline__ unsigned short f2bf(float f) {
    unsigned u = __builtin_bit_cast(unsigned, f);
    unsigned r = u + 0x7FFFu + ((u >> 16) & 1u);  // round-to-nearest-even
    return (unsigned short)(r >> 16);
}

__device__ __forceinline__ float bflo(unsigned u) { return __builtin_bit_cast(float, u << 16); }
__device__ __forceinline__ float bfhi(unsigned u) { return __builtin_bit_cast(float, u & 0xffff0000u); }

__device__ __forceinline__ unsigned packbf2(float x, float y) {
    return (unsigned)f2bf(x) | ((unsigned)f2bf(y) << 16);
}

// ---------------- fp32 -> bf16 bulk converts ----------------

__global__ void cvt_kernel(const float* __restrict__ src, unsigned short* __restrict__ dst, int n8) {
    int i = blockIdx.x * blockDim.x + threadIdx.x;
    if (i >= n8) return;
    float4 a = ((const float4*)src)[2 * i];
    float4 b = ((const float4*)src)[2 * i + 1];
    uint4 o;
    o.x = packbf2(a.x, a.y);
    o.y = packbf2(a.z, a.w);
    o.z = packbf2(b.x, b.y);
    o.w = packbf2(b.z, b.w);
    ((uint4*)dst)[i] = o;
}

__global__ void cvt6_kernel(const float* __restrict__ s0, const float* __restrict__ s1,
                            const float* __restrict__ s2, const float* __restrict__ s3,
                            const float* __restrict__ s4, const float* __restrict__ s5,
                            unsigned short* __restrict__ dst) {
    int i = blockIdx.x * blockDim.x + threadIdx.x;  // 0 .. 6*2048-1
    const int wsel = i >> 11;
    const int o8 = i & 2047;
    const float* sp = (wsel == 0) ? s0 : (wsel == 1) ? s1 : (wsel == 2) ? s2
                    : (wsel == 3) ? s3 : (wsel == 4) ? s4 : s5;
    float4 a = ((const float4*)sp)[2 * o8];
    float4 b = ((const float4*)sp)[2 * o8 + 1];
    uint4 o;
    o.x = packbf2(a.x, a.y);
    o.y = packbf2(a.z, a.w);
    o.z = packbf2(b.x, b.y);
    o.w = packbf2(b.z, b.w);
    ((uint4*)(dst + (size_t)wsel * HD * HD))[o8] = o;
}

// ---------------- CSR build ----------------

__global__ void hist_kernel(const int* __restrict__ dst, int* __restrict__ deg, int E) {
    int i = blockIdx.x * blockDim.x + threadIdx.x;
    if (i < E) atomicAdd(&deg[dst[i]], 1);
}

__global__ void local_scan_kernel(const int* __restrict__ deg, int* __restrict__ lexcl,
                                  int* __restrict__ bsum, int n) {
    __shared__ int part[SCAN_BLK];
    const int tid = threadIdx.x;
    const int i = blockIdx.x * SCAN_BLK + tid;
    int v = (i < n) ? deg[i] : 0;
    part[tid] = v;
    __syncthreads();
    int incl = v;
    for (int off = 1; off < SCAN_BLK; off <<= 1) {
        int t = (tid >= off) ? part[tid - off] : 0;
        __syncthreads();
        incl += t;
        part[tid] = incl;
        __syncthreads();
    }
    if (i < n) lexcl[i] = incl - v;
    if (tid == SCAN_BLK - 1) bsum[blockIdx.x] = incl;
}

__global__ void scan_bsum_kernel(const int* __restrict__ bsum, int* __restrict__ boff,
                                 int* __restrict__ offsets, int nb, int n) {
    const int tid = threadIdx.x;  // 64 threads
    int orig = (tid < nb) ? bsum[tid] : 0;
    int v = orig;
    for (int off = 1; off < 64; off <<= 1) {
        int t = __shfl_up(v, off);
        if (tid >= off) v += t;
    }
    if (tid < nb) boff[tid] = v - orig;
    if (tid == 63) offsets[n] = v;  // total = E
}

__global__ void finalize_scan_kernel(const int* __restrict__ lexcl, const int* __restrict__ boff,
                                     int* __restrict__ offsets, int* __restrict__ cursor, int n) {
    int i = blockIdx.x * blockDim.x + threadIdx.x;
    if (i < n) {
        int o = lexcl[i] + boff[i >> 10];
        offsets[i] = o;
        cursor[i] = o;
    }
}

__global__ void fill_kernel(const int* __restrict__ src, const int* __restrict__ dst,
                            int* __restrict__ cursor, int* __restrict__ srcs, int E) {
    int i = blockIdx.x * blockDim.x + threadIdx.x;
    if (i < E) {
        int pos = atomicAdd(&cursor[dst[i]], 1);
        srcs[pos] = src[i];
    }
}

__global__ void gstart_kernel(const int* __restrict__ batch, int* __restrict__ gstart,
                              int n, int G) {
    int i = blockIdx.x * blockDim.x + threadIdx.x;
    if (i >= n) return;
    int b = batch[i];
    int bp = (i == 0) ? -1 : batch[i - 1];
    for (int g = bp + 1; g <= b; ++g) gstart[g] = i;
    if (i == n - 1) {
        for (int g = b + 1; g <= G; ++g) gstart[g] = n;
    }
}

// ---------------- fused GIN layer: [BN+relu] gather + 2xMFMA MLP + BN stats ----------------
// h = DOBN ? relu(sc*c+sh) : c  per gathered element
// C = relu((h_i + sum_nbr h_j) @ Wa^T + ba) @ Wb^T + bb   -> bf16 out
// statsOut[c] += sum_rows C[:,c]; statsOut[128+c] += sum_rows C[:,c]^2
// 512 threads = 8 waves: gather 8 rows/wave; MFMA wave tile 32x32 (wr=w>>2, wc=w&3).

template <bool DOBN>
__global__ __launch_bounds__(512) void fused_gin(const unsigned* __restrict__ hp,
                                                 const int* __restrict__ offsets,
                                                 const int* __restrict__ srcs,
                                                 const float* __restrict__ statsIn,
                                                 const float* __restrict__ gam,
                                                 const float* __restrict__ bet,
                                                 const unsigned short* __restrict__ WaBf,
                                                 const float* __restrict__ ba,
                                                 const unsigned short* __restrict__ WbBf,
                                                 const float* __restrict__ bb,
                                                 unsigned short* __restrict__ Cb,
                                                 float* __restrict__ statsOut,
                                                 int nrows) {
    __shared__ short SB[64 * 136];
    __shared__ int elds[ECAP];
    __shared__ float sred[2][128][2];

    const int t = threadIdx.x;
    const int lane = t & 63;
    const int w = t >> 6;      // wave 0..7
    const int row0 = blockIdx.x * 64;

    float sc0 = 1.f, sh0 = 0.f, sc1 = 1.f, sh1 = 0.f;
    if (DOBN) {
        const float invn = 1.0f / (float)NN;
        const int c0 = 2 * lane, c1 = c0 + 1;
        float mu0 = statsIn[c0] * invn;
        float va0 = statsIn[128 + c0] * invn - mu0 * mu0;
        sc0 = gam[c0] * rsqrtf(va0 + BN_EPS);
        sh0 = bet[c0] - mu0 * sc0;
        float mu1 = statsIn[c1] * invn;
        float va1 = statsIn[128 + c1] * invn - mu1 * mu1;
        sc1 = gam[c1] * rsqrtf(va1 + BN_EPS);
        sh1 = bet[c1] - mu1 * sc1;
    }

    auto xf = [&](unsigned u, float& x, float& y) {
        x = bflo(u);
        y = bfhi(u);
        if (DOBN) {
            x = fmaxf(fmaf(x, sc0, sh0), 0.f);
            y = fmaxf(fmaf(y, sc1, sh1), 0.f);
        }
    };

    const int rend = (row0 + 64 < nrows) ? row0 + 64 : nrows;
    const int ebase = offsets[row0];
    const int cnt = offsets[rend] - ebase;
    const bool fast = (cnt <= ECAP);

    if (fast) {
        for (int k = t; k < cnt; k += 512) elds[k] = srcs[ebase + k];
    }
    __syncthreads();

    // ---- gather: wave w owns rows w*8 .. w*8+7
    for (int i = 0; i < 8; ++i) {
        const int r = w * 8 + i;
        const int grow = row0 + r;
        float ax = 0.f, ay = 0.f;
        if (grow < nrows) {
            {
                float x, y;
                xf(hp[(size_t)grow * 64 + lane], x, y);
                ax = x; ay = y;
            }
            const int j0 = offsets[grow], e1 = offsets[grow + 1];
            if (fast) {
                int jj = j0 - ebase;
                const int ee = e1 - ebase;
                for (; jj + 7 < ee; jj += 8) {
                    const int s0 = elds[jj], s1 = elds[jj + 1], s2 = elds[jj + 2], s3 = elds[jj + 3];
                    const int s4 = elds[jj + 4], s5 = elds[jj + 5], s6 = elds[jj + 6], s7 = elds[jj + 7];
                    unsigned v0 = hp[(size_t)s0 * 64 + lane];
                    unsigned v1 = hp[(size_t)s1 * 64 + lane];
                    unsigned v2 = hp[(size_t)s2 * 64 + lane];
                    unsigned v3 = hp[(size_t)s3 * 64 + lane];
                    unsigned v4 = hp[(size_t)s4 * 64 + lane];
                    unsigned v5 = hp[(size_t)s5 * 64 + lane];
                    unsigned v6 = hp[(size_t)s6 * 64 + lane];
                    unsigned v7 = hp[(size_t)s7 * 64 + lane];
                    float x, y;
                    xf(v0, x, y); ax += x; ay += y;
                    xf(v1, x, y); ax += x; ay += y;
                    xf(v2, x, y); ax += x; ay += y;
                    xf(v3, x, y); ax += x; ay += y;
                    xf(v4, x, y); ax += x; ay += y;
                    xf(v5, x, y); ax += x; ay += y;
                    xf(v6, x, y); ax += x; ay += y;
                    xf(v7, x, y); ax += x; ay += y;
                }
                for (; jj + 3 < ee; jj += 4) {
                    const int s0 = elds[jj], s1 = elds[jj + 1], s2 = elds[jj + 2], s3 = elds[jj + 3];
                    unsigned v0 = hp[(size_t)s0 * 64 + lane];
                    unsigned v1 = hp[(size_t)s1 * 64 + lane];
                    unsigned v2 = hp[(size_t)s2 * 64 + lane];
                    unsigned v3 = hp[(size_t)s3 * 64 + lane];
                    float x, y;
                    xf(v0, x, y); ax += x; ay += y;
                    xf(v1, x, y); ax += x; ay += y;
                    xf(v2, x, y); ax += x; ay += y;
                    xf(v3, x, y); ax += x; ay += y;
                }
                for (; jj < ee; ++jj) {
                    unsigned v = hp[(size_t)elds[jj] * 64 + lane];
                    float x, y;
                    xf(v, x, y); ax += x; ay += y;
                }
            } else {
                for (int j = j0; j < e1; ++j) {
                    unsigned v = hp[(size_t)srcs[j] * 64 + lane];
                    float x, y;
                    xf(v, x, y); ax += x; ay += y;
                }
            }
        }
        *(unsigned*)&SB[r * 136 + 2 * lane] = packbf2(ax, ay);
    }
    __syncthreads();  // SB holds A

    const int wr = w >> 2;     // row half (32 rows)
    const int wc = w & 3;      // col quarter (32 cols)
    const int l15 = lane & 15;
    const int l4 = lane >> 4;  // 0..3

    // ---- MFMA pass 1: t = A @ Wa^T
    f32x4 acc[2][2];
#pragma unroll
    for (int m = 0; m < 2; ++m)
#pragma unroll
        for (int n = 0; n < 2; ++n) acc[m][n] = (f32x4){0.f, 0.f, 0.f, 0.f};

#pragma unroll
    for (int kk = 0; kk < 4; ++kk) {
        bf16x8 af[2], bfr[2];
#pragma unroll
        for (int m = 0; m < 2; ++m)
            af[m] = *(const bf16x8*)&SB[(wr * 32 + m * 16 + l15) * 136 + kk * 32 + l4 * 8];
#pragma unroll
        for (int n = 0; n < 2; ++n)
            bfr[n] = *(const bf16x8*)(WaBf + (size_t)(wc * 32 + n * 16 + l15) * HD + kk * 32 + l4 * 8);
#pragma unroll
        for (int m = 0; m < 2; ++m)
#pragma unroll
            for (int n = 0; n < 2; ++n)
                acc[m][n] = __builtin_amdgcn_mfma_f32_16x16x32_bf16(af[m], bfr[n], acc[m][n], 0, 0, 0);
    }
    __syncthreads();  // pass-1 SB reads complete

    // epilogue 1: relu(t + ba) -> SB (as A2, bf16)
#pragma unroll
    for (int n = 0; n < 2; ++n) {
        const int col = wc * 32 + n * 16 + l15;
        const float bav = ba[col];
#pragma unroll
        for (int m = 0; m < 2; ++m) {
#pragma unroll
            for (int j = 0; j < 4; ++j) {
                const int row = wr * 32 + m * 16 + l4 * 4 + j;
                SB[row * 136 + col] = (short)f2bf(fmaxf(acc[m][n][j] + bav, 0.f));
            }
        }
    }
    __syncthreads();  // A2 visible

    // ---- MFMA pass 2: C = A2 @ Wb^T
#pragma unroll
    for (int m = 0; m < 2; ++m)
#pragma unroll
        for (int n = 0; n < 2; ++n) acc[m][n] = (f32x4){0.f, 0.f, 0.f, 0.f};

#pragma unroll
    for (int kk = 0; kk < 4; ++kk) {
        bf16x8 af[2], bfr[2];
#pragma unroll
        for (int m = 0; m < 2; ++m)
            af[m] = *(const bf16x8*)&SB[(wr * 32 + m * 16 + l15) * 136 + kk * 32 + l4 * 8];
#pragma unroll
        for (int n = 0; n < 2; ++n)
            bfr[n] = *(const bf16x8*)(WbBf + (size_t)(wc * 32 + n * 16 + l15) * HD + kk * 32 + l4 * 8);
#pragma unroll
        for (int m = 0; m < 2; ++m)
#pragma unroll
            for (int n = 0; n < 2; ++n)
                acc[m][n] = __builtin_amdgcn_mfma_f32_16x16x32_bf16(af[m], bfr[n], acc[m][n], 0, 0, 0);
    }

    // epilogue 2: Cb = bf16(acc + bb), plus per-column stats partials
    float st00 = 0.f, st01 = 0.f, st10 = 0.f, st11 = 0.f;  // [n][sum|sumsq]
#pragma unroll
    for (int n = 0; n < 2; ++n) {
        const int col = wc * 32 + n * 16 + l15;
        const float bbv = bb[col];
#pragma unroll
        for (int m = 0; m < 2; ++m) {
#pragma unroll
            for (int j = 0; j < 4; ++j) {
                const int row = row0 + wr * 32 + m * 16 + l4 * 4 + j;
                if (row < nrows) {
                    float v = acc[m][n][j] + bbv;
                    Cb[(size_t)row * HD + col] = f2bf(v);
                    if (n == 0) { st00 += v; st01 = fmaf(v, v, st01); }
                    else        { st10 += v; st11 = fmaf(v, v, st11); }
                }
            }
        }
    }
    // reduce over l4 (lane bits 4,5)
#pragma unroll
    for (int d = 16; d < 64; d <<= 1) {
        st00 += __shfl_xor(st00, d);
        st01 += __shfl_xor(st01, d);
        st10 += __shfl_xor(st10, d);
        st11 += __shfl_xor(st11, d);
    }
    if (l4 == 0) {  // lanes 0..15
        const int c0 = wc * 32 + l15, c1 = c0 + 16;
        sred[wr][c0][0] = st00; sred[wr][c0][1] = st01;
        sred[wr][c1][0] = st10; sred[wr][c1][1] = st11;
    }
    __syncthreads();
    if (t < 128) {
        atomicAdd(&statsOut[t], sred[0][t][0] + sred[1][t][0]);
        atomicAdd(&statsOut[128 + t], sred[0][t][1] + sred[1][t][1]);
    }
}

// ---------------- mean pool with BN+relu applied on the fly ----------------

__global__ void pool_bn(const unsigned* __restrict__ hp, const int* __restrict__ gstart,
                        const float* __restrict__ stats, const float* __restrict__ gam,
                        const float* __restrict__ bet, float* __restrict__ pooled, int layerOff) {
    __shared__ float2 red[8][64];
    const int g = blockIdx.x;
    const int tx = threadIdx.x;  // 512
    const int cp = tx & 63;
    const int q = tx >> 6;       // 0..7
    const float invn = 1.0f / (float)NN;
    const int c0 = 2 * cp, c1 = c0 + 1;
    float mu0 = stats[c0] * invn;
    float va0 = stats[128 + c0] * invn - mu0 * mu0;
    float sc0 = gam[c0] * rsqrtf(va0 + BN_EPS), sh0 = bet[c0] - mu0 * sc0;
    float mu1 = stats[c1] * invn;
    float va1 = stats[128 + c1] * invn - mu1 * mu1;
    float sc1 = gam[c1] * rsqrtf(va1 + BN_EPS), sh1 = bet[c1] - mu1 * sc1;

    const int s0 = gstart[g], s1 = gstart[g + 1];
    float a0 = 0.f, a1 = 0.f;
    for (int i = s0 + q; i < s1; i += 8) {
        unsigned u = hp[(size_t)i * 64 + cp];
        a0 += fmaxf(fmaf(bflo(u), sc0, sh0), 0.f);
        a1 += fmaxf(fmaf(bfhi(u), sc1, sh1), 0.f);
    }
    red[q][cp] = make_float2(a0, a1);
    __syncthreads();
    if (q == 0) {
        float r0 = 0.f, r1 = 0.f;
#pragma unroll
        for (int k = 0; k < 8; ++k) { r0 += red[k][cp].x; r1 += red[k][cp].y; }
        const int cnt = s1 - s0;
        const float fc = (cnt > 0) ? (float)cnt : 1.0f;
        *(float2*)&pooled[(size_t)g * (3 * HD) + layerOff + c0] = make_float2(r0 / fc, r1 / fc);
    }
}

// ---------------- final linear + row L2 normalize ----------------

__global__ void final_kernel(const float* __restrict__ pooled, const float* __restrict__ linW,
                             const float* __restrict__ linb, float* __restrict__ out) {
    __shared__ float p[3 * HD];
    const int g = blockIdx.x;
    const int o = threadIdx.x;  // 64 threads = 1 wave
    for (int k = o; k < 3 * HD; k += 64) p[k] = pooled[(size_t)g * (3 * HD) + k];
    __syncthreads();
    float acc = linb[o];
    const float* wrow = linW + (size_t)o * (3 * HD);
#pragma unroll 4
    for (int k = 0; k < 3 * HD; k += 4) {
        float4 wv = *(const float4*)(wrow + k);
        float4 pv = *(const float4*)(&p[k]);
        acc = fmaf(wv.x, pv.x, acc);
        acc = fmaf(wv.y, pv.y, acc);
        acc = fmaf(wv.z, pv.z, acc);
        acc = fmaf(wv.w, pv.w, acc);
    }
    float sq = acc * acc;
#pragma unroll
    for (int off = 32; off > 0; off >>= 1) sq += __shfl_xor(sq, off);
    float nrm = sqrtf(sq);
    nrm = fmaxf(nrm, 1e-12f);
    out[(size_t)g * OD + o] = acc / nrm;
}

// ---------------- launch ----------------

extern "C" void kernel_launch(void* const* d_in, const int* in_sizes, int n_in,
                              void* d_out, int out_size, void* d_ws, size_t ws_size,
                              hipStream_t stream) {
    const float* x    = (const float*)d_in[0];
    const int* ei     = (const int*)d_in[1];
    const int* batch  = (const int*)d_in[2];
    const float* W11  = (const float*)d_in[3];
    const float* b11  = (const float*)d_in[4];
    const float* W12  = (const float*)d_in[5];
    const float* b12  = (const float*)d_in[6];
    const float* g1   = (const float*)d_in[7];
    const float* be1  = (const float*)d_in[8];
    const float* W21  = (const float*)d_in[9];
    const float* b21  = (const float*)d_in[10];
    const float* W22  = (const float*)d_in[11];
    const float* b22  = (const float*)d_in[12];
    const float* g2   = (const float*)d_in[13];
    const float* be2  = (const float*)d_in[14];
    const float* W31  = (const float*)d_in[15];
    const float* b31  = (const float*)d_in[16];
    const float* W32  = (const float*)d_in[17];
    const float* b32  = (const float*)d_in[18];
    const float* g3   = (const float*)d_in[19];
    const float* be3  = (const float*)d_in[20];
    const float* linW = (const float*)d_in[21];
    const float* linb = (const float*)d_in[22];

    const int* src = ei;
    const int* dst = ei + NE;

    char* ws = (char*)d_ws;
    size_t off = 0;
    auto alloc = [&](size_t bytes) -> void* {
        void* p = ws + off;
        off += (bytes + 255) & ~(size_t)255;
        return p;
    };
    int* deg      = (int*)alloc((size_t)NN * 4);
    int* offsets  = (int*)alloc((size_t)(NN + 1) * 4);
    int* cursor   = (int*)alloc((size_t)NN * 4);
    int* srcs     = (int*)alloc((size_t)NE * 4);
    int* gstart   = (int*)alloc((size_t)(NG + 1) * 4);
    int* lexcl    = (int*)alloc((size_t)NN * 4);
    int* bsum     = (int*)alloc((size_t)NSB * 4);
    int* boff     = (int*)alloc((size_t)NSB * 4);
    float* stats  = (float*)alloc(3 * 256 * 4);
    float* pooled = (float*)alloc((size_t)NG * 3 * HD * 4);
    unsigned short* xbf  = (unsigned short*)alloc((size_t)NN * HD * 2);
    unsigned short* cbf1 = (unsigned short*)alloc((size_t)NN * HD * 2);
    unsigned short* cbf2 = (unsigned short*)alloc((size_t)NN * HD * 2);
    unsigned short* wbf  = (unsigned short*)alloc((size_t)6 * HD * HD * 2);
    (void)ws_size; (void)n_in; (void)in_sizes; (void)out_size;

    // ---- conversions to bf16
    cvt_kernel<<<(NN * HD / 8 + 255) / 256, 256, 0, stream>>>(x, xbf, NN * HD / 8);
    cvt6_kernel<<<48, 256, 0, stream>>>(W11, W12, W21, W22, W31, W32, wbf);

    // ---- CSR build
    hipMemsetAsync(deg, 0, (size_t)NN * 4, stream);
    hist_kernel<<<(NE + 255) / 256, 256, 0, stream>>>(dst, deg, NE);
    local_scan_kernel<<<NSB, SCAN_BLK, 0, stream>>>(deg, lexcl, bsum, NN);
    scan_bsum_kernel<<<1, 64, 0, stream>>>(bsum, boff, offsets, NSB, NN);
    finalize_scan_kernel<<<(NN + 255) / 256, 256, 0, stream>>>(lexcl, boff, offsets, cursor, NN);
    fill_kernel<<<(NE + 255) / 256, 256, 0, stream>>>(src, dst, cursor, srcs, NE);
    gstart_kernel<<<(NN + 255) / 256, 256, 0, stream>>>(batch, gstart, NN, NG);

    hipMemsetAsync(stats, 0, 3 * 256 * 4, stream);

    const int ginGrid = (NN + 63) / 64;  // 782

    const unsigned* xu  = (const unsigned*)xbf;
    const unsigned* c1u = (const unsigned*)cbf1;
    const unsigned* c2u = (const unsigned*)cbf2;

    // L1: gather x (identity) -> cbf1, stats -> stats+0
    fused_gin<false><<<ginGrid, 512, 0, stream>>>(xu, offsets, srcs, stats, g1, be1,
                                                  wbf + 0 * HD * HD, b11, wbf + 1 * HD * HD, b12,
                                                  cbf1, stats + 0, NN);
    pool_bn<<<NG, 512, 0, stream>>>(c1u, gstart, stats + 0, g1, be1, pooled, 0);

    // L2: gather h1 = relu(BN1(c1)) -> cbf2, stats -> stats+256
    fused_gin<true><<<ginGrid, 512, 0, stream>>>(c1u, offsets, srcs, stats + 0, g1, be1,
                                                 wbf + 2 * HD * HD, b21, wbf + 3 * HD * HD, b22,
                                                 cbf2, stats + 256, NN);
    pool_bn<<<NG, 512, 0, stream>>>(c2u, gstart, stats + 256, g2, be2, pooled, HD);

    // L3: gather h2 = relu(BN2(c2)) -> cbf1 (reuse), stats -> stats+512
    fused_gin<true><<<ginGrid, 512, 0, stream>>>(c2u, offsets, srcs, stats + 256, g2, be2,
                                                 wbf + 4 * HD * HD, b31, wbf + 5 * HD * HD, b32,
                                                 cbf1, stats + 512, NN);
    pool_bn<<<NG, 512, 0, stream>>>(c1u, gstart, stats + 512, g3, be3, pooled, 2 * HD);

    final_kernel<<<NG, OD, 0, stream>>>(pooled, linW, linb, (float*)d_out);
}

// Round 9
// 298.147 us; speedup vs baseline: 15.7632x; 1.0221x over previous
//
#include <hip/hip_runtime.h>

#define NN 50000
#define NE 600000
#define HD 128
#define NG 512
#define OD 64
#define BN_EPS 1e-5f

#define SCAN_BLK 1024
#define NSB ((NN + SCAN_BLK - 1) / SCAN_BLK)  // 49
#define ECAP 1536   // LDS edge-index capacity (mean 768/block; fallback if exceeded)
#define NBANK 8     // stats atomic shards

typedef __attribute__((ext_vector_type(8))) short bf16x8;
typedef __attribute__((ext_vector_type(4))) float f32x4;

__device__ __forceinline__ unsigned short f2bf(float f) {
    unsigned u = __builtin_bit_cast(unsigned, f);
    unsigned r = u + 0x7FFFu + ((u >> 16) & 1u);  // round-to-nearest-even
    return (unsigned short)(r >> 16);
}

__device__ __forceinline__ float bflo(unsigned u) { return __builtin_bit_cast(float, u << 16); }
__device__ __forceinline__ float bfhi(unsigned u) { return __builtin_bit_cast(float, u & 0xffff0000u); }

__device__ __forceinline__ unsigned packbf2(float x, float y) {
    return (unsigned)f2bf(x) | ((unsigned)f2bf(y) << 16);
}

// ---------------- fp32 -> bf16 bulk converts ----------------

__global__ void cvt_kernel(const float* __restrict__ src, unsigned short* __restrict__ dst, int n8) {
    int i = blockIdx.x * blockDim.x + threadIdx.x;
    if (i >= n8) return;
    float4 a = ((const float4*)src)[2 * i];
    float4 b = ((const float4*)src)[2 * i + 1];
    uint4 o;
    o.x = packbf2(a.x, a.y);
    o.y = packbf2(a.z, a.w);
    o.z = packbf2(b.x, b.y);
    o.w = packbf2(b.z, b.w);
    ((uint4*)dst)[i] = o;
}

__global__ void cvt6_kernel(const float* __restrict__ s0, const float* __restrict__ s1,
                            const float* __restrict__ s2, const float* __restrict__ s3,
                            const float* __restrict__ s4, const float* __restrict__ s5,
                            unsigned short* __restrict__ dst) {
    int i = blockIdx.x * blockDim.x + threadIdx.x;  // 0 .. 6*2048-1
    const int wsel = i >> 11;
    const int o8 = i & 2047;
    const float* sp = (wsel == 0) ? s0 : (wsel == 1) ? s1 : (wsel == 2) ? s2
                    : (wsel == 3) ? s3 : (wsel == 4) ? s4 : s5;
    float4 a = ((const float4*)sp)[2 * o8];
    float4 b = ((const float4*)sp)[2 * o8 + 1];
    uint4 o;
    o.x = packbf2(a.x, a.y);
    o.y = packbf2(a.z, a.w);
    o.z = packbf2(b.x, b.y);
    o.w = packbf2(b.z, b.w);
    ((uint4*)(dst + (size_t)wsel * HD * HD))[o8] = o;
}

// ---------------- CSR build ----------------

__global__ void hist_kernel(const int* __restrict__ dst, int* __restrict__ deg, int E) {
    int i = blockIdx.x * blockDim.x + threadIdx.x;
    if (i < E) atomicAdd(&deg[dst[i]], 1);
}

__global__ void local_scan_kernel(const int* __restrict__ deg, int* __restrict__ lexcl,
                                  int* __restrict__ bsum, int n) {
    __shared__ int part[SCAN_BLK];
    const int tid = threadIdx.x;
    const int i = blockIdx.x * SCAN_BLK + tid;
    int v = (i < n) ? deg[i] : 0;
    part[tid] = v;
    __syncthreads();
    int incl = v;
    for (int off = 1; off < SCAN_BLK; off <<= 1) {
        int t = (tid >= off) ? part[tid - off] : 0;
        __syncthreads();
        incl += t;
        part[tid] = incl;
        __syncthreads();
    }
    if (i < n) lexcl[i] = incl - v;
    if (tid == SCAN_BLK - 1) bsum[blockIdx.x] = incl;
}

__global__ void scan_bsum_kernel(const int* __restrict__ bsum, int* __restrict__ boff,
                                 int* __restrict__ offsets, int nb, int n) {
    const int tid = threadIdx.x;  // 64 threads
    int orig = (tid < nb) ? bsum[tid] : 0;
    int v = orig;
    for (int off = 1; off < 64; off <<= 1) {
        int t = __shfl_up(v, off);
        if (tid >= off) v += t;
    }
    if (tid < nb) boff[tid] = v - orig;
    if (tid == 63) offsets[n] = v;  // total = E
}

__global__ void finalize_scan_kernel(const int* __restrict__ lexcl, const int* __restrict__ boff,
                                     int* __restrict__ offsets, int* __restrict__ cursor, int n) {
    int i = blockIdx.x * blockDim.x + threadIdx.x;
    if (i < n) {
        int o = lexcl[i] + boff[i >> 10];
        offsets[i] = o;
        cursor[i] = o;
    }
}

__global__ void fill_kernel(const int* __restrict__ src, const int* __restrict__ dst,
                            int* __restrict__ cursor, int* __restrict__ srcs, int E) {
    int i = blockIdx.x * blockDim.x + threadIdx.x;
    if (i < E) {
        int pos = atomicAdd(&cursor[dst[i]], 1);
        srcs[pos] = src[i];
    }
}

__global__ void gstart_kernel(const int* __restrict__ batch, int* __restrict__ gstart,
                              int n, int G) {
    int i = blockIdx.x * blockDim.x + threadIdx.x;
    if (i >= n) return;
    int b = batch[i];
    int bp = (i == 0) ? -1 : batch[i - 1];
    for (int g = bp + 1; g <= b; ++g) gstart[g] = i;
    if (i == n - 1) {
        for (int g = b + 1; g <= G; ++g) gstart[g] = n;
    }
}

// ---------------- fused GIN layer ----------------
// h = DOBN ? relu(sc*c+sh) : c  per gathered element (stats summed over NBANK shards)
// C = relu((h_i + sum_nbr h_j) @ Wa^T + ba) @ Wb^T + bb  -> bf16 out
// stats partials atomically added to shard (blockIdx & 7).
// 512 threads = 8 waves; gather rows in PAIRS (16 loads in flight).

template <bool DOBN>
__global__ __launch_bounds__(512) void fused_gin(const unsigned* __restrict__ hp,
                                                 const int* __restrict__ offsets,
                                                 const int* __restrict__ srcs,
                                                 const float* __restrict__ statsIn,
                                                 const float* __restrict__ gam,
                                                 const float* __restrict__ bet,
                                                 const unsigned short* __restrict__ WaBf,
                                                 const float* __restrict__ ba,
                                                 const unsigned short* __restrict__ WbBf,
                                                 const float* __restrict__ bb,
                                                 unsigned short* __restrict__ Cb,
                                                 float* __restrict__ statsOut,
                                                 int nrows) {
    __shared__ short SB[64 * 136];
    __shared__ int elds[ECAP];
    __shared__ float sred[2][128][2];

    const int t = threadIdx.x;
    const int lane = t & 63;
    const int w = t >> 6;      // wave 0..7
    const int row0 = blockIdx.x * 64;

    float sc0 = 1.f, sh0 = 0.f, sc1 = 1.f, sh1 = 0.f;
    if (DOBN) {
        const float invn = 1.0f / (float)NN;
        const int c0 = 2 * lane, c1 = c0 + 1;
        float su0 = 0.f, sq0 = 0.f, su1 = 0.f, sq1 = 0.f;
#pragma unroll
        for (int b = 0; b < NBANK; ++b) {
            su0 += statsIn[b * 256 + c0];
            sq0 += statsIn[b * 256 + 128 + c0];
            su1 += statsIn[b * 256 + c1];
            sq1 += statsIn[b * 256 + 128 + c1];
        }
        float mu0 = su0 * invn;
        float va0 = sq0 * invn - mu0 * mu0;
        sc0 = gam[c0] * rsqrtf(va0 + BN_EPS);
        sh0 = bet[c0] - mu0 * sc0;
        float mu1 = su1 * invn;
        float va1 = sq1 * invn - mu1 * mu1;
        sc1 = gam[c1] * rsqrtf(va1 + BN_EPS);
        sh1 = bet[c1] - mu1 * sc1;
    }

    auto xf = [&](unsigned u, float& x, float& y) {
        x = bflo(u);
        y = bfhi(u);
        if (DOBN) {
            x = fmaxf(fmaf(x, sc0, sh0), 0.f);
            y = fmaxf(fmaf(y, sc1, sh1), 0.f);
        }
    };
    auto ld = [&](int s) -> unsigned { return hp[(size_t)s * 64 + lane]; };

    const int rend = (row0 + 64 < nrows) ? row0 + 64 : nrows;
    const int ebase = offsets[row0];
    const int cnt = offsets[rend] - ebase;
    const bool fast = (cnt <= ECAP);

    if (fast) {
        for (int k = t; k < cnt; k += 512) elds[k] = srcs[ebase + k];
    }
    __syncthreads();

    // ---- gather: wave w owns rows w*8 .. w*8+7, processed in pairs
    for (int ii = 0; ii < 8; ii += 2) {
        const int r0 = w * 8 + ii, r1 = r0 + 1;
        const int ga = row0 + r0, gb = row0 + r1;
        const bool va = ga < nrows, vb = gb < nrows;
        float ax0 = 0.f, ay0 = 0.f, ax1 = 0.f, ay1 = 0.f;
        float x, y;
        if (va) { xf(ld(ga), x, y); ax0 = x; ay0 = y; }
        if (vb) { xf(ld(gb), x, y); ax1 = x; ay1 = y; }

        if (fast) {
            int p0 = 0, q0 = 0, p1 = 0, q1 = 0;
            if (va) { p0 = offsets[ga] - ebase; q0 = offsets[ga + 1] - ebase; }
            if (vb) { p1 = offsets[gb] - ebase; q1 = offsets[gb + 1] - ebase; }
            // paired rounds: 8+8 loads in flight
            while (q0 - p0 >= 8 && q1 - p1 >= 8) {
                const int a0 = elds[p0], a1 = elds[p0 + 1], a2 = elds[p0 + 2], a3 = elds[p0 + 3];
                const int a4 = elds[p0 + 4], a5 = elds[p0 + 5], a6 = elds[p0 + 6], a7 = elds[p0 + 7];
                const int b0 = elds[p1], b1 = elds[p1 + 1], b2 = elds[p1 + 2], b3 = elds[p1 + 3];
                const int b4 = elds[p1 + 4], b5 = elds[p1 + 5], b6 = elds[p1 + 6], b7 = elds[p1 + 7];
                unsigned ua0 = ld(a0), ua1 = ld(a1), ua2 = ld(a2), ua3 = ld(a3);
                unsigned ua4 = ld(a4), ua5 = ld(a5), ua6 = ld(a6), ua7 = ld(a7);
                unsigned ub0 = ld(b0), ub1 = ld(b1), ub2 = ld(b2), ub3 = ld(b3);
                unsigned ub4 = ld(b4), ub5 = ld(b5), ub6 = ld(b6), ub7 = ld(b7);
                xf(ua0, x, y); ax0 += x; ay0 += y;
                xf(ua1, x, y); ax0 += x; ay0 += y;
                xf(ua2, x, y); ax0 += x; ay0 += y;
                xf(ua3, x, y); ax0 += x; ay0 += y;
                xf(ua4, x, y); ax0 += x; ay0 += y;
                xf(ua5, x, y); ax0 += x; ay0 += y;
                xf(ua6, x, y); ax0 += x; ay0 += y;
                xf(ua7, x, y); ax0 += x; ay0 += y;
                xf(ub0, x, y); ax1 += x; ay1 += y;
                xf(ub1, x, y); ax1 += x; ay1 += y;
                xf(ub2, x, y); ax1 += x; ay1 += y;
                xf(ub3, x, y); ax1 += x; ay1 += y;
                xf(ub4, x, y); ax1 += x; ay1 += y;
                xf(ub5, x, y); ax1 += x; ay1 += y;
                xf(ub6, x, y); ax1 += x; ay1 += y;
                xf(ub7, x, y); ax1 += x; ay1 += y;
                p0 += 8; p1 += 8;
            }
            // paired rounds: 4+4
            while (q0 - p0 >= 4 && q1 - p1 >= 4) {
                const int a0 = elds[p0], a1 = elds[p0 + 1], a2 = elds[p0 + 2], a3 = elds[p0 + 3];
                const int b0 = elds[p1], b1 = elds[p1 + 1], b2 = elds[p1 + 2], b3 = elds[p1 + 3];
                unsigned ua0 = ld(a0), ua1 = ld(a1), ua2 = ld(a2), ua3 = ld(a3);
                unsigned ub0 = ld(b0), ub1 = ld(b1), ub2 = ld(b2), ub3 = ld(b3);
                xf(ua0, x, y); ax0 += x; ay0 += y;
                xf(ua1, x, y); ax0 += x; ay0 += y;
                xf(ua2, x, y); ax0 += x; ay0 += y;
                xf(ua3, x, y); ax0 += x; ay0 += y;
                xf(ub0, x, y); ax1 += x; ay1 += y;
                xf(ub1, x, y); ax1 += x; ay1 += y;
                xf(ub2, x, y); ax1 += x; ay1 += y;
                xf(ub3, x, y); ax1 += x; ay1 += y;
                p0 += 4; p1 += 4;
            }
            // row0 tail
            for (; p0 + 3 < q0; p0 += 4) {
                const int a0 = elds[p0], a1 = elds[p0 + 1], a2 = elds[p0 + 2], a3 = elds[p0 + 3];
                unsigned ua0 = ld(a0), ua1 = ld(a1), ua2 = ld(a2), ua3 = ld(a3);
                xf(ua0, x, y); ax0 += x; ay0 += y;
                xf(ua1, x, y); ax0 += x; ay0 += y;
                xf(ua2, x, y); ax0 += x; ay0 += y;
                xf(ua3, x, y); ax0 += x; ay0 += y;
            }
            for (; p0 < q0; ++p0) { xf(ld(elds[p0]), x, y); ax0 += x; ay0 += y; }
            // row1 tail
            for (; p1 + 3 < q1; p1 += 4) {
                const int b0 = elds[p1], b1 = elds[p1 + 1], b2 = elds[p1 + 2], b3 = elds[p1 + 3];
                unsigned ub0 = ld(b0), ub1 = ld(b1), ub2 = ld(b2), ub3 = ld(b3);
                xf(ub0, x, y); ax1 += x; ay1 += y;
                xf(ub1, x, y); ax1 += x; ay1 += y;
                xf(ub2, x, y); ax1 += x; ay1 += y;
                xf(ub3, x, y); ax1 += x; ay1 += y;
            }
            for (; p1 < q1; ++p1) { xf(ld(elds[p1]), x, y); ax1 += x; ay1 += y; }
        } else {
            if (va) {
                for (int j = offsets[ga]; j < offsets[ga + 1]; ++j) {
                    xf(ld(srcs[j]), x, y); ax0 += x; ay0 += y;
                }
            }
            if (vb) {
                for (int j = offsets[gb]; j < offsets[gb + 1]; ++j) {
                    xf(ld(srcs[j]), x, y); ax1 += x; ay1 += y;
                }
            }
        }
        *(unsigned*)&SB[r0 * 136 + 2 * lane] = packbf2(ax0, ay0);
        *(unsigned*)&SB[r1 * 136 + 2 * lane] = packbf2(ax1, ay1);
    }
    __syncthreads();  // SB holds A

    const int wr = w >> 2;     // row half (32 rows)
    const int wc = w & 3;      // col quarter (32 cols)
    const int l15 = lane & 15;
    const int l4 = lane >> 4;  // 0..3

    // ---- MFMA pass 1: t = A @ Wa^T
    f32x4 acc[2][2];
#pragma unroll
    for (int m = 0; m < 2; ++m)
#pragma unroll
        for (int n = 0; n < 2; ++n) acc[m][n] = (f32x4){0.f, 0.f, 0.f, 0.f};

#pragma unroll
    for (int kk = 0; kk < 4; ++kk) {
        bf16x8 af[2], bfr[2];
#pragma unroll
        for (int m = 0; m < 2; ++m)
            af[m] = *(const bf16x8*)&SB[(wr * 32 + m * 16 + l15) * 136 + kk * 32 + l4 * 8];
#pragma unroll
        for (int n = 0; n < 2; ++n)
            bfr[n] = *(const bf16x8*)(WaBf + (size_t)(wc * 32 + n * 16 + l15) * HD + kk * 32 + l4 * 8);
#pragma unroll
        for (int m = 0; m < 2; ++m)
#pragma unroll
            for (int n = 0; n < 2; ++n)
                acc[m][n] = __builtin_amdgcn_mfma_f32_16x16x32_bf16(af[m], bfr[n], acc[m][n], 0, 0, 0);
    }
    __syncthreads();  // pass-1 SB reads complete

    // epilogue 1: relu(t + ba) -> SB (as A2, bf16)
#pragma unroll
    for (int n = 0; n < 2; ++n) {
        const int col = wc * 32 + n * 16 + l15;
        const float bav = ba[col];
#pragma unroll
        for (int m = 0; m < 2; ++m) {
#pragma unroll
            for (int j = 0; j < 4; ++j) {
                const int row = wr * 32 + m * 16 + l4 * 4 + j;
                SB[row * 136 + col] = (short)f2bf(fmaxf(acc[m][n][j] + bav, 0.f));
            }
        }
    }
    __syncthreads();  // A2 visible

    // ---- MFMA pass 2: C = A2 @ Wb^T
#pragma unroll
    for (int m = 0; m < 2; ++m)
#pragma unroll
        for (int n = 0; n < 2; ++n) acc[m][n] = (f32x4){0.f, 0.f, 0.f, 0.f};

#pragma unroll
    for (int kk = 0; kk < 4; ++kk) {
        bf16x8 af[2], bfr[2];
#pragma unroll
        for (int m = 0; m < 2; ++m)
            af[m] = *(const bf16x8*)&SB[(wr * 32 + m * 16 + l15) * 136 + kk * 32 + l4 * 8];
#pragma unroll
        for (int n = 0; n < 2; ++n)
            bfr[n] = *(const bf16x8*)(WbBf + (size_t)(wc * 32 + n * 16 + l15) * HD + kk * 32 + l4 * 8);
#pragma unroll
        for (int m = 0; m < 2; ++m)
#pragma unroll
            for (int n = 0; n < 2; ++n)
                acc[m][n] = __builtin_amdgcn_mfma_f32_16x16x32_bf16(af[m], bfr[n], acc[m][n], 0, 0, 0);
    }

    // epilogue 2: Cb = bf16(acc + bb), plus per-column stats partials
    float st00 = 0.f, st01 = 0.f, st10 = 0.f, st11 = 0.f;
#pragma unroll
    for (int n = 0; n < 2; ++n) {
        const int col = wc * 32 + n * 16 + l15;
        const float bbv = bb[col];
#pragma unroll
        for (int m = 0; m < 2; ++m) {
#pragma unroll
            for (int j = 0; j < 4; ++j) {
                const int row = row0 + wr * 32 + m * 16 + l4 * 4 + j;
                if (row < nrows) {
                    float v = acc[m][n][j] + bbv;
                    Cb[(size_t)row * HD + col] = f2bf(v);
                    if (n == 0) { st00 += v; st01 = fmaf(v, v, st01); }
                    else        { st10 += v; st11 = fmaf(v, v, st11); }
                }
            }
        }
    }
#pragma unroll
    for (int d = 16; d < 64; d <<= 1) {
        st00 += __shfl_xor(st00, d);
        st01 += __shfl_xor(st01, d);
        st10 += __shfl_xor(st10, d);
        st11 += __shfl_xor(st11, d);
    }
    if (l4 == 0) {
        const int c0 = wc * 32 + l15, c1 = c0 + 16;
        sred[wr][c0][0] = st00; sred[wr][c0][1] = st01;
        sred[wr][c1][0] = st10; sred[wr][c1][1] = st11;
    }
    __syncthreads();
    if (t < 128) {
        float* so = statsOut + (blockIdx.x & (NBANK - 1)) * 256;
        atomicAdd(&so[t], sred[0][t][0] + sred[1][t][0]);
        atomicAdd(&so[128 + t], sred[0][t][1] + sred[1][t][1]);
    }
}

// ---------------- mean pool with BN+relu applied on the fly ----------------

__global__ void pool_bn(const unsigned* __restrict__ hp, const int* __restrict__ gstart,
                        const float* __restrict__ stats, const float* __restrict__ gam,
                        const float* __restrict__ bet, float* __restrict__ pooled, int layerOff) {
    __shared__ float2 red[8][64];
    const int g = blockIdx.x;
    const int tx = threadIdx.x;  // 512
    const int cp = tx & 63;
    const int q = tx >> 6;       // 0..7
    const float invn = 1.0f / (float)NN;
    const int c0 = 2 * cp, c1 = c0 + 1;
    float su0 = 0.f, sq0 = 0.f, su1 = 0.f, sq1 = 0.f;
#pragma unroll
    for (int b = 0; b < NBANK; ++b) {
        su0 += stats[b * 256 + c0];
        sq0 += stats[b * 256 + 128 + c0];
        su1 += stats[b * 256 + c1];
        sq1 += stats[b * 256 + 128 + c1];
    }
    float mu0 = su0 * invn;
    float va0 = sq0 * invn - mu0 * mu0;
    float sc0 = gam[c0] * rsqrtf(va0 + BN_EPS), sh0 = bet[c0] - mu0 * sc0;
    float mu1 = su1 * invn;
    float va1 = sq1 * invn - mu1 * mu1;
    float sc1 = gam[c1] * rsqrtf(va1 + BN_EPS), sh1 = bet[c1] - mu1 * sc1;

    const int s0 = gstart[g], s1 = gstart[g + 1];
    float a0 = 0.f, a1 = 0.f;
    for (int i = s0 + q; i < s1; i += 8) {
        unsigned u = hp[(size_t)i * 64 + cp];
        a0 += fmaxf(fmaf(bflo(u), sc0, sh0), 0.f);
        a1 += fmaxf(fmaf(bfhi(u), sc1, sh1), 0.f);
    }
    red[q][cp] = make_float2(a0, a1);
    __syncthreads();
    if (q == 0) {
        float r0 = 0.f, r1 = 0.f;
#pragma unroll
        for (int k = 0; k < 8; ++k) { r0 += red[k][cp].x; r1 += red[k][cp].y; }
        const int cnt = s1 - s0;
        const float fc = (cnt > 0) ? (float)cnt : 1.0f;
        *(float2*)&pooled[(size_t)g * (3 * HD) + layerOff + c0] = make_float2(r0 / fc, r1 / fc);
    }
}

// ---------------- final linear + row L2 normalize ----------------

__global__ void final_kernel(const float* __restrict__ pooled, const float* __restrict__ linW,
                             const float* __restrict__ linb, float* __restrict__ out) {
    __shared__ float p[3 * HD];
    const int g = blockIdx.x;
    const int o = threadIdx.x;  // 64 threads = 1 wave
    for (int k = o; k < 3 * HD; k += 64) p[k] = pooled[(size_t)g * (3 * HD) + k];
    __syncthreads();
    float acc = linb[o];
    const float* wrow = linW + (size_t)o * (3 * HD);
#pragma unroll 4
    for (int k = 0; k < 3 * HD; k += 4) {
        float4 wv = *(const float4*)(wrow + k);
        float4 pv = *(const float4*)(&p[k]);
        acc = fmaf(wv.x, pv.x, acc);
        acc = fmaf(wv.y, pv.y, acc);
        acc = fmaf(wv.z, pv.z, acc);
        acc = fmaf(wv.w, pv.w, acc);
    }
    float sq = acc * acc;
#pragma unroll
    for (int off = 32; off > 0; off >>= 1) sq += __shfl_xor(sq, off);
    float nrm = sqrtf(sq);
    nrm = fmaxf(nrm, 1e-12f);
    out[(size_t)g * OD + o] = acc / nrm;
}

// ---------------- launch ----------------

extern "C" void kernel_launch(void* const* d_in, const int* in_sizes, int n_in,
                              void* d_out, int out_size, void* d_ws, size_t ws_size,
                              hipStream_t stream) {
    const float* x    = (const float*)d_in[0];
    const int* ei     = (const int*)d_in[1];
    const int* batch  = (const int*)d_in[2];
    const float* W11  = (const float*)d_in[3];
    const float* b11  = (const float*)d_in[4];
    const float* W12  = (const float*)d_in[5];
    const float* b12  = (const float*)d_in[6];
    const float* g1   = (const float*)d_in[7];
    const float* be1  = (const float*)d_in[8];
    const float* W21  = (const float*)d_in[9];
    const float* b21  = (const float*)d_in[10];
    const float* W22  = (const float*)d_in[11];
    const float* b22  = (const float*)d_in[12];
    const float* g2   = (const float*)d_in[13];
    const float* be2  = (const float*)d_in[14];
    const float* W31  = (const float*)d_in[15];
    const float* b31  = (const float*)d_in[16];
    const float* W32  = (const float*)d_in[17];
    const float* b32  = (const float*)d_in[18];
    const float* g3   = (const float*)d_in[19];
    const float* be3  = (const float*)d_in[20];
    const float* linW = (const float*)d_in[21];
    const float* linb = (const float*)d_in[22];

    const int* src = ei;
    const int* dst = ei + NE;

    char* ws = (char*)d_ws;
    size_t off = 0;
    auto alloc = [&](size_t bytes) -> void* {
        void* p = ws + off;
        off += (bytes + 255) & ~(size_t)255;
        return p;
    };
    int* deg      = (int*)alloc((size_t)NN * 4);
    int* offsets  = (int*)alloc((size_t)(NN + 1) * 4);
    int* cursor   = (int*)alloc((size_t)NN * 4);
    int* srcs     = (int*)alloc((size_t)NE * 4);
    int* gstart   = (int*)alloc((size_t)(NG + 1) * 4);
    int* lexcl    = (int*)alloc((size_t)NN * 4);
    int* bsum     = (int*)alloc((size_t)NSB * 4);
    int* boff     = (int*)alloc((size_t)NSB * 4);
    float* stats  = (float*)alloc((size_t)3 * NBANK * 256 * 4);
    float* pooled = (float*)alloc((size_t)NG * 3 * HD * 4);
    unsigned short* xbf  = (unsigned short*)alloc((size_t)NN * HD * 2);
    unsigned short* cbf1 = (unsigned short*)alloc((size_t)NN * HD * 2);
    unsigned short* cbf2 = (unsigned short*)alloc((size_t)NN * HD * 2);
    unsigned short* wbf  = (unsigned short*)alloc((size_t)6 * HD * HD * 2);
    (void)ws_size; (void)n_in; (void)in_sizes; (void)out_size;

    // ---- conversions to bf16
    cvt_kernel<<<(NN * HD / 8 + 255) / 256, 256, 0, stream>>>(x, xbf, NN * HD / 8);
    cvt6_kernel<<<48, 256, 0, stream>>>(W11, W12, W21, W22, W31, W32, wbf);

    // ---- CSR build
    hipMemsetAsync(deg, 0, (size_t)NN * 4, stream);
    hist_kernel<<<(NE + 255) / 256, 256, 0, stream>>>(dst, deg, NE);
    local_scan_kernel<<<NSB, SCAN_BLK, 0, stream>>>(deg, lexcl, bsum, NN);
    scan_bsum_kernel<<<1, 64, 0, stream>>>(bsum, boff, offsets, NSB, NN);
    finalize_scan_kernel<<<(NN + 255) / 256, 256, 0, stream>>>(lexcl, boff, offsets, cursor, NN);
    fill_kernel<<<(NE + 255) / 256, 256, 0, stream>>>(src, dst, cursor, srcs, NE);
    gstart_kernel<<<(NN + 255) / 256, 256, 0, stream>>>(batch, gstart, NN, NG);

    hipMemsetAsync(stats, 0, (size_t)3 * NBANK * 256 * 4, stream);

    const int ginGrid = (NN + 63) / 64;  // 782

    const unsigned* xu  = (const unsigned*)xbf;
    const unsigned* c1u = (const unsigned*)cbf1;
    const unsigned* c2u = (const unsigned*)cbf2;

    float* st1 = stats;
    float* st2 = stats + NBANK * 256;
    float* st3 = stats + 2 * NBANK * 256;

    // L1: gather x (identity) -> cbf1, stats -> st1
    fused_gin<false><<<ginGrid, 512, 0, stream>>>(xu, offsets, srcs, st1, g1, be1,
                                                  wbf + 0 * HD * HD, b11, wbf + 1 * HD * HD, b12,
                                                  cbf1, st1, NN);
    pool_bn<<<NG, 512, 0, stream>>>(c1u, gstart, st1, g1, be1, pooled, 0);

    // L2: gather h1 = relu(BN1(c1)) -> cbf2, stats -> st2
    fused_gin<true><<<ginGrid, 512, 0, stream>>>(c1u, offsets, srcs, st1, g1, be1,
                                                 wbf + 2 * HD * HD, b21, wbf + 3 * HD * HD, b22,
                                                 cbf2, st2, NN);
    pool_bn<<<NG, 512, 0, stream>>>(c2u, gstart, st2, g2, be2, pooled, HD);

    // L3: gather h2 = relu(BN2(c2)) -> cbf1 (reuse), stats -> st3
    fused_gin<true><<<ginGrid, 512, 0, stream>>>(c2u, offsets, srcs, st2, g2, be2,
                                                 wbf + 4 * HD * HD, b31, wbf + 5 * HD * HD, b32,
                                                 cbf1, st3, NN);
    pool_bn<<<NG, 512, 0, stream>>>(c1u, gstart, st3, g3, be3, pooled, 2 * HD);

    final_kernel<<<NG, OD, 0, stream>>>(pooled, linW, linb, (float*)d_out);
}

// Round 10
// 248.790 us; speedup vs baseline: 18.8904x; 1.1984x over previous
//
#include <hip/hip_runtime.h>

#define NN 50000
#define NE 600000
#define HD 128
#define NG 512
#define OD 64
#define BN_EPS 1e-5f

#define SCAN_BLK 1024
#define NSB ((NN + SCAN_BLK - 1) / SCAN_BLK)  // 49
#define ECAP 1536   // LDS edge-index capacity (mean 768/block; fallback if exceeded)
#define NBANK 8     // stats atomic shards

typedef __attribute__((ext_vector_type(8))) short bf16x8;
typedef __attribute__((ext_vector_type(4))) float f32x4;

__device__ __forceinline__ unsigned short f2bf(float f) {
    unsigned u = __builtin_bit_cast(unsigned, f);
    unsigned r = u + 0x7FFFu + ((u >> 16) & 1u);  // round-to-nearest-even
    return (unsigned short)(r >> 16);
}

__device__ __forceinline__ float bflo(unsigned u) { return __builtin_bit_cast(float, u << 16); }
__device__ __forceinline__ float bfhi(unsigned u) { return __builtin_bit_cast(float, u & 0xffff0000u); }

__device__ __forceinline__ unsigned packbf2(float x, float y) {
    return (unsigned)f2bf(x) | ((unsigned)f2bf(y) << 16);
}

// ---------------- fp32 -> bf16 bulk converts ----------------

__global__ void cvt_kernel(const float* __restrict__ src, unsigned short* __restrict__ dst, int n8) {
    int i = blockIdx.x * blockDim.x + threadIdx.x;
    if (i >= n8) return;
    float4 a = ((const float4*)src)[2 * i];
    float4 b = ((const float4*)src)[2 * i + 1];
    uint4 o;
    o.x = packbf2(a.x, a.y);
    o.y = packbf2(a.z, a.w);
    o.z = packbf2(b.x, b.y);
    o.w = packbf2(b.z, b.w);
    ((uint4*)dst)[i] = o;
}

__global__ void cvt6_kernel(const float* __restrict__ s0, const float* __restrict__ s1,
                            const float* __restrict__ s2, const float* __restrict__ s3,
                            const float* __restrict__ s4, const float* __restrict__ s5,
                            unsigned short* __restrict__ dst) {
    int i = blockIdx.x * blockDim.x + threadIdx.x;  // 0 .. 6*2048-1
    const int wsel = i >> 11;
    const int o8 = i & 2047;
    const float* sp = (wsel == 0) ? s0 : (wsel == 1) ? s1 : (wsel == 2) ? s2
                    : (wsel == 3) ? s3 : (wsel == 4) ? s4 : s5;
    float4 a = ((const float4*)sp)[2 * o8];
    float4 b = ((const float4*)sp)[2 * o8 + 1];
    uint4 o;
    o.x = packbf2(a.x, a.y);
    o.y = packbf2(a.z, a.w);
    o.z = packbf2(b.x, b.y);
    o.w = packbf2(b.z, b.w);
    ((uint4*)(dst + (size_t)wsel * HD * HD))[o8] = o;
}

// ---------------- CSR build ----------------

__global__ void hist_kernel(const int* __restrict__ dst, int* __restrict__ deg, int E) {
    int i = blockIdx.x * blockDim.x + threadIdx.x;
    if (i < E) atomicAdd(&deg[dst[i]], 1);
}

__global__ void local_scan_kernel(const int* __restrict__ deg, int* __restrict__ lexcl,
                                  int* __restrict__ bsum, int n) {
    __shared__ int part[SCAN_BLK];
    const int tid = threadIdx.x;
    const int i = blockIdx.x * SCAN_BLK + tid;
    int v = (i < n) ? deg[i] : 0;
    part[tid] = v;
    __syncthreads();
    int incl = v;
    for (int off = 1; off < SCAN_BLK; off <<= 1) {
        int t = (tid >= off) ? part[tid - off] : 0;
        __syncthreads();
        incl += t;
        part[tid] = incl;
        __syncthreads();
    }
    if (i < n) lexcl[i] = incl - v;
    if (tid == SCAN_BLK - 1) bsum[blockIdx.x] = incl;
}

__global__ void scan_bsum_kernel(const int* __restrict__ bsum, int* __restrict__ boff,
                                 int* __restrict__ offsets, int nb, int n) {
    const int tid = threadIdx.x;  // 64 threads
    int orig = (tid < nb) ? bsum[tid] : 0;
    int v = orig;
    for (int off = 1; off < 64; off <<= 1) {
        int t = __shfl_up(v, off);
        if (tid >= off) v += t;
    }
    if (tid < nb) boff[tid] = v - orig;
    if (tid == 63) offsets[n] = v;  // total = E
}

__global__ void finalize_scan_kernel(const int* __restrict__ lexcl, const int* __restrict__ boff,
                                     int* __restrict__ offsets, int* __restrict__ cursor, int n) {
    int i = blockIdx.x * blockDim.x + threadIdx.x;
    if (i < n) {
        int o = lexcl[i] + boff[i >> 10];
        offsets[i] = o;
        cursor[i] = o;
    }
}

__global__ void fill_kernel(const int* __restrict__ src, const int* __restrict__ dst,
                            int* __restrict__ cursor, int* __restrict__ srcs, int E) {
    int i = blockIdx.x * blockDim.x + threadIdx.x;
    if (i < E) {
        int pos = atomicAdd(&cursor[dst[i]], 1);
        srcs[pos] = src[i];
    }
}

__global__ void gstart_kernel(const int* __restrict__ batch, int* __restrict__ gstart,
                              int n, int G) {
    int i = blockIdx.x * blockDim.x + threadIdx.x;
    if (i >= n) return;
    int b = batch[i];
    int bp = (i == 0) ? -1 : batch[i - 1];
    for (int g = bp + 1; g <= b; ++g) gstart[g] = i;
    if (i == n - 1) {
        for (int g = b + 1; g <= G; ++g) gstart[g] = n;
    }
}

// ---------------- fused GIN layer ----------------
// z_i = h_i + sum_{j in N(i)} h_j  (h already BN+relu'd; pure sum gather)
// C = relu(z @ Wa^T + ba) @ Wb^T + bb  -> bf16 out + sharded column stats.
// 512 threads = 8 waves. Gather: lanes split 4 groups x 16 chunks; one uint4
// wave-load fetches FOUR rows (1 KB); <=16 items covered by 4 independent
// upfront loads (1 latency exposure/node); shfl_xor(16,32) combines groups.

__global__ __launch_bounds__(512) void fused_gin(const unsigned* __restrict__ hp,
                                                 const int* __restrict__ offsets,
                                                 const int* __restrict__ srcs,
                                                 const unsigned short* __restrict__ WaBf,
                                                 const float* __restrict__ ba,
                                                 const unsigned short* __restrict__ WbBf,
                                                 const float* __restrict__ bb,
                                                 unsigned short* __restrict__ Cb,
                                                 float* __restrict__ statsOut,
                                                 int nrows) {
    __shared__ short SB[64 * 136];
    __shared__ int elds[ECAP];
    __shared__ float sred[2][128][2];

    const int t = threadIdx.x;
    const int lane = t & 63;
    const int w = t >> 6;        // wave 0..7
    const int g16 = lane >> 4;   // item slot 0..3
    const int c16 = lane & 15;   // 16B chunk within row
    const int row0 = blockIdx.x * 64;

    const int rend = (row0 + 64 < nrows) ? row0 + 64 : nrows;
    const int ebase = offsets[row0];
    const int cnt = offsets[rend] - ebase;
    const bool fast = (cnt <= ECAP);

    if (fast) {
        for (int k = t; k < cnt; k += 512) elds[k] = srcs[ebase + k];
    }
    __syncthreads();

    // ---- gather: wave w owns rows w*8 .. w*8+7, one node at a time
    for (int i = 0; i < 8; ++i) {
        const int r = w * 8 + i;
        const int grow = row0 + r;
        float a0 = 0.f, a1 = 0.f, a2 = 0.f, a3 = 0.f;
        float a4 = 0.f, a5 = 0.f, a6 = 0.f, a7 = 0.f;

        auto acc8 = [&](uint4 v) {
            a0 += bflo(v.x); a1 += bfhi(v.x);
            a2 += bflo(v.y); a3 += bfhi(v.y);
            a4 += bflo(v.z); a5 += bfhi(v.z);
            a6 += bflo(v.w); a7 += bfhi(v.w);
        };
        auto ld4 = [&](int idx) -> uint4 {
            return ((const uint4*)(hp + (size_t)idx * 64))[c16];
        };

        if (grow < nrows) {
            const int jb = offsets[grow];
            const int items = offsets[grow + 1] - jb + 1;  // self + edges
            if (fast) {
                const int j0 = jb - ebase;
                // 4 independent upfront loads cover items 0..15
                uint4 v0 = {0, 0, 0, 0}, v1 = {0, 0, 0, 0}, v2 = {0, 0, 0, 0}, v3 = {0, 0, 0, 0};
                {
                    const int it = g16;
                    if (it < items) v0 = ld4(it == 0 ? grow : elds[j0 + it - 1]);
                }
                {
                    const int it = 4 + g16;
                    if (it < items) v1 = ld4(elds[j0 + it - 1]);
                }
                {
                    const int it = 8 + g16;
                    if (it < items) v2 = ld4(elds[j0 + it - 1]);
                }
                {
                    const int it = 12 + g16;
                    if (it < items) v3 = ld4(elds[j0 + it - 1]);
                }
                acc8(v0); acc8(v1); acc8(v2); acc8(v3);
                // rare tail: items > 16
                for (int base = 16; base < items; base += 4) {
                    const int it = base + g16;
                    uint4 v = {0, 0, 0, 0};
                    if (it < items) v = ld4(elds[j0 + it - 1]);
                    acc8(v);
                }
            } else {
                for (int base = 0; base < items; base += 4) {
                    const int it = base + g16;
                    uint4 v = {0, 0, 0, 0};
                    if (it < items) v = ld4(it == 0 ? grow : srcs[jb + it - 1]);
                    acc8(v);
                }
            }
        }
        // combine the 4 lane-groups
        a0 += __shfl_xor(a0, 16); a1 += __shfl_xor(a1, 16);
        a2 += __shfl_xor(a2, 16); a3 += __shfl_xor(a3, 16);
        a4 += __shfl_xor(a4, 16); a5 += __shfl_xor(a5, 16);
        a6 += __shfl_xor(a6, 16); a7 += __shfl_xor(a7, 16);
        a0 += __shfl_xor(a0, 32); a1 += __shfl_xor(a1, 32);
        a2 += __shfl_xor(a2, 32); a3 += __shfl_xor(a3, 32);
        a4 += __shfl_xor(a4, 32); a5 += __shfl_xor(a5, 32);
        a6 += __shfl_xor(a6, 32); a7 += __shfl_xor(a7, 32);
        if (g16 == 0) {
            uint4 o;
            o.x = packbf2(a0, a1);
            o.y = packbf2(a2, a3);
            o.z = packbf2(a4, a5);
            o.w = packbf2(a6, a7);
            *(uint4*)&SB[r * 136 + c16 * 8] = o;
        }
    }
    __syncthreads();  // SB holds A

    const int wr = w >> 2;     // row half (32 rows)
    const int wc = w & 3;      // col quarter (32 cols)
    const int l15 = lane & 15;
    const int l4 = lane >> 4;  // 0..3

    // ---- MFMA pass 1: t = A @ Wa^T
    f32x4 acc[2][2];
#pragma unroll
    for (int m = 0; m < 2; ++m)
#pragma unroll
        for (int n = 0; n < 2; ++n) acc[m][n] = (f32x4){0.f, 0.f, 0.f, 0.f};

#pragma unroll
    for (int kk = 0; kk < 4; ++kk) {
        bf16x8 af[2], bfr[2];
#pragma unroll
        for (int m = 0; m < 2; ++m)
            af[m] = *(const bf16x8*)&SB[(wr * 32 + m * 16 + l15) * 136 + kk * 32 + l4 * 8];
#pragma unroll
        for (int n = 0; n < 2; ++n)
            bfr[n] = *(const bf16x8*)(WaBf + (size_t)(wc * 32 + n * 16 + l15) * HD + kk * 32 + l4 * 8);
#pragma unroll
        for (int m = 0; m < 2; ++m)
#pragma unroll
            for (int n = 0; n < 2; ++n)
                acc[m][n] = __builtin_amdgcn_mfma_f32_16x16x32_bf16(af[m], bfr[n], acc[m][n], 0, 0, 0);
    }
    __syncthreads();  // pass-1 SB reads complete

    // epilogue 1: relu(t + ba) -> SB (as A2, bf16)
#pragma unroll
    for (int n = 0; n < 2; ++n) {
        const int col = wc * 32 + n * 16 + l15;
        const float bav = ba[col];
#pragma unroll
        for (int m = 0; m < 2; ++m) {
#pragma unroll
            for (int j = 0; j < 4; ++j) {
                const int row = wr * 32 + m * 16 + l4 * 4 + j;
                SB[row * 136 + col] = (short)f2bf(fmaxf(acc[m][n][j] + bav, 0.f));
            }
        }
    }
    __syncthreads();  // A2 visible

    // ---- MFMA pass 2: C = A2 @ Wb^T
#pragma unroll
    for (int m = 0; m < 2; ++m)
#pragma unroll
        for (int n = 0; n < 2; ++n) acc[m][n] = (f32x4){0.f, 0.f, 0.f, 0.f};

#pragma unroll
    for (int kk = 0; kk < 4; ++kk) {
        bf16x8 af[2], bfr[2];
#pragma unroll
        for (int m = 0; m < 2; ++m)
            af[m] = *(const bf16x8*)&SB[(wr * 32 + m * 16 + l15) * 136 + kk * 32 + l4 * 8];
#pragma unroll
        for (int n = 0; n < 2; ++n)
            bfr[n] = *(const bf16x8*)(WbBf + (size_t)(wc * 32 + n * 16 + l15) * HD + kk * 32 + l4 * 8);
#pragma unroll
        for (int m = 0; m < 2; ++m)
#pragma unroll
            for (int n = 0; n < 2; ++n)
                acc[m][n] = __builtin_amdgcn_mfma_f32_16x16x32_bf16(af[m], bfr[n], acc[m][n], 0, 0, 0);
    }

    // epilogue 2: Cb = bf16(acc + bb), plus per-column stats partials
    float st00 = 0.f, st01 = 0.f, st10 = 0.f, st11 = 0.f;
#pragma unroll
    for (int n = 0; n < 2; ++n) {
        const int col = wc * 32 + n * 16 + l15;
        const float bbv = bb[col];
#pragma unroll
        for (int m = 0; m < 2; ++m) {
#pragma unroll
            for (int j = 0; j < 4; ++j) {
                const int row = row0 + wr * 32 + m * 16 + l4 * 4 + j;
                if (row < nrows) {
                    float v = acc[m][n][j] + bbv;
                    Cb[(size_t)row * HD + col] = f2bf(v);
                    if (n == 0) { st00 += v; st01 = fmaf(v, v, st01); }
                    else        { st10 += v; st11 = fmaf(v, v, st11); }
                }
            }
        }
    }
#pragma unroll
    for (int d = 16; d < 64; d <<= 1) {
        st00 += __shfl_xor(st00, d);
        st01 += __shfl_xor(st01, d);
        st10 += __shfl_xor(st10, d);
        st11 += __shfl_xor(st11, d);
    }
    if (l4 == 0) {
        const int c0 = wc * 32 + l15, c1 = c0 + 16;
        sred[wr][c0][0] = st00; sred[wr][c0][1] = st01;
        sred[wr][c1][0] = st10; sred[wr][c1][1] = st11;
    }
    __syncthreads();
    if (t < 128) {
        float* so = statsOut + (blockIdx.x & (NBANK - 1)) * 256;
        atomicAdd(&so[t], sred[0][t][0] + sred[1][t][0]);
        atomicAdd(&so[128 + t], sred[0][t][1] + sred[1][t][1]);
    }
}

// ---------------- mean pool with BN+relu on the fly; optional h=relu(BN(c)) write ----

template <bool WR>
__global__ void pool_bn(const unsigned* __restrict__ hp, const int* __restrict__ gstart,
                        const float* __restrict__ stats, const float* __restrict__ gam,
                        const float* __restrict__ bet, float* __restrict__ pooled, int layerOff,
                        unsigned* __restrict__ hn) {
    __shared__ float2 red[8][64];
    const int g = blockIdx.x;
    const int tx = threadIdx.x;  // 512
    const int cp = tx & 63;
    const int q = tx >> 6;       // 0..7
    const float invn = 1.0f / (float)NN;
    const int c0 = 2 * cp, c1 = c0 + 1;
    float su0 = 0.f, sq0 = 0.f, su1 = 0.f, sq1 = 0.f;
#pragma unroll
    for (int b = 0; b < NBANK; ++b) {
        su0 += stats[b * 256 + c0];
        sq0 += stats[b * 256 + 128 + c0];
        su1 += stats[b * 256 + c1];
        sq1 += stats[b * 256 + 128 + c1];
    }
    float mu0 = su0 * invn;
    float va0 = sq0 * invn - mu0 * mu0;
    float sc0 = gam[c0] * rsqrtf(va0 + BN_EPS), sh0 = bet[c0] - mu0 * sc0;
    float mu1 = su1 * invn;
    float va1 = sq1 * invn - mu1 * mu1;
    float sc1 = gam[c1] * rsqrtf(va1 + BN_EPS), sh1 = bet[c1] - mu1 * sc1;

    const int s0 = gstart[g], s1 = gstart[g + 1];
    float a0 = 0.f, a1 = 0.f;
    for (int i = s0 + q; i < s1; i += 8) {
        unsigned u = hp[(size_t)i * 64 + cp];
        float v0 = fmaxf(fmaf(bflo(u), sc0, sh0), 0.f);
        float v1 = fmaxf(fmaf(bfhi(u), sc1, sh1), 0.f);
        if (WR) hn[(size_t)i * 64 + cp] = packbf2(v0, v1);
        a0 += v0;
        a1 += v1;
    }
    red[q][cp] = make_float2(a0, a1);
    __syncthreads();
    if (q == 0) {
        float r0 = 0.f, r1 = 0.f;
#pragma unroll
        for (int k = 0; k < 8; ++k) { r0 += red[k][cp].x; r1 += red[k][cp].y; }
        const int cnt = s1 - s0;
        const float fc = (cnt > 0) ? (float)cnt : 1.0f;
        *(float2*)&pooled[(size_t)g * (3 * HD) + layerOff + c0] = make_float2(r0 / fc, r1 / fc);
    }
}

// ---------------- final linear + row L2 normalize ----------------

__global__ void final_kernel(const float* __restrict__ pooled, const float* __restrict__ linW,
                             const float* __restrict__ linb, float* __restrict__ out) {
    __shared__ float p[3 * HD];
    const int g = blockIdx.x;
    const int o = threadIdx.x;  // 64 threads = 1 wave
    for (int k = o; k < 3 * HD; k += 64) p[k] = pooled[(size_t)g * (3 * HD) + k];
    __syncthreads();
    float acc = linb[o];
    const float* wrow = linW + (size_t)o * (3 * HD);
#pragma unroll 4
    for (int k = 0; k < 3 * HD; k += 4) {
        float4 wv = *(const float4*)(wrow + k);
        float4 pv = *(const float4*)(&p[k]);
        acc = fmaf(wv.x, pv.x, acc);
        acc = fmaf(wv.y, pv.y, acc);
        acc = fmaf(wv.z, pv.z, acc);
        acc = fmaf(wv.w, pv.w, acc);
    }
    float sq = acc * acc;
#pragma unroll
    for (int off = 32; off > 0; off >>= 1) sq += __shfl_xor(sq, off);
    float nrm = sqrtf(sq);
    nrm = fmaxf(nrm, 1e-12f);
    out[(size_t)g * OD + o] = acc / nrm;
}

// ---------------- launch ----------------

extern "C" void kernel_launch(void* const* d_in, const int* in_sizes, int n_in,
                              void* d_out, int out_size, void* d_ws, size_t ws_size,
                              hipStream_t stream) {
    const float* x    = (const float*)d_in[0];
    const int* ei     = (const int*)d_in[1];
    const int* batch  = (const int*)d_in[2];
    const float* W11  = (const float*)d_in[3];
    const float* b11  = (const float*)d_in[4];
    const float* W12  = (const float*)d_in[5];
    const float* b12  = (const float*)d_in[6];
    const float* g1   = (const float*)d_in[7];
    const float* be1  = (const float*)d_in[8];
    const float* W21  = (const float*)d_in[9];
    const float* b21  = (const float*)d_in[10];
    const float* W22  = (const float*)d_in[11];
    const float* b22  = (const float*)d_in[12];
    const float* g2   = (const float*)d_in[13];
    const float* be2  = (const float*)d_in[14];
    const float* W31  = (const float*)d_in[15];
    const float* b31  = (const float*)d_in[16];
    const float* W32  = (const float*)d_in[17];
    const float* b32  = (const float*)d_in[18];
    const float* g3   = (const float*)d_in[19];
    const float* be3  = (const float*)d_in[20];
    const float* linW = (const float*)d_in[21];
    const float* linb = (const float*)d_in[22];

    const int* src = ei;
    const int* dst = ei + NE;

    char* ws = (char*)d_ws;
    size_t off = 0;
    auto alloc = [&](size_t bytes) -> void* {
        void* p = ws + off;
        off += (bytes + 255) & ~(size_t)255;
        return p;
    };
    int* deg      = (int*)alloc((size_t)NN * 4);
    int* offsets  = (int*)alloc((size_t)(NN + 1) * 4);
    int* cursor   = (int*)alloc((size_t)NN * 4);
    int* srcs     = (int*)alloc((size_t)NE * 4);
    int* gstart   = (int*)alloc((size_t)(NG + 1) * 4);
    int* lexcl    = (int*)alloc((size_t)NN * 4);
    int* bsum     = (int*)alloc((size_t)NSB * 4);
    int* boff     = (int*)alloc((size_t)NSB * 4);
    float* stats  = (float*)alloc((size_t)3 * NBANK * 256 * 4);
    float* pooled = (float*)alloc((size_t)NG * 3 * HD * 4);
    unsigned short* xbf  = (unsigned short*)alloc((size_t)NN * HD * 2);
    unsigned short* cbf1 = (unsigned short*)alloc((size_t)NN * HD * 2);
    unsigned short* cbf2 = (unsigned short*)alloc((size_t)NN * HD * 2);
    unsigned short* hbf1 = (unsigned short*)alloc((size_t)NN * HD * 2);
    unsigned short* hbf2 = (unsigned short*)alloc((size_t)NN * HD * 2);
    unsigned short* wbf  = (unsigned short*)alloc((size_t)6 * HD * HD * 2);
    (void)ws_size; (void)n_in; (void)in_sizes; (void)out_size;

    // ---- conversions to bf16
    cvt_kernel<<<(NN * HD / 8 + 255) / 256, 256, 0, stream>>>(x, xbf, NN * HD / 8);
    cvt6_kernel<<<48, 256, 0, stream>>>(W11, W12, W21, W22, W31, W32, wbf);

    // ---- CSR build
    hipMemsetAsync(deg, 0, (size_t)NN * 4, stream);
    hist_kernel<<<(NE + 255) / 256, 256, 0, stream>>>(dst, deg, NE);
    local_scan_kernel<<<NSB, SCAN_BLK, 0, stream>>>(deg, lexcl, bsum, NN);
    scan_bsum_kernel<<<1, 64, 0, stream>>>(bsum, boff, offsets, NSB, NN);
    finalize_scan_kernel<<<(NN + 255) / 256, 256, 0, stream>>>(lexcl, boff, offsets, cursor, NN);
    fill_kernel<<<(NE + 255) / 256, 256, 0, stream>>>(src, dst, cursor, srcs, NE);
    gstart_kernel<<<(NN + 255) / 256, 256, 0, stream>>>(batch, gstart, NN, NG);

    hipMemsetAsync(stats, 0, (size_t)3 * NBANK * 256 * 4, stream);

    const int ginGrid = (NN + 63) / 64;  // 782

    const unsigned* xu  = (const unsigned*)xbf;
    const unsigned* c1u = (const unsigned*)cbf1;
    const unsigned* c2u = (const unsigned*)cbf2;
    const unsigned* h1u = (const unsigned*)hbf1;
    const unsigned* h2u = (const unsigned*)hbf2;

    float* st1 = stats;
    float* st2 = stats + NBANK * 256;
    float* st3 = stats + 2 * NBANK * 256;

    // L1: gather xbf -> cbf1 + st1; pool writes h1 = relu(BN1(c1))
    fused_gin<<<ginGrid, 512, 0, stream>>>(xu, offsets, srcs,
                                           wbf + 0 * HD * HD, b11, wbf + 1 * HD * HD, b12,
                                           cbf1, st1, NN);
    pool_bn<true><<<NG, 512, 0, stream>>>(c1u, gstart, st1, g1, be1, pooled, 0, (unsigned*)hbf1);

    // L2: gather h1 -> cbf2 + st2; pool writes h2
    fused_gin<<<ginGrid, 512, 0, stream>>>(h1u, offsets, srcs,
                                           wbf + 2 * HD * HD, b21, wbf + 3 * HD * HD, b22,
                                           cbf2, st2, NN);
    pool_bn<true><<<NG, 512, 0, stream>>>(c2u, gstart, st2, g2, be2, pooled, HD, (unsigned*)hbf2);

    // L3: gather h2 -> cbf1 (reuse) + st3; pool (no h write)
    fused_gin<<<ginGrid, 512, 0, stream>>>(h2u, offsets, srcs,
                                           wbf + 4 * HD * HD, b31, wbf + 5 * HD * HD, b32,
                                           cbf1, st3, NN);
    pool_bn<false><<<NG, 512, 0, stream>>>(c1u, gstart, st3, g3, be3, pooled, 2 * HD, nullptr);

    final_kernel<<<NG, OD, 0, stream>>>(pooled, linW, linb, (float*)d_out);
}